// Round 1
// baseline (2884.170 us; speedup 1.0000x reference)
//
#include <hip/hip_runtime.h>

#define BLOCK 256

// ---- Hash-grid compile-time tables -------------------------------------
constexpr unsigned kP1 = 73856093u, kP2 = 19349663u, kP3 = 83492791u;
constexpr int kRes[16] = {16, 32, 64, 128, 256, 512, 512, 512,
                          512, 512, 512, 512, 512, 512, 512, 512};
// all level sizes are powers of two -> modulo == AND mask
constexpr unsigned kMask[16] = {4095u, 32767u, 262143u, 524287u, 524287u, 524287u,
                                524287u, 524287u, 524287u, 524287u, 524287u, 524287u,
                                524287u, 524287u, 524287u, 524287u};
constexpr int kOff[16] = {0,       4096,    36864,   299008,  823296,  1347584,
                          1871872, 2396160, 2920448, 3444736, 3969024, 4493312,
                          5017600, 5541888, 6066176, 6590464};

// ---- Fully-unrolled dense layer: x(IN) @ W(IN,OUT) + B, weights in LDS --
template <int IN, int OUT, bool RELU>
__device__ __forceinline__ void dense(const float* __restrict__ x, float* __restrict__ y,
                                      const float* __restrict__ W, const float* __restrict__ B) {
  if constexpr ((OUT % 4) == 0) {
#pragma unroll
    for (int j4 = 0; j4 < OUT / 4; ++j4) {
      const float4 b4 = *reinterpret_cast<const float4*>(B + 4 * j4);
      y[4 * j4 + 0] = b4.x; y[4 * j4 + 1] = b4.y;
      y[4 * j4 + 2] = b4.z; y[4 * j4 + 3] = b4.w;
    }
#pragma unroll
    for (int i = 0; i < IN; ++i) {
      const float xi = x[i];
#pragma unroll
      for (int j4 = 0; j4 < OUT / 4; ++j4) {
        const float4 w4 = *reinterpret_cast<const float4*>(W + i * OUT + 4 * j4);
        y[4 * j4 + 0] = __builtin_fmaf(xi, w4.x, y[4 * j4 + 0]);
        y[4 * j4 + 1] = __builtin_fmaf(xi, w4.y, y[4 * j4 + 1]);
        y[4 * j4 + 2] = __builtin_fmaf(xi, w4.z, y[4 * j4 + 2]);
        y[4 * j4 + 3] = __builtin_fmaf(xi, w4.w, y[4 * j4 + 3]);
      }
    }
  } else {
#pragma unroll
    for (int j = 0; j < OUT; ++j) y[j] = B[j];
#pragma unroll
    for (int i = 0; i < IN; ++i) {
      const float xi = x[i];
#pragma unroll
      for (int j = 0; j < OUT; ++j) y[j] = __builtin_fmaf(xi, W[i * OUT + j], y[j]);
    }
  }
  if constexpr (RELU) {
#pragma unroll
    for (int j = 0; j < OUT; ++j) y[j] = fmaxf(y[j], 0.0f);
  }
}

__device__ __forceinline__ void copy_seg(float* __restrict__ dst, const float* __restrict__ src,
                                         int n, int tid) {
  for (int t = tid; t < n; t += BLOCK) dst[t] = src[t];
}

__global__ __launch_bounds__(BLOCK) void ngp_fused(
    const float* __restrict__ pos, const float* __restrict__ dirs, const float* __restrict__ emb,
    const float* __restrict__ dw0, const float* __restrict__ db0,
    const float* __restrict__ dw1, const float* __restrict__ db1,
    const float* __restrict__ dw2, const float* __restrict__ db2,
    const float* __restrict__ cw0, const float* __restrict__ cb0,
    const float* __restrict__ cw1, const float* __restrict__ cb1,
    const float* __restrict__ cw2, const float* __restrict__ cb2,
    const float* __restrict__ cw3, const float* __restrict__ cb3,
    float* __restrict__ out, int n) {
  __shared__ __align__(16) float sW[10564];
  const int tid = threadIdx.x;

  // ---- Phase 1 weights: density MLP (7312 floats) ----
  copy_seg(sW + 0,    dw0, 2048, tid);
  copy_seg(sW + 2048, db0, 64, tid);
  copy_seg(sW + 2112, dw1, 4096, tid);
  copy_seg(sW + 6208, db1, 64, tid);
  copy_seg(sW + 6272, dw2, 1024, tid);
  copy_seg(sW + 7296, db2, 16, tid);
  __syncthreads();

  int i = blockIdx.x * BLOCK + tid;
  if (i >= n) i = n - 1;  // duplicate work instead of divergent barriers

  // ---- Hash-grid encode ----
  const float px = pos[3 * i + 0], py = pos[3 * i + 1], pz = pos[3 * i + 2];
  float pn[3] = {fminf(fmaxf((px + 1.0f) * 0.5f, 0.0f), 1.0f),
                 fminf(fmaxf((py + 1.0f) * 0.5f, 0.0f), 1.0f),
                 fminf(fmaxf((pz + 1.0f) * 0.5f, 0.0f), 1.0f)};

  float feat[32];
  const float2* emb2 = reinterpret_cast<const float2*>(emb);
#pragma unroll
  for (int l = 0; l < 16; ++l) {
    const int res = kRes[l];
    const unsigned mask = kMask[l];
    const float2* elvl = emb2 + kOff[l];
    float w0, w1, w2;
    unsigned g0, g1, g2;
    {
      const float s = pn[0] * (float)(res - 1);
      const float fg = floorf(s);
      w0 = s - fg; g0 = (unsigned)fg;
    }
    {
      const float s = pn[1] * (float)(res - 1);
      const float fg = floorf(s);
      w1 = s - fg; g1 = (unsigned)fg;
    }
    {
      const float s = pn[2] * (float)(res - 1);
      const float fg = floorf(s);
      w2 = s - fg; g2 = (unsigned)fg;
    }
    const unsigned rm = (unsigned)(res - 1);
    const unsigned g0p = (g0 + 1u > rm) ? rm : g0 + 1u;
    const unsigned g1p = (g1 + 1u > rm) ? rm : g1 + 1u;
    const unsigned g2p = (g2 + 1u > rm) ? rm : g2 + 1u;
    const unsigned hx0 = g0 * kP1, hx1 = g0p * kP1;
    const unsigned hy0 = g1 * kP2, hy1 = g1p * kP2;
    const unsigned hz0 = g2 * kP3, hz1 = g2p * kP3;
    float f0 = 0.0f, f1 = 0.0f;
#pragma unroll
    for (int c = 0; c < 8; ++c) {
      const bool bx = (c >> 2) & 1, by = (c >> 1) & 1, bz = c & 1;
      const unsigned h = ((bx ? hx1 : hx0) + (by ? hy1 : hy0) + (bz ? hz1 : hz0)) & mask;
      const float2 e = elvl[h];
      const float wp = (bx ? w0 : 1.0f - w0) * (by ? w1 : 1.0f - w1) * (bz ? w2 : 1.0f - w2);
      f0 = __builtin_fmaf(wp, e.x, f0);
      f1 = __builtin_fmaf(wp, e.y, f1);
    }
    feat[2 * l + 0] = f0;
    feat[2 * l + 1] = f1;
  }

  // ---- Density MLP ----
  float h0a[64];
  dense<32, 64, true>(feat, h0a, sW + 0, sW + 2048);
  float h1a[64];
  dense<64, 64, true>(h0a, h1a, sW + 2112, sW + 6208);
  float dens[16];
  dense<64, 16, false>(h1a, dens, sW + 6272, sW + 7296);
  const float sigma = dens[0];

  // ---- Phase 2 weights: color MLP (10563 floats, reuse same LDS) ----
  __syncthreads();
  copy_seg(sW + 0,     cw0, 1984, tid);
  copy_seg(sW + 1984,  cb0, 64, tid);
  copy_seg(sW + 2048,  cw1, 4096, tid);
  copy_seg(sW + 6144,  cb1, 64, tid);
  copy_seg(sW + 6208,  cw2, 4096, tid);
  copy_seg(sW + 10304, cb2, 64, tid);
  copy_seg(sW + 10368, cw3, 192, tid);
  copy_seg(sW + 10560, cb3, 3, tid);
  __syncthreads();

  // ---- SH degree-3 encode ----
  const float dxr = dirs[3 * i + 0], dyr = dirs[3 * i + 1], dzr = dirs[3 * i + 2];
  const float invn = 1.0f / sqrtf(dxr * dxr + dyr * dyr + dzr * dzr);
  const float x = dxr * invn, y = dyr * invn, z = dzr * invn;
  const float x2 = x * x, y2 = y * y, z2 = z * z;

  float cin[31];
#pragma unroll
  for (int j = 0; j < 15; ++j) cin[j] = dens[j + 1];
  cin[15] = 0.28209479177387814f;
  cin[16] = -0.48860251190291987f * y;
  cin[17] = 0.48860251190291987f * z;
  cin[18] = -0.48860251190291987f * x;
  cin[19] = 1.0925484305920792f * x * y;
  cin[20] = -1.0925484305920792f * y * z;
  cin[21] = 0.31539156525252005f * (2.0f * z2 - x2 - y2);
  cin[22] = -1.0925484305920792f * x * z;
  cin[23] = 0.5462742152960396f * (x2 - y2);
  cin[24] = -0.5900435899266435f * y * (3.0f * x2 - y2);
  cin[25] = 2.890611442640554f * x * y * z;
  cin[26] = -0.4570457994644658f * y * (4.0f * z2 - x2 - y2);
  cin[27] = 0.3731763325901154f * z * (2.0f * z2 - 3.0f * x2 - 3.0f * y2);
  cin[28] = -0.4570457994644658f * x * (4.0f * z2 - x2 - y2);
  cin[29] = 1.445305721320277f * z * (x2 - y2);
  cin[30] = -0.5900435899266435f * x * (x2 - 3.0f * y2);

  // ---- Color MLP ----
  float c0[64];
  dense<31, 64, true>(cin, c0, sW + 0, sW + 1984);
  float c1[64];
  dense<64, 64, true>(c0, c1, sW + 2048, sW + 6144);
  dense<64, 64, true>(c1, c0, sW + 6208, sW + 10304);
  float rgb[3];
  dense<64, 3, false>(c0, rgb, sW + 10368, sW + 10560);

  float4 o;
  o.x = sigma;
  o.y = 1.0f / (1.0f + __expf(-rgb[0]));
  o.z = 1.0f / (1.0f + __expf(-rgb[1]));
  o.w = 1.0f / (1.0f + __expf(-rgb[2]));
  reinterpret_cast<float4*>(out)[i] = o;
}

extern "C" void kernel_launch(void* const* d_in, const int* in_sizes, int n_in,
                              void* d_out, int out_size, void* d_ws, size_t ws_size,
                              hipStream_t stream) {
  const float* pos = (const float*)d_in[0];
  const float* dirs = (const float*)d_in[1];
  const float* emb = (const float*)d_in[2];
  const float* dw0 = (const float*)d_in[3];
  const float* db0 = (const float*)d_in[4];
  const float* dw1 = (const float*)d_in[5];
  const float* db1 = (const float*)d_in[6];
  const float* dw2 = (const float*)d_in[7];
  const float* db2 = (const float*)d_in[8];
  const float* cw0 = (const float*)d_in[9];
  const float* cb0 = (const float*)d_in[10];
  const float* cw1 = (const float*)d_in[11];
  const float* cb1 = (const float*)d_in[12];
  const float* cw2 = (const float*)d_in[13];
  const float* cb2 = (const float*)d_in[14];
  const float* cw3 = (const float*)d_in[15];
  const float* cb3 = (const float*)d_in[16];
  float* out = (float*)d_out;

  const int n = in_sizes[0] / 3;
  const int grid = (n + BLOCK - 1) / BLOCK;
  ngp_fused<<<grid, BLOCK, 0, stream>>>(pos, dirs, emb, dw0, db0, dw1, db1, dw2, db2,
                                        cw0, cb0, cw1, cb1, cw2, cb2, cw3, cb3, out, n);
}

// Round 2
// 1555.102 us; speedup vs baseline: 1.8547x; 1.8547x over previous
//
#include <hip/hip_runtime.h>

#define BLOCK 256

typedef _Float16 f16x8 __attribute__((ext_vector_type(8)));
typedef _Float16 f16x4 __attribute__((ext_vector_type(4)));
typedef float f32x4 __attribute__((ext_vector_type(4)));

// ---- Hash-grid compile-time tables -------------------------------------
constexpr unsigned kP1 = 73856093u, kP2 = 19349663u, kP3 = 83492791u;
constexpr int kRes[16] = {16, 32, 64, 128, 256, 512, 512, 512,
                          512, 512, 512, 512, 512, 512, 512, 512};
constexpr unsigned kMask[16] = {4095u, 32767u, 262143u, 524287u, 524287u, 524287u,
                                524287u, 524287u, 524287u, 524287u, 524287u, 524287u,
                                524287u, 524287u, 524287u, 524287u};
constexpr int kOff[16] = {0,       4096,    36864,   299008,  823296,  1347584,
                          1871872, 2396160, 2920448, 3444736, 3969024, 4493312,
                          5017600, 5541888, 6066176, 6590464};

// LDS act tile: [64 rows(points)][64 cols(features)] f16, XOR-swizzled.
__device__ __forceinline__ int swz(int row, int col) {
  return row * 64 + (col ^ ((row & 7) << 3));
}

// Pack W[Ksrc][Nsrc] fp32 row-major -> f16 packed [KP/8][NP][8];
// packed row k maps to src row (k - rowShift); out-of-range -> 0.
__device__ __forceinline__ void stage_w(_Float16* dst, const float* __restrict__ W,
                                        int Ksrc, int Nsrc, int KP, int NP, int rowShift,
                                        int tid) {
  const int total = KP * NP;
  for (int t = tid; t < total; t += BLOCK) {
    const int j = t & 7;
    const int n = (t >> 3) % NP;
    const int kb = t / (8 * NP);
    const int k = kb * 8 + j - rowShift;
    float v = 0.0f;
    if (k >= 0 && k < Ksrc && n < Nsrc) v = W[k * Nsrc + n];
    dst[t] = (_Float16)v;
  }
}

__device__ __forceinline__ void stage_b(float* dst, const float* __restrict__ B,
                                        int nsrc, int np, int tid) {
  for (int t = tid; t < np; t += BLOCK) dst[t] = (t < nsrc) ? B[t] : 0.0f;
}

// D[out 16*OT][pt 64] = W^T(out x K) * act^T(K x pt); KT = K/32.
// A-frag (W^T): lane holds row=out=(lane&15), k=(lane>>4)*8+j  -> packed read
// B-frag (act^T): lane holds col=pt=(lane&15), k=(lane>>4)*8+j -> act row read
template <int KT, int OT>
__device__ __forceinline__ void mfma_tiles(const _Float16* act, const _Float16* wp,
                                           int lane, f32x4 (&acc)[OT][4]) {
  const int lr = lane & 15, lg = lane >> 4;
  f16x8 bF[4][KT];
#pragma unroll
  for (int pt = 0; pt < 4; ++pt)
#pragma unroll
    for (int kf = 0; kf < KT; ++kf) {
      const int row = pt * 16 + lr;
      bF[pt][kf] = *reinterpret_cast<const f16x8*>(&act[swz(row, kf * 32 + lg * 8)]);
    }
#pragma unroll
  for (int ot = 0; ot < OT; ++ot)
#pragma unroll
    for (int pt = 0; pt < 4; ++pt) acc[ot][pt] = 0.0f;
#pragma unroll
  for (int ot = 0; ot < OT; ++ot) {
#pragma unroll
    for (int kf = 0; kf < KT; ++kf) {
      const f16x8 aF =
          *reinterpret_cast<const f16x8*>(&wp[((kf * 4 + lg) * (OT * 16) + ot * 16 + lr) * 8]);
#pragma unroll
      for (int pt = 0; pt < 4; ++pt)
        acc[ot][pt] = __builtin_amdgcn_mfma_f32_16x16x32_f16(aF, bF[pt][kf], acc[ot][pt], 0, 0, 0);
    }
  }
}

// bias-add + optional relu, write D back to act tile as f16 (8B stores).
template <int OT, bool RELU>
__device__ __forceinline__ void epilogue_act(const f32x4 (&acc)[OT][4], const float* bias,
                                             _Float16* act, int lane) {
  const int lr = lane & 15, lg = lane >> 4;
#pragma unroll
  for (int ot = 0; ot < OT; ++ot) {
    const float4 b4 = *reinterpret_cast<const float4*>(&bias[ot * 16 + lg * 4]);
#pragma unroll
    for (int pt = 0; pt < 4; ++pt) {
      const int row = pt * 16 + lr;
      float v0 = acc[ot][pt][0] + b4.x;
      float v1 = acc[ot][pt][1] + b4.y;
      float v2 = acc[ot][pt][2] + b4.z;
      float v3 = acc[ot][pt][3] + b4.w;
      if (RELU) {
        v0 = fmaxf(v0, 0.0f); v1 = fmaxf(v1, 0.0f);
        v2 = fmaxf(v2, 0.0f); v3 = fmaxf(v3, 0.0f);
      }
      f16x4 h;
      h[0] = (_Float16)v0; h[1] = (_Float16)v1; h[2] = (_Float16)v2; h[3] = (_Float16)v3;
      *reinterpret_cast<f16x4*>(&act[swz(row, ot * 16 + lg * 4)]) = h;
    }
  }
}

__global__ __launch_bounds__(BLOCK, 2) void ngp_mfma(
    const float* __restrict__ pos, const float* __restrict__ dirs, const float* __restrict__ emb,
    const float* __restrict__ dw0, const float* __restrict__ db0,
    const float* __restrict__ dw1, const float* __restrict__ db1,
    const float* __restrict__ dw2, const float* __restrict__ db2,
    const float* __restrict__ cw0, const float* __restrict__ cb0,
    const float* __restrict__ cw1, const float* __restrict__ cb1,
    const float* __restrict__ cw2, const float* __restrict__ cb2,
    const float* __restrict__ cw3, const float* __restrict__ cb3,
    float* __restrict__ out, int n) {
  __shared__ __align__(16) _Float16 sAct[4 * 4096];  // 4 waves x [64][64]
  __shared__ __align__(16) _Float16 sWp[11264];      // packed f16 weights (phase max)
  __shared__ __align__(16) float sB[208];            // fp32 biases

  const int tid = threadIdx.x;
  const int lane = tid & 63, wid = tid >> 6;
  const int lr = lane & 15, lg = lane >> 4;
  _Float16* myAct = &sAct[wid * 4096];
  const int blockBase = blockIdx.x * BLOCK;

  int i = blockBase + tid;
  if (i >= n) i = n - 1;

  // ---- Hash-grid encode (per-thread, 1 point) ----
  const float px = pos[3 * i + 0], py = pos[3 * i + 1], pz = pos[3 * i + 2];
  const float pn0 = fminf(fmaxf((px + 1.0f) * 0.5f, 0.0f), 1.0f);
  const float pn1 = fminf(fmaxf((py + 1.0f) * 0.5f, 0.0f), 1.0f);
  const float pn2 = fminf(fmaxf((pz + 1.0f) * 0.5f, 0.0f), 1.0f);

  float feat[32];
  const float2* emb2 = reinterpret_cast<const float2*>(emb);
#pragma unroll
  for (int l = 0; l < 16; ++l) {
    const int res = kRes[l];
    const unsigned mask = kMask[l];
    const float2* elvl = emb2 + kOff[l];
    float w0, w1, w2;
    unsigned g0, g1, g2;
    {
      const float s = pn0 * (float)(res - 1); const float fg = floorf(s);
      w0 = s - fg; g0 = (unsigned)fg;
    }
    {
      const float s = pn1 * (float)(res - 1); const float fg = floorf(s);
      w1 = s - fg; g1 = (unsigned)fg;
    }
    {
      const float s = pn2 * (float)(res - 1); const float fg = floorf(s);
      w2 = s - fg; g2 = (unsigned)fg;
    }
    const unsigned rm = (unsigned)(res - 1);
    const unsigned g0p = (g0 + 1u > rm) ? rm : g0 + 1u;
    const unsigned g1p = (g1 + 1u > rm) ? rm : g1 + 1u;
    const unsigned g2p = (g2 + 1u > rm) ? rm : g2 + 1u;
    const unsigned hx0 = g0 * kP1, hx1 = g0p * kP1;
    const unsigned hy0 = g1 * kP2, hy1 = g1p * kP2;
    const unsigned hz0 = g2 * kP3, hz1 = g2p * kP3;
    float f0 = 0.0f, f1 = 0.0f;
#pragma unroll
    for (int c = 0; c < 8; ++c) {
      const bool bx = (c >> 2) & 1, by = (c >> 1) & 1, bz = c & 1;
      const unsigned h = ((bx ? hx1 : hx0) + (by ? hy1 : hy0) + (bz ? hz1 : hz0)) & mask;
      const float2 e = elvl[h];
      const float wp = (bx ? w0 : 1.0f - w0) * (by ? w1 : 1.0f - w1) * (bz ? w2 : 1.0f - w2);
      f0 = __builtin_fmaf(wp, e.x, f0);
      f1 = __builtin_fmaf(wp, e.y, f1);
    }
    feat[2 * l + 0] = f0;
    feat[2 * l + 1] = f1;
  }

  // ---- SH deg-3 (into regs; LDS write deferred until density done) ----
  float sh[16];
  {
    const float dxr = dirs[3 * i + 0], dyr = dirs[3 * i + 1], dzr = dirs[3 * i + 2];
    const float invn = 1.0f / sqrtf(dxr * dxr + dyr * dyr + dzr * dzr);
    const float x = dxr * invn, y = dyr * invn, z = dzr * invn;
    const float x2 = x * x, y2 = y * y, z2 = z * z;
    sh[0] = 0.28209479177387814f;
    sh[1] = -0.48860251190291987f * y;
    sh[2] = 0.48860251190291987f * z;
    sh[3] = -0.48860251190291987f * x;
    sh[4] = 1.0925484305920792f * x * y;
    sh[5] = -1.0925484305920792f * y * z;
    sh[6] = 0.31539156525252005f * (2.0f * z2 - x2 - y2);
    sh[7] = -1.0925484305920792f * x * z;
    sh[8] = 0.5462742152960396f * (x2 - y2);
    sh[9] = -0.5900435899266435f * y * (3.0f * x2 - y2);
    sh[10] = 2.890611442640554f * x * y * z;
    sh[11] = -0.4570457994644658f * y * (4.0f * z2 - x2 - y2);
    sh[12] = 0.3731763325901154f * z * (2.0f * z2 - 3.0f * x2 - 3.0f * y2);
    sh[13] = -0.4570457994644658f * x * (4.0f * z2 - x2 - y2);
    sh[14] = 1.445305721320277f * z * (x2 - y2);
    sh[15] = -0.5900435899266435f * x * (x2 - 3.0f * y2);
  }

  // ---- feat -> act tile (cols 0..31), f16, swizzled 16B stores ----
#pragma unroll
  for (int cb = 0; cb < 4; ++cb) {
    f16x8 v;
#pragma unroll
    for (int j = 0; j < 8; ++j) v[j] = (_Float16)feat[cb * 8 + j];
    *reinterpret_cast<f16x8*>(&myAct[swz(lane, cb * 8)]) = v;
  }

  // ---- Phase-1 weight staging (density MLP) ----
  stage_w(sWp + 0, dw0, 32, 64, 32, 64, 0, tid);
  stage_w(sWp + 2048, dw1, 64, 64, 64, 64, 0, tid);
  stage_w(sWp + 6144, dw2, 64, 16, 64, 16, 0, tid);
  stage_b(sB + 0, db0, 64, 64, tid);
  stage_b(sB + 64, db1, 64, 64, tid);
  stage_b(sB + 128, db2, 16, 16, tid);
  __syncthreads();

  // ---- Density MLP ----
  {
    f32x4 acc[4][4];
    mfma_tiles<1, 4>(myAct, sWp + 0, lane, acc);
    epilogue_act<4, true>(acc, sB + 0, myAct, lane);
  }
  __syncthreads();
  {
    f32x4 acc[4][4];
    mfma_tiles<2, 4>(myAct, sWp + 2048, lane, acc);
    epilogue_act<4, true>(acc, sB + 64, myAct, lane);
  }
  __syncthreads();
  {
    f32x4 acc[1][4];
    mfma_tiles<2, 1>(myAct, sWp + 6144, lane, acc);
    const float4 b4 = *reinterpret_cast<const float4*>(&sB[128 + lg * 4]);
#pragma unroll
    for (int pt = 0; pt < 4; ++pt) {
      const int row = pt * 16 + lr;
      const int gpt = blockBase + wid * 64 + row;
      const float v0 = acc[0][pt][0] + b4.x;
      const float v1 = acc[0][pt][1] + b4.y;
      const float v2 = acc[0][pt][2] + b4.z;
      const float v3 = acc[0][pt][3] + b4.w;
      if (lg == 0) {
        if (gpt < n) out[gpt * 4] = v0;  // sigma
        myAct[swz(row, 1)] = (_Float16)v1;
        myAct[swz(row, 2)] = (_Float16)v2;
        myAct[swz(row, 3)] = (_Float16)v3;
      } else {
        f16x4 h;
        h[0] = (_Float16)v0; h[1] = (_Float16)v1; h[2] = (_Float16)v2; h[3] = (_Float16)v3;
        *reinterpret_cast<f16x4*>(&myAct[swz(row, lg * 4)]) = h;
      }
    }
  }

  // ---- SH -> act cols 16..31; col 0 = pad (weights row-shifted by 1) ----
  myAct[swz(lane, 0)] = (_Float16)0.0f;
  {
    f16x8 v0, v1;
#pragma unroll
    for (int j = 0; j < 8; ++j) { v0[j] = (_Float16)sh[j]; v1[j] = (_Float16)sh[8 + j]; }
    *reinterpret_cast<f16x8*>(&myAct[swz(lane, 16)]) = v0;
    *reinterpret_cast<f16x8*>(&myAct[swz(lane, 24)]) = v1;
  }
  __syncthreads();

  // ---- Phase-2 weight staging (color MLP; cw0 rows shifted +1, cw3 N-padded) ----
  stage_w(sWp + 0, cw0, 31, 64, 32, 64, 1, tid);
  stage_w(sWp + 2048, cw1, 64, 64, 64, 64, 0, tid);
  stage_w(sWp + 6144, cw2, 64, 64, 64, 64, 0, tid);
  stage_w(sWp + 10240, cw3, 64, 3, 64, 16, 0, tid);
  stage_b(sB + 0, cb0, 64, 64, tid);
  stage_b(sB + 64, cb1, 64, 64, tid);
  stage_b(sB + 128, cb2, 64, 64, tid);
  stage_b(sB + 192, cb3, 3, 16, tid);
  __syncthreads();

  // ---- Color MLP ----
  {
    f32x4 acc[4][4];
    mfma_tiles<1, 4>(myAct, sWp + 0, lane, acc);
    epilogue_act<4, true>(acc, sB + 0, myAct, lane);
  }
  __syncthreads();
  {
    f32x4 acc[4][4];
    mfma_tiles<2, 4>(myAct, sWp + 2048, lane, acc);
    epilogue_act<4, true>(acc, sB + 64, myAct, lane);
  }
  __syncthreads();
  {
    f32x4 acc[4][4];
    mfma_tiles<2, 4>(myAct, sWp + 6144, lane, acc);
    epilogue_act<4, true>(acc, sB + 128, myAct, lane);
  }
  __syncthreads();
  {
    f32x4 acc[1][4];
    mfma_tiles<2, 1>(myAct, sWp + 10240, lane, acc);
    if (lg == 0) {
      const float4 b4 = *reinterpret_cast<const float4*>(&sB[192]);
#pragma unroll
      for (int pt = 0; pt < 4; ++pt) {
        const int gpt = blockBase + wid * 64 + pt * 16 + lr;
        if (gpt < n) {
          out[gpt * 4 + 1] = 1.0f / (1.0f + __expf(-(acc[0][pt][0] + b4.x)));
          out[gpt * 4 + 2] = 1.0f / (1.0f + __expf(-(acc[0][pt][1] + b4.y)));
          out[gpt * 4 + 3] = 1.0f / (1.0f + __expf(-(acc[0][pt][2] + b4.z)));
        }
      }
    }
  }
}

extern "C" void kernel_launch(void* const* d_in, const int* in_sizes, int n_in,
                              void* d_out, int out_size, void* d_ws, size_t ws_size,
                              hipStream_t stream) {
  const float* pos = (const float*)d_in[0];
  const float* dirs = (const float*)d_in[1];
  const float* emb = (const float*)d_in[2];
  const float* dw0 = (const float*)d_in[3];
  const float* db0 = (const float*)d_in[4];
  const float* dw1 = (const float*)d_in[5];
  const float* db1 = (const float*)d_in[6];
  const float* dw2 = (const float*)d_in[7];
  const float* db2 = (const float*)d_in[8];
  const float* cw0 = (const float*)d_in[9];
  const float* cb0 = (const float*)d_in[10];
  const float* cw1 = (const float*)d_in[11];
  const float* cb1 = (const float*)d_in[12];
  const float* cw2 = (const float*)d_in[13];
  const float* cb2 = (const float*)d_in[14];
  const float* cw3 = (const float*)d_in[15];
  const float* cb3 = (const float*)d_in[16];
  float* out = (float*)d_out;

  const int n = in_sizes[0] / 3;
  const int grid = (n + BLOCK - 1) / BLOCK;
  ngp_mfma<<<grid, BLOCK, 0, stream>>>(pos, dirs, emb, dw0, db0, dw1, db1, dw2, db2,
                                       cw0, cb0, cw1, cb1, cw2, cb2, cw3, cb3, out, n);
}

// Round 3
// 634.767 us; speedup vs baseline: 4.5437x; 2.4499x over previous
//
#include <hip/hip_runtime.h>

#define BLOCK 256

typedef _Float16 f16x8 __attribute__((ext_vector_type(8)));
typedef _Float16 f16x4 __attribute__((ext_vector_type(4)));
typedef _Float16 f16x2 __attribute__((ext_vector_type(2)));
typedef float f32x4 __attribute__((ext_vector_type(4)));

// ---- Hash-grid compile-time tables -------------------------------------
constexpr unsigned kP1 = 73856093u, kP2 = 19349663u, kP3 = 83492791u;
constexpr int kRes[16] = {16, 32, 64, 128, 256, 512, 512, 512,
                          512, 512, 512, 512, 512, 512, 512, 512};
constexpr unsigned kMask[16] = {4095u, 32767u, 262143u, 524287u, 524287u, 524287u,
                                524287u, 524287u, 524287u, 524287u, 524287u, 524287u,
                                524287u, 524287u, 524287u, 524287u};
constexpr int kOff[16] = {0,       4096,    36864,   299008,  823296,  1347584,
                          1871872, 2396160, 2920448, 3444736, 3969024, 4493312,
                          5017600, 5541888, 6066176, 6590464};

// =========================================================================
// Kernel 0: convert fp32 embedding table -> f16 (halves per-level table to
// 2 MB so one level fits comfortably in a 4 MB per-XCD L2)
// =========================================================================
__global__ __launch_bounds__(BLOCK) void cvt_emb(const float2* __restrict__ emb,
                                                 f16x2* __restrict__ tab, int total) {
  const int i = blockIdx.x * BLOCK + threadIdx.x;
  if (i < total) {
    const float2 e = emb[i];
    f16x2 h;
    h.x = (_Float16)e.x;
    h.y = (_Float16)e.y;
    tab[i] = h;
  }
}

// =========================================================================
// Kernel 1: level-major hash gather. grid = 16 levels x chunks; all blocks
// of one level are dispatched contiguously -> each XCD works one level at a
// time -> that level's 2 MB f16 table is L2-resident.
// feats layout: [level][point] as f16x2 (dword), fully coalesced stores.
// =========================================================================
__global__ __launch_bounds__(BLOCK) void hash_gather(const float* __restrict__ pos,
                                                     const f16x2* __restrict__ tab,
                                                     f16x2* __restrict__ feats, int n,
                                                     int chunks) {
  const int b = blockIdx.x;
  const int level = b / chunks;
  const int pt = (b - level * chunks) * BLOCK + threadIdx.x;
  if (pt >= n) return;

  const float px = pos[3 * pt + 0], py = pos[3 * pt + 1], pz = pos[3 * pt + 2];
  const float pn0 = fminf(fmaxf((px + 1.0f) * 0.5f, 0.0f), 1.0f);
  const float pn1 = fminf(fmaxf((py + 1.0f) * 0.5f, 0.0f), 1.0f);
  const float pn2 = fminf(fmaxf((pz + 1.0f) * 0.5f, 0.0f), 1.0f);

  const int res = kRes[level];
  const unsigned mask = kMask[level];
  const f16x2* t = tab + kOff[level];

  float w0, w1, w2;
  unsigned g0, g1, g2;
  {
    const float s = pn0 * (float)(res - 1); const float fg = floorf(s);
    w0 = s - fg; g0 = (unsigned)fg;
  }
  {
    const float s = pn1 * (float)(res - 1); const float fg = floorf(s);
    w1 = s - fg; g1 = (unsigned)fg;
  }
  {
    const float s = pn2 * (float)(res - 1); const float fg = floorf(s);
    w2 = s - fg; g2 = (unsigned)fg;
  }
  const unsigned rm = (unsigned)(res - 1);
  const unsigned g0p = (g0 + 1u > rm) ? rm : g0 + 1u;
  const unsigned g1p = (g1 + 1u > rm) ? rm : g1 + 1u;
  const unsigned g2p = (g2 + 1u > rm) ? rm : g2 + 1u;
  const unsigned hx0 = g0 * kP1, hx1 = g0p * kP1;
  const unsigned hy0 = g1 * kP2, hy1 = g1p * kP2;
  const unsigned hz0 = g2 * kP3, hz1 = g2p * kP3;

  float f0 = 0.0f, f1 = 0.0f;
#pragma unroll
  for (int c = 0; c < 8; ++c) {
    const bool bx = (c >> 2) & 1, by = (c >> 1) & 1, bz = c & 1;
    const unsigned h = ((bx ? hx1 : hx0) + (by ? hy1 : hy0) + (bz ? hz1 : hz0)) & mask;
    const f16x2 e = t[h];
    const float wp = (bx ? w0 : 1.0f - w0) * (by ? w1 : 1.0f - w1) * (bz ? w2 : 1.0f - w2);
    f0 = __builtin_fmaf(wp, (float)e.x, f0);
    f1 = __builtin_fmaf(wp, (float)e.y, f1);
  }
  f16x2 o;
  o.x = (_Float16)f0;
  o.y = (_Float16)f1;
  feats[(size_t)level * n + pt] = o;
}

// =========================================================================
// Shared MFMA machinery (verified in R2)
// =========================================================================
__device__ __forceinline__ int swz(int row, int col) {
  return row * 64 + (col ^ ((row & 7) << 3));
}

__device__ __forceinline__ void stage_w(_Float16* dst, const float* __restrict__ W,
                                        int Ksrc, int Nsrc, int KP, int NP, int rowShift,
                                        int tid) {
  const int total = KP * NP;
  for (int t = tid; t < total; t += BLOCK) {
    const int j = t & 7;
    const int nn = (t >> 3) % NP;
    const int kb = t / (8 * NP);
    const int k = kb * 8 + j - rowShift;
    float v = 0.0f;
    if (k >= 0 && k < Ksrc && nn < Nsrc) v = W[k * Nsrc + nn];
    dst[t] = (_Float16)v;
  }
}

__device__ __forceinline__ void stage_b(float* dst, const float* __restrict__ B,
                                        int nsrc, int np, int tid) {
  for (int t = tid; t < np; t += BLOCK) dst[t] = (t < nsrc) ? B[t] : 0.0f;
}

template <int KT, int OT>
__device__ __forceinline__ void mfma_tiles(const _Float16* act, const _Float16* wp,
                                           int lane, f32x4 (&acc)[OT][4]) {
  const int lr = lane & 15, lg = lane >> 4;
  f16x8 bF[4][KT];
#pragma unroll
  for (int pt = 0; pt < 4; ++pt)
#pragma unroll
    for (int kf = 0; kf < KT; ++kf) {
      const int row = pt * 16 + lr;
      bF[pt][kf] = *reinterpret_cast<const f16x8*>(&act[swz(row, kf * 32 + lg * 8)]);
    }
#pragma unroll
  for (int ot = 0; ot < OT; ++ot)
#pragma unroll
    for (int pt = 0; pt < 4; ++pt) acc[ot][pt] = 0.0f;
#pragma unroll
  for (int ot = 0; ot < OT; ++ot) {
#pragma unroll
    for (int kf = 0; kf < KT; ++kf) {
      const f16x8 aF =
          *reinterpret_cast<const f16x8*>(&wp[((kf * 4 + lg) * (OT * 16) + ot * 16 + lr) * 8]);
#pragma unroll
      for (int pt = 0; pt < 4; ++pt)
        acc[ot][pt] = __builtin_amdgcn_mfma_f32_16x16x32_f16(aF, bF[pt][kf], acc[ot][pt], 0, 0, 0);
    }
  }
}

template <int OT, bool RELU>
__device__ __forceinline__ void epilogue_act(const f32x4 (&acc)[OT][4], const float* bias,
                                             _Float16* act, int lane) {
  const int lr = lane & 15, lg = lane >> 4;
#pragma unroll
  for (int ot = 0; ot < OT; ++ot) {
    const float4 b4 = *reinterpret_cast<const float4*>(&bias[ot * 16 + lg * 4]);
#pragma unroll
    for (int pt = 0; pt < 4; ++pt) {
      const int row = pt * 16 + lr;
      float v0 = acc[ot][pt][0] + b4.x;
      float v1 = acc[ot][pt][1] + b4.y;
      float v2 = acc[ot][pt][2] + b4.z;
      float v3 = acc[ot][pt][3] + b4.w;
      if (RELU) {
        v0 = fmaxf(v0, 0.0f); v1 = fmaxf(v1, 0.0f);
        v2 = fmaxf(v2, 0.0f); v3 = fmaxf(v3, 0.0f);
      }
      f16x4 h;
      h[0] = (_Float16)v0; h[1] = (_Float16)v1; h[2] = (_Float16)v2; h[3] = (_Float16)v3;
      *reinterpret_cast<f16x4*>(&act[swz(row, ot * 16 + lg * 4)]) = h;
    }
  }
}

// =========================================================================
// Kernel 2: fused MLPs, layer-0 B-fragments read directly from feat buffer
// =========================================================================
__global__ __launch_bounds__(BLOCK, 2) void ngp_mlp(
    const unsigned* __restrict__ feats, const float* __restrict__ dirs,
    const float* __restrict__ dw0, const float* __restrict__ db0,
    const float* __restrict__ dw1, const float* __restrict__ db1,
    const float* __restrict__ dw2, const float* __restrict__ db2,
    const float* __restrict__ cw0, const float* __restrict__ cb0,
    const float* __restrict__ cw1, const float* __restrict__ cb1,
    const float* __restrict__ cw2, const float* __restrict__ cb2,
    const float* __restrict__ cw3, const float* __restrict__ cb3,
    float* __restrict__ out, int n) {
  __shared__ __align__(16) _Float16 sAct[4 * 4096];
  __shared__ __align__(16) _Float16 sWp[11264];
  __shared__ __align__(16) float sB[208];

  const int tid = threadIdx.x;
  const int lane = tid & 63, wid = tid >> 6;
  const int lr = lane & 15, lg = lane >> 4;
  _Float16* myAct = &sAct[wid * 4096];
  const int blockBase = blockIdx.x * BLOCK;
  const int base64 = blockBase + wid * 64;

  int i = blockBase + tid;
  if (i >= n) i = n - 1;

  // ---- SH deg-3 into regs ----
  float sh[16];
  {
    const float dxr = dirs[3 * i + 0], dyr = dirs[3 * i + 1], dzr = dirs[3 * i + 2];
    const float invn = 1.0f / sqrtf(dxr * dxr + dyr * dyr + dzr * dzr);
    const float x = dxr * invn, y = dyr * invn, z = dzr * invn;
    const float x2 = x * x, y2 = y * y, z2 = z * z;
    sh[0] = 0.28209479177387814f;
    sh[1] = -0.48860251190291987f * y;
    sh[2] = 0.48860251190291987f * z;
    sh[3] = -0.48860251190291987f * x;
    sh[4] = 1.0925484305920792f * x * y;
    sh[5] = -1.0925484305920792f * y * z;
    sh[6] = 0.31539156525252005f * (2.0f * z2 - x2 - y2);
    sh[7] = -1.0925484305920792f * x * z;
    sh[8] = 0.5462742152960396f * (x2 - y2);
    sh[9] = -0.5900435899266435f * y * (3.0f * x2 - y2);
    sh[10] = 2.890611442640554f * x * y * z;
    sh[11] = -0.4570457994644658f * y * (4.0f * z2 - x2 - y2);
    sh[12] = 0.3731763325901154f * z * (2.0f * z2 - 3.0f * x2 - 3.0f * y2);
    sh[13] = -0.4570457994644658f * x * (4.0f * z2 - x2 - y2);
    sh[14] = 1.445305721320277f * z * (x2 - y2);
    sh[15] = -0.5900435899266435f * x * (x2 - 3.0f * y2);
  }

  // ---- Phase-1 weight staging (density MLP) ----
  stage_w(sWp + 0, dw0, 32, 64, 32, 64, 0, tid);
  stage_w(sWp + 2048, dw1, 64, 64, 64, 64, 0, tid);
  stage_w(sWp + 6144, dw2, 64, 16, 64, 16, 0, tid);
  stage_b(sB + 0, db0, 64, 64, tid);
  stage_b(sB + 64, db1, 64, 64, tid);
  stage_b(sB + 128, db2, 16, 16, tid);
  __syncthreads();

  // ---- Density layer 0: B-frags straight from global feat buffer ----
  {
    f32x4 acc[4][4];
    {
      f16x8 bF[4];
#pragma unroll
      for (int pt = 0; pt < 4; ++pt) {
        int gpt = base64 + pt * 16 + lr;
        if (gpt >= n) gpt = n - 1;
        union { unsigned u[4]; f16x8 v; } cv;
#pragma unroll
        for (int m = 0; m < 4; ++m) cv.u[m] = feats[(unsigned)(4 * lg + m) * (unsigned)n + gpt];
        bF[pt] = cv.v;
      }
#pragma unroll
      for (int ot = 0; ot < 4; ++ot)
#pragma unroll
        for (int pt = 0; pt < 4; ++pt) acc[ot][pt] = 0.0f;
#pragma unroll
      for (int ot = 0; ot < 4; ++ot) {
        const f16x8 aF = *reinterpret_cast<const f16x8*>(&sWp[(lg * 64 + ot * 16 + lr) * 8]);
#pragma unroll
        for (int pt = 0; pt < 4; ++pt)
          acc[ot][pt] = __builtin_amdgcn_mfma_f32_16x16x32_f16(aF, bF[pt], acc[ot][pt], 0, 0, 0);
      }
    }
    epilogue_act<4, true>(acc, sB + 0, myAct, lane);
  }
  {
    f32x4 acc[4][4];
    mfma_tiles<2, 4>(myAct, sWp + 2048, lane, acc);
    epilogue_act<4, true>(acc, sB + 64, myAct, lane);
  }
  {
    f32x4 acc[1][4];
    mfma_tiles<2, 1>(myAct, sWp + 6144, lane, acc);
    const float4 b4 = *reinterpret_cast<const float4*>(&sB[128 + lg * 4]);
#pragma unroll
    for (int pt = 0; pt < 4; ++pt) {
      const int row = pt * 16 + lr;
      const int gpt = base64 + row;
      const float v0 = acc[0][pt][0] + b4.x;
      const float v1 = acc[0][pt][1] + b4.y;
      const float v2 = acc[0][pt][2] + b4.z;
      const float v3 = acc[0][pt][3] + b4.w;
      if (lg == 0) {
        if (gpt < n) out[gpt * 4] = v0;  // sigma
        myAct[swz(row, 1)] = (_Float16)v1;
        myAct[swz(row, 2)] = (_Float16)v2;
        myAct[swz(row, 3)] = (_Float16)v3;
      } else {
        f16x4 h;
        h[0] = (_Float16)v0; h[1] = (_Float16)v1; h[2] = (_Float16)v2; h[3] = (_Float16)v3;
        *reinterpret_cast<f16x4*>(&myAct[swz(row, lg * 4)]) = h;
      }
    }
  }

  // ---- SH -> act cols 16..31; col 0 = pad (cw0 rows shifted by 1) ----
  myAct[swz(lane, 0)] = (_Float16)0.0f;
  {
    f16x8 v0, v1;
#pragma unroll
    for (int j = 0; j < 8; ++j) { v0[j] = (_Float16)sh[j]; v1[j] = (_Float16)sh[8 + j]; }
    *reinterpret_cast<f16x8*>(&myAct[swz(lane, 16)]) = v0;
    *reinterpret_cast<f16x8*>(&myAct[swz(lane, 24)]) = v1;
  }
  __syncthreads();  // all waves done with phase-1 weights

  // ---- Phase-2 weight staging (color MLP) ----
  stage_w(sWp + 0, cw0, 31, 64, 32, 64, 1, tid);
  stage_w(sWp + 2048, cw1, 64, 64, 64, 64, 0, tid);
  stage_w(sWp + 6144, cw2, 64, 64, 64, 64, 0, tid);
  stage_w(sWp + 10240, cw3, 64, 3, 64, 16, 0, tid);
  stage_b(sB + 0, cb0, 64, 64, tid);
  stage_b(sB + 64, cb1, 64, 64, tid);
  stage_b(sB + 128, cb2, 64, 64, tid);
  stage_b(sB + 192, cb3, 3, 16, tid);
  __syncthreads();

  // ---- Color MLP (no cross-wave deps -> no barriers between layers) ----
  {
    f32x4 acc[4][4];
    mfma_tiles<1, 4>(myAct, sWp + 0, lane, acc);
    epilogue_act<4, true>(acc, sB + 0, myAct, lane);
  }
  {
    f32x4 acc[4][4];
    mfma_tiles<2, 4>(myAct, sWp + 2048, lane, acc);
    epilogue_act<4, true>(acc, sB + 64, myAct, lane);
  }
  {
    f32x4 acc[4][4];
    mfma_tiles<2, 4>(myAct, sWp + 6144, lane, acc);
    epilogue_act<4, true>(acc, sB + 128, myAct, lane);
  }
  {
    f32x4 acc[1][4];
    mfma_tiles<2, 1>(myAct, sWp + 10240, lane, acc);
    if (lg == 0) {
      const float4 b4 = *reinterpret_cast<const float4*>(&sB[192]);
#pragma unroll
      for (int pt = 0; pt < 4; ++pt) {
        const int gpt = base64 + pt * 16 + lr;
        if (gpt < n) {
          out[gpt * 4 + 1] = 1.0f / (1.0f + __expf(-(acc[0][pt][0] + b4.x)));
          out[gpt * 4 + 2] = 1.0f / (1.0f + __expf(-(acc[0][pt][1] + b4.y)));
          out[gpt * 4 + 3] = 1.0f / (1.0f + __expf(-(acc[0][pt][2] + b4.z)));
        }
      }
    }
  }
}

// =========================================================================
// Fallback: R2's proven fused kernel (used if d_ws is too small)
// =========================================================================
__global__ __launch_bounds__(BLOCK, 2) void ngp_mfma(
    const float* __restrict__ pos, const float* __restrict__ dirs, const float* __restrict__ emb,
    const float* __restrict__ dw0, const float* __restrict__ db0,
    const float* __restrict__ dw1, const float* __restrict__ db1,
    const float* __restrict__ dw2, const float* __restrict__ db2,
    const float* __restrict__ cw0, const float* __restrict__ cb0,
    const float* __restrict__ cw1, const float* __restrict__ cb1,
    const float* __restrict__ cw2, const float* __restrict__ cb2,
    const float* __restrict__ cw3, const float* __restrict__ cb3,
    float* __restrict__ out, int n) {
  __shared__ __align__(16) _Float16 sAct[4 * 4096];
  __shared__ __align__(16) _Float16 sWp[11264];
  __shared__ __align__(16) float sB[208];

  const int tid = threadIdx.x;
  const int lane = tid & 63, wid = tid >> 6;
  const int lr = lane & 15, lg = lane >> 4;
  _Float16* myAct = &sAct[wid * 4096];
  const int blockBase = blockIdx.x * BLOCK;

  int i = blockBase + tid;
  if (i >= n) i = n - 1;

  const float px = pos[3 * i + 0], py = pos[3 * i + 1], pz = pos[3 * i + 2];
  const float pn0 = fminf(fmaxf((px + 1.0f) * 0.5f, 0.0f), 1.0f);
  const float pn1 = fminf(fmaxf((py + 1.0f) * 0.5f, 0.0f), 1.0f);
  const float pn2 = fminf(fmaxf((pz + 1.0f) * 0.5f, 0.0f), 1.0f);

  float feat[32];
  const float2* emb2 = reinterpret_cast<const float2*>(emb);
#pragma unroll
  for (int l = 0; l < 16; ++l) {
    const int res = kRes[l];
    const unsigned mask = kMask[l];
    const float2* elvl = emb2 + kOff[l];
    float w0, w1, w2;
    unsigned g0, g1, g2;
    { const float s = pn0 * (float)(res - 1); const float fg = floorf(s); w0 = s - fg; g0 = (unsigned)fg; }
    { const float s = pn1 * (float)(res - 1); const float fg = floorf(s); w1 = s - fg; g1 = (unsigned)fg; }
    { const float s = pn2 * (float)(res - 1); const float fg = floorf(s); w2 = s - fg; g2 = (unsigned)fg; }
    const unsigned rm = (unsigned)(res - 1);
    const unsigned g0p = (g0 + 1u > rm) ? rm : g0 + 1u;
    const unsigned g1p = (g1 + 1u > rm) ? rm : g1 + 1u;
    const unsigned g2p = (g2 + 1u > rm) ? rm : g2 + 1u;
    const unsigned hx0 = g0 * kP1, hx1 = g0p * kP1;
    const unsigned hy0 = g1 * kP2, hy1 = g1p * kP2;
    const unsigned hz0 = g2 * kP3, hz1 = g2p * kP3;
    float f0 = 0.0f, f1 = 0.0f;
#pragma unroll
    for (int c = 0; c < 8; ++c) {
      const bool bx = (c >> 2) & 1, by = (c >> 1) & 1, bz = c & 1;
      const unsigned h = ((bx ? hx1 : hx0) + (by ? hy1 : hy0) + (bz ? hz1 : hz0)) & mask;
      const float2 e = elvl[h];
      const float wp = (bx ? w0 : 1.0f - w0) * (by ? w1 : 1.0f - w1) * (bz ? w2 : 1.0f - w2);
      f0 = __builtin_fmaf(wp, e.x, f0);
      f1 = __builtin_fmaf(wp, e.y, f1);
    }
    feat[2 * l + 0] = f0;
    feat[2 * l + 1] = f1;
  }

  float sh[16];
  {
    const float dxr = dirs[3 * i + 0], dyr = dirs[3 * i + 1], dzr = dirs[3 * i + 2];
    const float invn = 1.0f / sqrtf(dxr * dxr + dyr * dyr + dzr * dzr);
    const float x = dxr * invn, y = dyr * invn, z = dzr * invn;
    const float x2 = x * x, y2 = y * y, z2 = z * z;
    sh[0] = 0.28209479177387814f;
    sh[1] = -0.48860251190291987f * y;
    sh[2] = 0.48860251190291987f * z;
    sh[3] = -0.48860251190291987f * x;
    sh[4] = 1.0925484305920792f * x * y;
    sh[5] = -1.0925484305920792f * y * z;
    sh[6] = 0.31539156525252005f * (2.0f * z2 - x2 - y2);
    sh[7] = -1.0925484305920792f * x * z;
    sh[8] = 0.5462742152960396f * (x2 - y2);
    sh[9] = -0.5900435899266435f * y * (3.0f * x2 - y2);
    sh[10] = 2.890611442640554f * x * y * z;
    sh[11] = -0.4570457994644658f * y * (4.0f * z2 - x2 - y2);
    sh[12] = 0.3731763325901154f * z * (2.0f * z2 - 3.0f * x2 - 3.0f * y2);
    sh[13] = -0.4570457994644658f * x * (4.0f * z2 - x2 - y2);
    sh[14] = 1.445305721320277f * z * (x2 - y2);
    sh[15] = -0.5900435899266435f * x * (x2 - 3.0f * y2);
  }

#pragma unroll
  for (int cb = 0; cb < 4; ++cb) {
    f16x8 v;
#pragma unroll
    for (int j = 0; j < 8; ++j) v[j] = (_Float16)feat[cb * 8 + j];
    *reinterpret_cast<f16x8*>(&myAct[swz(lane, cb * 8)]) = v;
  }

  stage_w(sWp + 0, dw0, 32, 64, 32, 64, 0, tid);
  stage_w(sWp + 2048, dw1, 64, 64, 64, 64, 0, tid);
  stage_w(sWp + 6144, dw2, 64, 16, 64, 16, 0, tid);
  stage_b(sB + 0, db0, 64, 64, tid);
  stage_b(sB + 64, db1, 64, 64, tid);
  stage_b(sB + 128, db2, 16, 16, tid);
  __syncthreads();

  {
    f32x4 acc[4][4];
    mfma_tiles<1, 4>(myAct, sWp + 0, lane, acc);
    epilogue_act<4, true>(acc, sB + 0, myAct, lane);
  }
  {
    f32x4 acc[4][4];
    mfma_tiles<2, 4>(myAct, sWp + 2048, lane, acc);
    epilogue_act<4, true>(acc, sB + 64, myAct, lane);
  }
  {
    f32x4 acc[1][4];
    mfma_tiles<2, 1>(myAct, sWp + 6144, lane, acc);
    const float4 b4 = *reinterpret_cast<const float4*>(&sB[128 + lg * 4]);
#pragma unroll
    for (int pt = 0; pt < 4; ++pt) {
      const int row = pt * 16 + lr;
      const int gpt = blockBase + wid * 64 + row;
      const float v0 = acc[0][pt][0] + b4.x;
      const float v1 = acc[0][pt][1] + b4.y;
      const float v2 = acc[0][pt][2] + b4.z;
      const float v3 = acc[0][pt][3] + b4.w;
      if (lg == 0) {
        if (gpt < n) out[gpt * 4] = v0;
        myAct[swz(row, 1)] = (_Float16)v1;
        myAct[swz(row, 2)] = (_Float16)v2;
        myAct[swz(row, 3)] = (_Float16)v3;
      } else {
        f16x4 h;
        h[0] = (_Float16)v0; h[1] = (_Float16)v1; h[2] = (_Float16)v2; h[3] = (_Float16)v3;
        *reinterpret_cast<f16x4*>(&myAct[swz(row, lg * 4)]) = h;
      }
    }
  }

  myAct[swz(lane, 0)] = (_Float16)0.0f;
  {
    f16x8 v0, v1;
#pragma unroll
    for (int j = 0; j < 8; ++j) { v0[j] = (_Float16)sh[j]; v1[j] = (_Float16)sh[8 + j]; }
    *reinterpret_cast<f16x8*>(&myAct[swz(lane, 16)]) = v0;
    *reinterpret_cast<f16x8*>(&myAct[swz(lane, 24)]) = v1;
  }
  __syncthreads();

  stage_w(sWp + 0, cw0, 31, 64, 32, 64, 1, tid);
  stage_w(sWp + 2048, cw1, 64, 64, 64, 64, 0, tid);
  stage_w(sWp + 6144, cw2, 64, 64, 64, 64, 0, tid);
  stage_w(sWp + 10240, cw3, 64, 3, 64, 16, 0, tid);
  stage_b(sB + 0, cb0, 64, 64, tid);
  stage_b(sB + 64, cb1, 64, 64, tid);
  stage_b(sB + 128, cb2, 64, 64, tid);
  stage_b(sB + 192, cb3, 3, 16, tid);
  __syncthreads();

  {
    f32x4 acc[4][4];
    mfma_tiles<1, 4>(myAct, sWp + 0, lane, acc);
    epilogue_act<4, true>(acc, sB + 0, myAct, lane);
  }
  {
    f32x4 acc[4][4];
    mfma_tiles<2, 4>(myAct, sWp + 2048, lane, acc);
    epilogue_act<4, true>(acc, sB + 64, myAct, lane);
  }
  {
    f32x4 acc[4][4];
    mfma_tiles<2, 4>(myAct, sWp + 6144, lane, acc);
    epilogue_act<4, true>(acc, sB + 128, myAct, lane);
  }
  {
    f32x4 acc[1][4];
    mfma_tiles<2, 1>(myAct, sWp + 10240, lane, acc);
    if (lg == 0) {
      const float4 b4 = *reinterpret_cast<const float4*>(&sB[192]);
#pragma unroll
      for (int pt = 0; pt < 4; ++pt) {
        const int gpt = blockBase + wid * 64 + pt * 16 + lr;
        if (gpt < n) {
          out[gpt * 4 + 1] = 1.0f / (1.0f + __expf(-(acc[0][pt][0] + b4.x)));
          out[gpt * 4 + 2] = 1.0f / (1.0f + __expf(-(acc[0][pt][1] + b4.y)));
          out[gpt * 4 + 3] = 1.0f / (1.0f + __expf(-(acc[0][pt][2] + b4.z)));
        }
      }
    }
  }
}

extern "C" void kernel_launch(void* const* d_in, const int* in_sizes, int n_in,
                              void* d_out, int out_size, void* d_ws, size_t ws_size,
                              hipStream_t stream) {
  const float* pos = (const float*)d_in[0];
  const float* dirs = (const float*)d_in[1];
  const float* emb = (const float*)d_in[2];
  const float* dw0 = (const float*)d_in[3];
  const float* db0 = (const float*)d_in[4];
  const float* dw1 = (const float*)d_in[5];
  const float* db1 = (const float*)d_in[6];
  const float* dw2 = (const float*)d_in[7];
  const float* db2 = (const float*)d_in[8];
  const float* cw0 = (const float*)d_in[9];
  const float* cb0 = (const float*)d_in[10];
  const float* cw1 = (const float*)d_in[11];
  const float* cb1 = (const float*)d_in[12];
  const float* cw2 = (const float*)d_in[13];
  const float* cb2 = (const float*)d_in[14];
  const float* cw3 = (const float*)d_in[15];
  const float* cb3 = (const float*)d_in[16];
  float* out = (float*)d_out;

  const int n = in_sizes[0] / 3;
  const int nTab = in_sizes[2] / 2;  // embedding entries (float2 each)
  const size_t tabBytes = (size_t)nTab * 4;            // f16x2 per entry
  const size_t featBytes = (size_t)16 * (size_t)n * 4; // [level][pt] f16x2
  const size_t need = tabBytes + featBytes;
  const int grid = (n + BLOCK - 1) / BLOCK;

  if (ws_size >= need) {
    f16x2* tab = (f16x2*)d_ws;
    f16x2* feats = (f16x2*)((char*)d_ws + tabBytes);
    const int chunks = grid;
    cvt_emb<<<(nTab + BLOCK - 1) / BLOCK, BLOCK, 0, stream>>>(
        (const float2*)emb, tab, nTab);
    hash_gather<<<16 * chunks, BLOCK, 0, stream>>>(pos, tab, feats, n, chunks);
    ngp_mlp<<<grid, BLOCK, 0, stream>>>((const unsigned*)feats, dirs, dw0, db0, dw1, db1,
                                        dw2, db2, cw0, cb0, cw1, cb1, cw2, cb2, cw3, cb3,
                                        out, n);
  } else {
    ngp_mfma<<<grid, BLOCK, 0, stream>>>(pos, dirs, emb, dw0, db0, dw1, db1, dw2, db2,
                                         cw0, cb0, cw1, cb1, cw2, cb2, cw3, cb3, out, n);
  }
}

// Round 4
// 434.405 us; speedup vs baseline: 6.6394x; 1.4612x over previous
//
#include <hip/hip_runtime.h>

#define BLOCK 256

typedef _Float16 f16x8 __attribute__((ext_vector_type(8)));
typedef _Float16 f16x4 __attribute__((ext_vector_type(4)));
typedef _Float16 f16x2 __attribute__((ext_vector_type(2)));
typedef float f32x4 __attribute__((ext_vector_type(4)));

// ---- Hash-grid compile-time tables -------------------------------------
constexpr unsigned kP1 = 73856093u, kP2 = 19349663u, kP3 = 83492791u;
constexpr int kRes[16] = {16, 32, 64, 128, 256, 512, 512, 512,
                          512, 512, 512, 512, 512, 512, 512, 512};
constexpr unsigned kMask[16] = {4095u, 32767u, 262143u, 524287u, 524287u, 524287u,
                                524287u, 524287u, 524287u, 524287u, 524287u, 524287u,
                                524287u, 524287u, 524287u, 524287u};
constexpr int kOff[16] = {0,       4096,    36864,   299008,  823296,  1347584,
                          1871872, 2396160, 2920448, 3444736, 3969024, 4493312,
                          5017600, 5541888, 6066176, 6590464};
constexpr int kNumFine = 11;        // levels 5..15 share res=512, size=2^19
constexpr int kFineEntries = 524288;
constexpr int kSmallEntries = 1347584;  // sum of level 0..4 sizes (= kOff[5])

union U32F16 { unsigned u; f16x2 h; };

// =========================================================================
// Kernel 0: fp32 embedding -> f16 (levels 0..4 region only in tier-1)
// =========================================================================
__global__ __launch_bounds__(BLOCK) void cvt_emb(const float2* __restrict__ emb,
                                                 f16x2* __restrict__ tab, int total) {
  const int i = blockIdx.x * BLOCK + threadIdx.x;
  if (i < total) {
    const float2 e = emb[i];
    f16x2 h;
    h.x = (_Float16)e.x;
    h.y = (_Float16)e.y;
    tab[i] = h;
  }
}

// =========================================================================
// Kernel 0b: build interleaved fine table R[h] = 64-B row, dword j (j<11)
// = f16x2 of level 5+j at entry h. One 64-B row per hash index.
// thread (row, j): j = tid&3 writes dwords 4j..4j+3 -> coalesced dwordx4.
// =========================================================================
__global__ __launch_bounds__(BLOCK) void build_R(const float2* __restrict__ emb,
                                                 uint4* __restrict__ R) {
  const int tid = threadIdx.x;
  const int j = tid & 3;
  const int row = blockIdx.x * 64 + (tid >> 2);
  unsigned vv[4];
#pragma unroll
  for (int m = 0; m < 4; ++m) {
    const int lvl = 4 * j + m;
    unsigned u = 0;
    if (lvl < kNumFine) {
      const float2 e = emb[kOff[5 + lvl] + row];
      U32F16 cv;
      cv.h.x = (_Float16)e.x;
      cv.h.y = (_Float16)e.y;
      u = cv.u;
    }
    vv[m] = u;
  }
  uint4 v;
  v.x = vv[0]; v.y = vv[1]; v.z = vv[2]; v.w = vv[3];
  R[row * 4 + j] = v;
}

// =========================================================================
// Kernel 1: level-major hash gather for levels 0..4 (small, L2-resident)
// =========================================================================
__global__ __launch_bounds__(BLOCK) void hash_gather(const float* __restrict__ pos,
                                                     const f16x2* __restrict__ tab,
                                                     f16x2* __restrict__ feats, int n,
                                                     int chunks) {
  const int b = blockIdx.x;
  const int level = b / chunks;
  const int pt = (b - level * chunks) * BLOCK + threadIdx.x;
  if (pt >= n) return;

  const float px = pos[3 * pt + 0], py = pos[3 * pt + 1], pz = pos[3 * pt + 2];
  const float pn0 = fminf(fmaxf((px + 1.0f) * 0.5f, 0.0f), 1.0f);
  const float pn1 = fminf(fmaxf((py + 1.0f) * 0.5f, 0.0f), 1.0f);
  const float pn2 = fminf(fmaxf((pz + 1.0f) * 0.5f, 0.0f), 1.0f);

  const int res = kRes[level];
  const unsigned mask = kMask[level];
  const f16x2* t = tab + kOff[level];

  float w0, w1, w2;
  unsigned g0, g1, g2;
  { const float s = pn0 * (float)(res - 1); const float fg = floorf(s); w0 = s - fg; g0 = (unsigned)fg; }
  { const float s = pn1 * (float)(res - 1); const float fg = floorf(s); w1 = s - fg; g1 = (unsigned)fg; }
  { const float s = pn2 * (float)(res - 1); const float fg = floorf(s); w2 = s - fg; g2 = (unsigned)fg; }
  const unsigned rm = (unsigned)(res - 1);
  const unsigned g0p = (g0 + 1u > rm) ? rm : g0 + 1u;
  const unsigned g1p = (g1 + 1u > rm) ? rm : g1 + 1u;
  const unsigned g2p = (g2 + 1u > rm) ? rm : g2 + 1u;
  const unsigned hx0 = g0 * kP1, hx1 = g0p * kP1;
  const unsigned hy0 = g1 * kP2, hy1 = g1p * kP2;
  const unsigned hz0 = g2 * kP3, hz1 = g2p * kP3;

  float f0 = 0.0f, f1 = 0.0f;
#pragma unroll
  for (int c = 0; c < 8; ++c) {
    const bool bx = (c >> 2) & 1, by = (c >> 1) & 1, bz = c & 1;
    const unsigned h = ((bx ? hx1 : hx0) + (by ? hy1 : hy0) + (bz ? hz1 : hz0)) & mask;
    const f16x2 e = t[h];
    const float wp = (bx ? w0 : 1.0f - w0) * (by ? w1 : 1.0f - w1) * (bz ? w2 : 1.0f - w2);
    f0 = __builtin_fmaf(wp, (float)e.x, f0);
    f1 = __builtin_fmaf(wp, (float)e.y, f1);
  }
  f16x2 o;
  o.x = (_Float16)f0;
  o.y = (_Float16)f1;
  feats[(size_t)level * n + pt] = o;
}

// =========================================================================
// Kernel 1b: fused fine gather, levels 5..15. 4 lanes per point; lane j
// reads dwordx4 (levels 4j..4j+3) from the SAME 64-B row -> 1 line-request
// per corner for all 11 levels.
// =========================================================================
__global__ __launch_bounds__(BLOCK) void gather_fine(const float* __restrict__ pos,
                                                     const uint4* __restrict__ R,
                                                     unsigned* __restrict__ feats, int n) {
  const int tid = threadIdx.x;
  const int j = tid & 3;
  int p = blockIdx.x * 64 + (tid >> 2);
  if (p >= n) p = n - 1;

  const float px = pos[3 * p + 0], py = pos[3 * p + 1], pz = pos[3 * p + 2];
  const float pn0 = fminf(fmaxf((px + 1.0f) * 0.5f, 0.0f), 1.0f);
  const float pn1 = fminf(fmaxf((py + 1.0f) * 0.5f, 0.0f), 1.0f);
  const float pn2 = fminf(fmaxf((pz + 1.0f) * 0.5f, 0.0f), 1.0f);

  float w0, w1, w2;
  unsigned g0, g1, g2;
  { const float s = pn0 * 511.0f; const float fg = floorf(s); w0 = s - fg; g0 = (unsigned)fg; }
  { const float s = pn1 * 511.0f; const float fg = floorf(s); w1 = s - fg; g1 = (unsigned)fg; }
  { const float s = pn2 * 511.0f; const float fg = floorf(s); w2 = s - fg; g2 = (unsigned)fg; }
  const unsigned g0p = (g0 + 1u > 511u) ? 511u : g0 + 1u;
  const unsigned g1p = (g1 + 1u > 511u) ? 511u : g1 + 1u;
  const unsigned g2p = (g2 + 1u > 511u) ? 511u : g2 + 1u;
  const unsigned hx0 = g0 * kP1, hx1 = g0p * kP1;
  const unsigned hy0 = g1 * kP2, hy1 = g1p * kP2;
  const unsigned hz0 = g2 * kP3, hz1 = g2p * kP3;

  float fa[8] = {0.0f, 0.0f, 0.0f, 0.0f, 0.0f, 0.0f, 0.0f, 0.0f};
#pragma unroll
  for (int c = 0; c < 8; ++c) {
    const bool bx = (c >> 2) & 1, by = (c >> 1) & 1, bz = c & 1;
    const unsigned h = ((bx ? hx1 : hx0) + (by ? hy1 : hy0) + (bz ? hz1 : hz0)) & 524287u;
    const uint4 v = R[h * 4 + j];
    const float wp = (bx ? w0 : 1.0f - w0) * (by ? w1 : 1.0f - w1) * (bz ? w2 : 1.0f - w2);
    U32F16 cv;
    cv.u = v.x; fa[0] = __builtin_fmaf(wp, (float)cv.h.x, fa[0]); fa[1] = __builtin_fmaf(wp, (float)cv.h.y, fa[1]);
    cv.u = v.y; fa[2] = __builtin_fmaf(wp, (float)cv.h.x, fa[2]); fa[3] = __builtin_fmaf(wp, (float)cv.h.y, fa[3]);
    cv.u = v.z; fa[4] = __builtin_fmaf(wp, (float)cv.h.x, fa[4]); fa[5] = __builtin_fmaf(wp, (float)cv.h.y, fa[5]);
    cv.u = v.w; fa[6] = __builtin_fmaf(wp, (float)cv.h.x, fa[6]); fa[7] = __builtin_fmaf(wp, (float)cv.h.y, fa[7]);
  }
#pragma unroll
  for (int m = 0; m < 4; ++m) {
    const int lvl = 4 * j + m;
    if (lvl < kNumFine) {
      U32F16 cv;
      cv.h.x = (_Float16)fa[2 * m];
      cv.h.y = (_Float16)fa[2 * m + 1];
      feats[(size_t)(5 + lvl) * n + p] = cv.u;
    }
  }
}

// =========================================================================
// Shared MFMA machinery (verified in R2/R3)
// =========================================================================
__device__ __forceinline__ int swz(int row, int col) {
  return row * 64 + (col ^ ((row & 7) << 3));
}

__device__ __forceinline__ void stage_w(_Float16* dst, const float* __restrict__ W,
                                        int Ksrc, int Nsrc, int KP, int NP, int rowShift,
                                        int tid) {
  const int total = KP * NP;
  for (int t = tid; t < total; t += BLOCK) {
    const int j = t & 7;
    const int nn = (t >> 3) % NP;
    const int kb = t / (8 * NP);
    const int k = kb * 8 + j - rowShift;
    float v = 0.0f;
    if (k >= 0 && k < Ksrc && nn < Nsrc) v = W[k * Nsrc + nn];
    dst[t] = (_Float16)v;
  }
}

__device__ __forceinline__ void stage_b(float* dst, const float* __restrict__ B,
                                        int nsrc, int np, int tid) {
  for (int t = tid; t < np; t += BLOCK) dst[t] = (t < nsrc) ? B[t] : 0.0f;
}

template <int KT, int OT>
__device__ __forceinline__ void mfma_tiles(const _Float16* act, const _Float16* wp,
                                           int lane, f32x4 (&acc)[OT][4]) {
  const int lr = lane & 15, lg = lane >> 4;
  f16x8 bF[4][KT];
#pragma unroll
  for (int pt = 0; pt < 4; ++pt)
#pragma unroll
    for (int kf = 0; kf < KT; ++kf) {
      const int row = pt * 16 + lr;
      bF[pt][kf] = *reinterpret_cast<const f16x8*>(&act[swz(row, kf * 32 + lg * 8)]);
    }
#pragma unroll
  for (int ot = 0; ot < OT; ++ot)
#pragma unroll
    for (int pt = 0; pt < 4; ++pt) acc[ot][pt] = 0.0f;
#pragma unroll
  for (int ot = 0; ot < OT; ++ot) {
#pragma unroll
    for (int kf = 0; kf < KT; ++kf) {
      const f16x8 aF =
          *reinterpret_cast<const f16x8*>(&wp[((kf * 4 + lg) * (OT * 16) + ot * 16 + lr) * 8]);
#pragma unroll
      for (int pt = 0; pt < 4; ++pt)
        acc[ot][pt] = __builtin_amdgcn_mfma_f32_16x16x32_f16(aF, bF[pt][kf], acc[ot][pt], 0, 0, 0);
    }
  }
}

template <int OT, bool RELU>
__device__ __forceinline__ void epilogue_act(const f32x4 (&acc)[OT][4], const float* bias,
                                             _Float16* act, int lane) {
  const int lr = lane & 15, lg = lane >> 4;
#pragma unroll
  for (int ot = 0; ot < OT; ++ot) {
    const float4 b4 = *reinterpret_cast<const float4*>(&bias[ot * 16 + lg * 4]);
#pragma unroll
    for (int pt = 0; pt < 4; ++pt) {
      const int row = pt * 16 + lr;
      float v0 = acc[ot][pt][0] + b4.x;
      float v1 = acc[ot][pt][1] + b4.y;
      float v2 = acc[ot][pt][2] + b4.z;
      float v3 = acc[ot][pt][3] + b4.w;
      if (RELU) {
        v0 = fmaxf(v0, 0.0f); v1 = fmaxf(v1, 0.0f);
        v2 = fmaxf(v2, 0.0f); v3 = fmaxf(v3, 0.0f);
      }
      f16x4 h;
      h[0] = (_Float16)v0; h[1] = (_Float16)v1; h[2] = (_Float16)v2; h[3] = (_Float16)v3;
      *reinterpret_cast<f16x4*>(&act[swz(row, ot * 16 + lg * 4)]) = h;
    }
  }
}

// =========================================================================
// Kernel 2: fused MLPs
// =========================================================================
__global__ __launch_bounds__(BLOCK, 2) void ngp_mlp(
    const unsigned* __restrict__ feats, const float* __restrict__ dirs,
    const float* __restrict__ dw0, const float* __restrict__ db0,
    const float* __restrict__ dw1, const float* __restrict__ db1,
    const float* __restrict__ dw2, const float* __restrict__ db2,
    const float* __restrict__ cw0, const float* __restrict__ cb0,
    const float* __restrict__ cw1, const float* __restrict__ cb1,
    const float* __restrict__ cw2, const float* __restrict__ cb2,
    const float* __restrict__ cw3, const float* __restrict__ cb3,
    float* __restrict__ out, int n) {
  __shared__ __align__(16) _Float16 sAct[4 * 4096];
  __shared__ __align__(16) _Float16 sWp[11264];
  __shared__ __align__(16) float sB[208];

  const int tid = threadIdx.x;
  const int lane = tid & 63, wid = tid >> 6;
  const int lr = lane & 15, lg = lane >> 4;
  _Float16* myAct = &sAct[wid * 4096];
  const int blockBase = blockIdx.x * BLOCK;
  const int base64 = blockBase + wid * 64;

  int i = blockBase + tid;
  if (i >= n) i = n - 1;

  float sh[16];
  {
    const float dxr = dirs[3 * i + 0], dyr = dirs[3 * i + 1], dzr = dirs[3 * i + 2];
    const float invn = 1.0f / sqrtf(dxr * dxr + dyr * dyr + dzr * dzr);
    const float x = dxr * invn, y = dyr * invn, z = dzr * invn;
    const float x2 = x * x, y2 = y * y, z2 = z * z;
    sh[0] = 0.28209479177387814f;
    sh[1] = -0.48860251190291987f * y;
    sh[2] = 0.48860251190291987f * z;
    sh[3] = -0.48860251190291987f * x;
    sh[4] = 1.0925484305920792f * x * y;
    sh[5] = -1.0925484305920792f * y * z;
    sh[6] = 0.31539156525252005f * (2.0f * z2 - x2 - y2);
    sh[7] = -1.0925484305920792f * x * z;
    sh[8] = 0.5462742152960396f * (x2 - y2);
    sh[9] = -0.5900435899266435f * y * (3.0f * x2 - y2);
    sh[10] = 2.890611442640554f * x * y * z;
    sh[11] = -0.4570457994644658f * y * (4.0f * z2 - x2 - y2);
    sh[12] = 0.3731763325901154f * z * (2.0f * z2 - 3.0f * x2 - 3.0f * y2);
    sh[13] = -0.4570457994644658f * x * (4.0f * z2 - x2 - y2);
    sh[14] = 1.445305721320277f * z * (x2 - y2);
    sh[15] = -0.5900435899266435f * x * (x2 - 3.0f * y2);
  }

  stage_w(sWp + 0, dw0, 32, 64, 32, 64, 0, tid);
  stage_w(sWp + 2048, dw1, 64, 64, 64, 64, 0, tid);
  stage_w(sWp + 6144, dw2, 64, 16, 64, 16, 0, tid);
  stage_b(sB + 0, db0, 64, 64, tid);
  stage_b(sB + 64, db1, 64, 64, tid);
  stage_b(sB + 128, db2, 16, 16, tid);
  __syncthreads();

  {
    f32x4 acc[4][4];
    {
      f16x8 bF[4];
#pragma unroll
      for (int pt = 0; pt < 4; ++pt) {
        int gpt = base64 + pt * 16 + lr;
        if (gpt >= n) gpt = n - 1;
        union { unsigned u[4]; f16x8 v; } cv;
#pragma unroll
        for (int m = 0; m < 4; ++m) cv.u[m] = feats[(unsigned)(4 * lg + m) * (unsigned)n + gpt];
        bF[pt] = cv.v;
      }
#pragma unroll
      for (int ot = 0; ot < 4; ++ot)
#pragma unroll
        for (int pt = 0; pt < 4; ++pt) acc[ot][pt] = 0.0f;
#pragma unroll
      for (int ot = 0; ot < 4; ++ot) {
        const f16x8 aF = *reinterpret_cast<const f16x8*>(&sWp[(lg * 64 + ot * 16 + lr) * 8]);
#pragma unroll
        for (int pt = 0; pt < 4; ++pt)
          acc[ot][pt] = __builtin_amdgcn_mfma_f32_16x16x32_f16(aF, bF[pt], acc[ot][pt], 0, 0, 0);
      }
    }
    epilogue_act<4, true>(acc, sB + 0, myAct, lane);
  }
  {
    f32x4 acc[4][4];
    mfma_tiles<2, 4>(myAct, sWp + 2048, lane, acc);
    epilogue_act<4, true>(acc, sB + 64, myAct, lane);
  }
  {
    f32x4 acc[1][4];
    mfma_tiles<2, 1>(myAct, sWp + 6144, lane, acc);
    const float4 b4 = *reinterpret_cast<const float4*>(&sB[128 + lg * 4]);
#pragma unroll
    for (int pt = 0; pt < 4; ++pt) {
      const int row = pt * 16 + lr;
      const int gpt = base64 + row;
      const float v0 = acc[0][pt][0] + b4.x;
      const float v1 = acc[0][pt][1] + b4.y;
      const float v2 = acc[0][pt][2] + b4.z;
      const float v3 = acc[0][pt][3] + b4.w;
      if (lg == 0) {
        if (gpt < n) out[gpt * 4] = v0;  // sigma
        myAct[swz(row, 1)] = (_Float16)v1;
        myAct[swz(row, 2)] = (_Float16)v2;
        myAct[swz(row, 3)] = (_Float16)v3;
      } else {
        f16x4 h;
        h[0] = (_Float16)v0; h[1] = (_Float16)v1; h[2] = (_Float16)v2; h[3] = (_Float16)v3;
        *reinterpret_cast<f16x4*>(&myAct[swz(row, lg * 4)]) = h;
      }
    }
  }

  myAct[swz(lane, 0)] = (_Float16)0.0f;
  {
    f16x8 v0, v1;
#pragma unroll
    for (int j = 0; j < 8; ++j) { v0[j] = (_Float16)sh[j]; v1[j] = (_Float16)sh[8 + j]; }
    *reinterpret_cast<f16x8*>(&myAct[swz(lane, 16)]) = v0;
    *reinterpret_cast<f16x8*>(&myAct[swz(lane, 24)]) = v1;
  }
  __syncthreads();

  stage_w(sWp + 0, cw0, 31, 64, 32, 64, 1, tid);
  stage_w(sWp + 2048, cw1, 64, 64, 64, 64, 0, tid);
  stage_w(sWp + 6144, cw2, 64, 64, 64, 64, 0, tid);
  stage_w(sWp + 10240, cw3, 64, 3, 64, 16, 0, tid);
  stage_b(sB + 0, cb0, 64, 64, tid);
  stage_b(sB + 64, cb1, 64, 64, tid);
  stage_b(sB + 128, cb2, 64, 64, tid);
  stage_b(sB + 192, cb3, 3, 16, tid);
  __syncthreads();

  {
    f32x4 acc[4][4];
    mfma_tiles<1, 4>(myAct, sWp + 0, lane, acc);
    epilogue_act<4, true>(acc, sB + 0, myAct, lane);
  }
  {
    f32x4 acc[4][4];
    mfma_tiles<2, 4>(myAct, sWp + 2048, lane, acc);
    epilogue_act<4, true>(acc, sB + 64, myAct, lane);
  }
  {
    f32x4 acc[4][4];
    mfma_tiles<2, 4>(myAct, sWp + 6144, lane, acc);
    epilogue_act<4, true>(acc, sB + 128, myAct, lane);
  }
  {
    f32x4 acc[1][4];
    mfma_tiles<2, 1>(myAct, sWp + 10240, lane, acc);
    if (lg == 0) {
      const float4 b4 = *reinterpret_cast<const float4*>(&sB[192]);
#pragma unroll
      for (int pt = 0; pt < 4; ++pt) {
        const int gpt = base64 + pt * 16 + lr;
        if (gpt < n) {
          out[gpt * 4 + 1] = 1.0f / (1.0f + __expf(-(acc[0][pt][0] + b4.x)));
          out[gpt * 4 + 2] = 1.0f / (1.0f + __expf(-(acc[0][pt][1] + b4.y)));
          out[gpt * 4 + 3] = 1.0f / (1.0f + __expf(-(acc[0][pt][2] + b4.z)));
        }
      }
    }
  }
}

// =========================================================================
// Fallback: R2's proven fused kernel (used only if d_ws is too small)
// =========================================================================
__global__ __launch_bounds__(BLOCK, 2) void ngp_mfma(
    const float* __restrict__ pos, const float* __restrict__ dirs, const float* __restrict__ emb,
    const float* __restrict__ dw0, const float* __restrict__ db0,
    const float* __restrict__ dw1, const float* __restrict__ db1,
    const float* __restrict__ dw2, const float* __restrict__ db2,
    const float* __restrict__ cw0, const float* __restrict__ cb0,
    const float* __restrict__ cw1, const float* __restrict__ cb1,
    const float* __restrict__ cw2, const float* __restrict__ cb2,
    const float* __restrict__ cw3, const float* __restrict__ cb3,
    float* __restrict__ out, int n) {
  __shared__ __align__(16) _Float16 sAct[4 * 4096];
  __shared__ __align__(16) _Float16 sWp[11264];
  __shared__ __align__(16) float sB[208];

  const int tid = threadIdx.x;
  const int lane = tid & 63, wid = tid >> 6;
  const int lr = lane & 15, lg = lane >> 4;
  _Float16* myAct = &sAct[wid * 4096];
  const int blockBase = blockIdx.x * BLOCK;

  int i = blockBase + tid;
  if (i >= n) i = n - 1;

  const float px = pos[3 * i + 0], py = pos[3 * i + 1], pz = pos[3 * i + 2];
  const float pn0 = fminf(fmaxf((px + 1.0f) * 0.5f, 0.0f), 1.0f);
  const float pn1 = fminf(fmaxf((py + 1.0f) * 0.5f, 0.0f), 1.0f);
  const float pn2 = fminf(fmaxf((pz + 1.0f) * 0.5f, 0.0f), 1.0f);

  float feat[32];
  const float2* emb2 = reinterpret_cast<const float2*>(emb);
#pragma unroll
  for (int l = 0; l < 16; ++l) {
    const int res = kRes[l];
    const unsigned mask = kMask[l];
    const float2* elvl = emb2 + kOff[l];
    float w0, w1, w2;
    unsigned g0, g1, g2;
    { const float s = pn0 * (float)(res - 1); const float fg = floorf(s); w0 = s - fg; g0 = (unsigned)fg; }
    { const float s = pn1 * (float)(res - 1); const float fg = floorf(s); w1 = s - fg; g1 = (unsigned)fg; }
    { const float s = pn2 * (float)(res - 1); const float fg = floorf(s); w2 = s - fg; g2 = (unsigned)fg; }
    const unsigned rm = (unsigned)(res - 1);
    const unsigned g0p = (g0 + 1u > rm) ? rm : g0 + 1u;
    const unsigned g1p = (g1 + 1u > rm) ? rm : g1 + 1u;
    const unsigned g2p = (g2 + 1u > rm) ? rm : g2 + 1u;
    const unsigned hx0 = g0 * kP1, hx1 = g0p * kP1;
    const unsigned hy0 = g1 * kP2, hy1 = g1p * kP2;
    const unsigned hz0 = g2 * kP3, hz1 = g2p * kP3;
    float f0 = 0.0f, f1 = 0.0f;
#pragma unroll
    for (int c = 0; c < 8; ++c) {
      const bool bx = (c >> 2) & 1, by = (c >> 1) & 1, bz = c & 1;
      const unsigned h = ((bx ? hx1 : hx0) + (by ? hy1 : hy0) + (bz ? hz1 : hz0)) & mask;
      const float2 e = elvl[h];
      const float wp = (bx ? w0 : 1.0f - w0) * (by ? w1 : 1.0f - w1) * (bz ? w2 : 1.0f - w2);
      f0 = __builtin_fmaf(wp, e.x, f0);
      f1 = __builtin_fmaf(wp, e.y, f1);
    }
    feat[2 * l + 0] = f0;
    feat[2 * l + 1] = f1;
  }

  float sh[16];
  {
    const float dxr = dirs[3 * i + 0], dyr = dirs[3 * i + 1], dzr = dirs[3 * i + 2];
    const float invn = 1.0f / sqrtf(dxr * dxr + dyr * dyr + dzr * dzr);
    const float x = dxr * invn, y = dyr * invn, z = dzr * invn;
    const float x2 = x * x, y2 = y * y, z2 = z * z;
    sh[0] = 0.28209479177387814f;
    sh[1] = -0.48860251190291987f * y;
    sh[2] = 0.48860251190291987f * z;
    sh[3] = -0.48860251190291987f * x;
    sh[4] = 1.0925484305920792f * x * y;
    sh[5] = -1.0925484305920792f * y * z;
    sh[6] = 0.31539156525252005f * (2.0f * z2 - x2 - y2);
    sh[7] = -1.0925484305920792f * x * z;
    sh[8] = 0.5462742152960396f * (x2 - y2);
    sh[9] = -0.5900435899266435f * y * (3.0f * x2 - y2);
    sh[10] = 2.890611442640554f * x * y * z;
    sh[11] = -0.4570457994644658f * y * (4.0f * z2 - x2 - y2);
    sh[12] = 0.3731763325901154f * z * (2.0f * z2 - 3.0f * x2 - 3.0f * y2);
    sh[13] = -0.4570457994644658f * x * (4.0f * z2 - x2 - y2);
    sh[14] = 1.445305721320277f * z * (x2 - y2);
    sh[15] = -0.5900435899266435f * x * (x2 - 3.0f * y2);
  }

#pragma unroll
  for (int cb = 0; cb < 4; ++cb) {
    f16x8 v;
#pragma unroll
    for (int j = 0; j < 8; ++j) v[j] = (_Float16)feat[cb * 8 + j];
    *reinterpret_cast<f16x8*>(&myAct[swz(lane, cb * 8)]) = v;
  }

  stage_w(sWp + 0, dw0, 32, 64, 32, 64, 0, tid);
  stage_w(sWp + 2048, dw1, 64, 64, 64, 64, 0, tid);
  stage_w(sWp + 6144, dw2, 64, 16, 64, 16, 0, tid);
  stage_b(sB + 0, db0, 64, 64, tid);
  stage_b(sB + 64, db1, 64, 64, tid);
  stage_b(sB + 128, db2, 16, 16, tid);
  __syncthreads();

  {
    f32x4 acc[4][4];
    mfma_tiles<1, 4>(myAct, sWp + 0, lane, acc);
    epilogue_act<4, true>(acc, sB + 0, myAct, lane);
  }
  {
    f32x4 acc[4][4];
    mfma_tiles<2, 4>(myAct, sWp + 2048, lane, acc);
    epilogue_act<4, true>(acc, sB + 64, myAct, lane);
  }
  {
    f32x4 acc[1][4];
    mfma_tiles<2, 1>(myAct, sWp + 6144, lane, acc);
    const float4 b4 = *reinterpret_cast<const float4*>(&sB[128 + lg * 4]);
#pragma unroll
    for (int pt = 0; pt < 4; ++pt) {
      const int row = pt * 16 + lr;
      const int gpt = blockBase + wid * 64 + row;
      const float v0 = acc[0][pt][0] + b4.x;
      const float v1 = acc[0][pt][1] + b4.y;
      const float v2 = acc[0][pt][2] + b4.z;
      const float v3 = acc[0][pt][3] + b4.w;
      if (lg == 0) {
        if (gpt < n) out[gpt * 4] = v0;
        myAct[swz(row, 1)] = (_Float16)v1;
        myAct[swz(row, 2)] = (_Float16)v2;
        myAct[swz(row, 3)] = (_Float16)v3;
      } else {
        f16x4 h;
        h[0] = (_Float16)v0; h[1] = (_Float16)v1; h[2] = (_Float16)v2; h[3] = (_Float16)v3;
        *reinterpret_cast<f16x4*>(&myAct[swz(row, lg * 4)]) = h;
      }
    }
  }

  myAct[swz(lane, 0)] = (_Float16)0.0f;
  {
    f16x8 v0, v1;
#pragma unroll
    for (int j = 0; j < 8; ++j) { v0[j] = (_Float16)sh[j]; v1[j] = (_Float16)sh[8 + j]; }
    *reinterpret_cast<f16x8*>(&myAct[swz(lane, 16)]) = v0;
    *reinterpret_cast<f16x8*>(&myAct[swz(lane, 24)]) = v1;
  }
  __syncthreads();

  stage_w(sWp + 0, cw0, 31, 64, 32, 64, 1, tid);
  stage_w(sWp + 2048, cw1, 64, 64, 64, 64, 0, tid);
  stage_w(sWp + 6144, cw2, 64, 64, 64, 64, 0, tid);
  stage_w(sWp + 10240, cw3, 64, 3, 64, 16, 0, tid);
  stage_b(sB + 0, cb0, 64, 64, tid);
  stage_b(sB + 64, cb1, 64, 64, tid);
  stage_b(sB + 128, cb2, 64, 64, tid);
  stage_b(sB + 192, cb3, 3, 16, tid);
  __syncthreads();

  {
    f32x4 acc[4][4];
    mfma_tiles<1, 4>(myAct, sWp + 0, lane, acc);
    epilogue_act<4, true>(acc, sB + 0, myAct, lane);
  }
  {
    f32x4 acc[4][4];
    mfma_tiles<2, 4>(myAct, sWp + 2048, lane, acc);
    epilogue_act<4, true>(acc, sB + 64, myAct, lane);
  }
  {
    f32x4 acc[4][4];
    mfma_tiles<2, 4>(myAct, sWp + 6144, lane, acc);
    epilogue_act<4, true>(acc, sB + 128, myAct, lane);
  }
  {
    f32x4 acc[1][4];
    mfma_tiles<2, 1>(myAct, sWp + 10240, lane, acc);
    if (lg == 0) {
      const float4 b4 = *reinterpret_cast<const float4*>(&sB[192]);
#pragma unroll
      for (int pt = 0; pt < 4; ++pt) {
        const int gpt = blockBase + wid * 64 + pt * 16 + lr;
        if (gpt < n) {
          out[gpt * 4 + 1] = 1.0f / (1.0f + __expf(-(acc[0][pt][0] + b4.x)));
          out[gpt * 4 + 2] = 1.0f / (1.0f + __expf(-(acc[0][pt][1] + b4.y)));
          out[gpt * 4 + 3] = 1.0f / (1.0f + __expf(-(acc[0][pt][2] + b4.z)));
        }
      }
    }
  }
}

extern "C" void kernel_launch(void* const* d_in, const int* in_sizes, int n_in,
                              void* d_out, int out_size, void* d_ws, size_t ws_size,
                              hipStream_t stream) {
  const float* pos = (const float*)d_in[0];
  const float* dirs = (const float*)d_in[1];
  const float* emb = (const float*)d_in[2];
  const float* dw0 = (const float*)d_in[3];
  const float* db0 = (const float*)d_in[4];
  const float* dw1 = (const float*)d_in[5];
  const float* db1 = (const float*)d_in[6];
  const float* dw2 = (const float*)d_in[7];
  const float* db2 = (const float*)d_in[8];
  const float* cw0 = (const float*)d_in[9];
  const float* cb0 = (const float*)d_in[10];
  const float* cw1 = (const float*)d_in[11];
  const float* cb1 = (const float*)d_in[12];
  const float* cw2 = (const float*)d_in[13];
  const float* cb2 = (const float*)d_in[14];
  const float* cw3 = (const float*)d_in[15];
  const float* cb3 = (const float*)d_in[16];
  float* out = (float*)d_out;

  const int n = in_sizes[0] / 3;
  const int nTab = in_sizes[2] / 2;
  const int grid = (n + BLOCK - 1) / BLOCK;
  const size_t featBytes = (size_t)16 * (size_t)n * 4;
  const size_t rBytes = (size_t)kFineEntries * 64;
  const size_t tabSmallBytes = (size_t)kSmallEntries * 4;
  const size_t tabFullBytes = (size_t)nTab * 4;
  const size_t need1 = rBytes + featBytes + tabSmallBytes;
  const size_t need2 = tabFullBytes + featBytes;

  if (ws_size >= need1) {
    // Tier 1: interleaved fine table + level-major coarse
    uint4* R = (uint4*)d_ws;
    f16x2* feats = (f16x2*)((char*)d_ws + rBytes);
    f16x2* tabS = (f16x2*)((char*)d_ws + rBytes + featBytes);
    cvt_emb<<<(kSmallEntries + BLOCK - 1) / BLOCK, BLOCK, 0, stream>>>(
        (const float2*)emb, tabS, kSmallEntries);
    build_R<<<kFineEntries / 64, BLOCK, 0, stream>>>((const float2*)emb, R);
    hash_gather<<<5 * grid, BLOCK, 0, stream>>>(pos, tabS, feats, n, grid);
    gather_fine<<<(n + 63) / 64, BLOCK, 0, stream>>>(pos, R, (unsigned*)feats, n);
    ngp_mlp<<<grid, BLOCK, 0, stream>>>((const unsigned*)feats, dirs, dw0, db0, dw1, db1,
                                        dw2, db2, cw0, cb0, cw1, cb1, cw2, cb2, cw3, cb3,
                                        out, n);
  } else if (ws_size >= need2) {
    // Tier 2: R3's proven level-major-everything path
    f16x2* tab = (f16x2*)d_ws;
    f16x2* feats = (f16x2*)((char*)d_ws + tabFullBytes);
    cvt_emb<<<(nTab + BLOCK - 1) / BLOCK, BLOCK, 0, stream>>>((const float2*)emb, tab, nTab);
    hash_gather<<<16 * grid, BLOCK, 0, stream>>>(pos, tab, feats, n, grid);
    ngp_mlp<<<grid, BLOCK, 0, stream>>>((const unsigned*)feats, dirs, dw0, db0, dw1, db1,
                                        dw2, db2, cw0, cb0, cw1, cb1, cw2, cb2, cw3, cb3,
                                        out, n);
  } else {
    ngp_mfma<<<grid, BLOCK, 0, stream>>>(pos, dirs, emb, dw0, db0, dw1, db1, dw2, db2,
                                         cw0, cb0, cw1, cb1, cw2, cb2, cw3, cb3, out, n);
  }
}

// Round 5
// 432.117 us; speedup vs baseline: 6.6745x; 1.0053x over previous
//
#include <hip/hip_runtime.h>

#define BLOCK 256

typedef _Float16 f16x8 __attribute__((ext_vector_type(8)));
typedef _Float16 f16x4 __attribute__((ext_vector_type(4)));
typedef _Float16 f16x2 __attribute__((ext_vector_type(2)));
typedef float f32x4 __attribute__((ext_vector_type(4)));
typedef unsigned u32x4 __attribute__((ext_vector_type(4)));

// ---- Hash-grid compile-time tables -------------------------------------
constexpr unsigned kP1 = 73856093u, kP2 = 19349663u, kP3 = 83492791u;
constexpr int kRes[16] = {16, 32, 64, 128, 256, 512, 512, 512,
                          512, 512, 512, 512, 512, 512, 512, 512};
constexpr unsigned kMask[16] = {4095u, 32767u, 262143u, 524287u, 524287u, 524287u,
                                524287u, 524287u, 524287u, 524287u, 524287u, 524287u,
                                524287u, 524287u, 524287u, 524287u};
constexpr int kOff[16] = {0,       4096,    36864,   299008,  823296,  1347584,
                          1871872, 2396160, 2920448, 3444736, 3969024, 4493312,
                          5017600, 5541888, 6066176, 6590464};
constexpr int kNumFine = 11;            // levels 5..15 share res=512, size=2^19
constexpr int kFineEntries = 524288;
constexpr int kSmallEntries = 1347584;  // entries of levels 0..4 (= kOff[5])

union U32F16 { unsigned u; f16x2 h; };

// =========================================================================
// Kernel 0: fp32 embedding -> f16 (levels 0..4 region)
// =========================================================================
__global__ __launch_bounds__(BLOCK) void cvt_emb(const float2* __restrict__ emb,
                                                 f16x2* __restrict__ tab, int total) {
  const int i = blockIdx.x * BLOCK + threadIdx.x;
  if (i < total) {
    const float2 e = emb[i];
    f16x2 h;
    h.x = (_Float16)e.x;
    h.y = (_Float16)e.y;
    tab[i] = h;
  }
}

// =========================================================================
// Kernel 0b: interleaved fine table R[h] = 64-B row; dword j (j<11) = f16x2
// of level 5+j at entry h.
// =========================================================================
__global__ __launch_bounds__(BLOCK) void build_R(const float2* __restrict__ emb,
                                                 u32x4* __restrict__ R) {
  const int tid = threadIdx.x;
  const int j = tid & 3;
  const int row = blockIdx.x * 64 + (tid >> 2);
  u32x4 v;
#pragma unroll
  for (int m = 0; m < 4; ++m) {
    const int lvl = 4 * j + m;
    unsigned u = 0;
    if (lvl < kNumFine) {
      const float2 e = emb[kOff[5 + lvl] + row];
      U32F16 cv;
      cv.h.x = (_Float16)e.x;
      cv.h.y = (_Float16)e.y;
      u = cv.u;
    }
    v[m] = u;
  }
  R[row * 4 + j] = v;
}

// =========================================================================
// Weight pre-pack (runs every launch; tiny). Packed f16 layout [K/8][N][8]:
//  ph1: dw0@0(2048) dw1@2048(4096) dw2@6144(1024)            -> 7168
//  ph2: cw0@7168(2048) cw1@9216(4096) cw2@13312(4096) cw3@17408(1024)
// biases fp32: ph1 144 @0; ph2 208 @144
// =========================================================================
__device__ __forceinline__ void stage_w(_Float16* dst, const float* __restrict__ W,
                                        int Ksrc, int Nsrc, int KP, int NP, int rowShift,
                                        int tid) {
  const int total = KP * NP;
  for (int t = tid; t < total; t += BLOCK) {
    const int j = t & 7;
    const int nn = (t >> 3) % NP;
    const int kb = t / (8 * NP);
    const int k = kb * 8 + j - rowShift;
    float v = 0.0f;
    if (k >= 0 && k < Ksrc && nn < Nsrc) v = W[k * Nsrc + nn];
    dst[t] = (_Float16)v;
  }
}

__device__ __forceinline__ void stage_b(float* dst, const float* __restrict__ B,
                                        int nsrc, int np, int tid) {
  for (int t = tid; t < np; t += BLOCK) dst[t] = (t < nsrc) ? B[t] : 0.0f;
}

__global__ __launch_bounds__(BLOCK) void pack_weights(
    const float* __restrict__ dw0, const float* __restrict__ db0,
    const float* __restrict__ dw1, const float* __restrict__ db1,
    const float* __restrict__ dw2, const float* __restrict__ db2,
    const float* __restrict__ cw0, const float* __restrict__ cb0,
    const float* __restrict__ cw1, const float* __restrict__ cb1,
    const float* __restrict__ cw2, const float* __restrict__ cb2,
    const float* __restrict__ cw3, const float* __restrict__ cb3,
    _Float16* __restrict__ pW, float* __restrict__ pB) {
  const int b = blockIdx.x, tid = threadIdx.x;
  switch (b) {
    case 0: stage_w(pW + 0, dw0, 32, 64, 32, 64, 0, tid); break;
    case 1: stage_w(pW + 2048, dw1, 64, 64, 64, 64, 0, tid); break;
    case 2: stage_w(pW + 6144, dw2, 64, 16, 64, 16, 0, tid); break;
    case 3: stage_w(pW + 7168, cw0, 31, 64, 32, 64, 1, tid); break;
    case 4: stage_w(pW + 9216, cw1, 64, 64, 64, 64, 0, tid); break;
    case 5: stage_w(pW + 13312, cw2, 64, 64, 64, 64, 0, tid); break;
    case 6: stage_w(pW + 17408, cw3, 64, 3, 64, 16, 0, tid); break;
    default:
      for (int t = tid; t < 352; t += BLOCK) {
        float v;
        if (t < 64) v = db0[t];
        else if (t < 128) v = db1[t - 64];
        else if (t < 144) v = (t - 128) < 16 ? db2[t - 128] : 0.0f;
        else if (t < 208) v = cb0[t - 144];
        else if (t < 272) v = cb1[t - 208];
        else if (t < 336) v = cb2[t - 272];
        else v = (t - 336) < 3 ? cb3[t - 336] : 0.0f;
        pB[t] = v;
      }
  }
}

// =========================================================================
// Kernel 1: level-major hash gather (used for level 4 in tier-1; all levels
// in tier-2). lvl0 = first level of this launch.
// =========================================================================
__global__ __launch_bounds__(BLOCK) void hash_gather(const float* __restrict__ pos,
                                                     const f16x2* __restrict__ tab,
                                                     f16x2* __restrict__ feats, int n,
                                                     int chunks, int lvl0) {
  const int b = blockIdx.x;
  const int level = lvl0 + b / chunks;
  const int pt = (b - (level - lvl0) * chunks) * BLOCK + threadIdx.x;
  if (pt >= n) return;

  const float px = pos[3 * pt + 0], py = pos[3 * pt + 1], pz = pos[3 * pt + 2];
  const float pn0 = fminf(fmaxf((px + 1.0f) * 0.5f, 0.0f), 1.0f);
  const float pn1 = fminf(fmaxf((py + 1.0f) * 0.5f, 0.0f), 1.0f);
  const float pn2 = fminf(fmaxf((pz + 1.0f) * 0.5f, 0.0f), 1.0f);

  const int res = kRes[level];
  const unsigned mask = kMask[level];
  const f16x2* t = tab + kOff[level];

  float w0, w1, w2;
  unsigned g0, g1, g2;
  { const float s = pn0 * (float)(res - 1); const float fg = floorf(s); w0 = s - fg; g0 = (unsigned)fg; }
  { const float s = pn1 * (float)(res - 1); const float fg = floorf(s); w1 = s - fg; g1 = (unsigned)fg; }
  { const float s = pn2 * (float)(res - 1); const float fg = floorf(s); w2 = s - fg; g2 = (unsigned)fg; }
  const unsigned rm = (unsigned)(res - 1);
  const unsigned g0p = (g0 + 1u > rm) ? rm : g0 + 1u;
  const unsigned g1p = (g1 + 1u > rm) ? rm : g1 + 1u;
  const unsigned g2p = (g2 + 1u > rm) ? rm : g2 + 1u;
  const unsigned hx0 = g0 * kP1, hx1 = g0p * kP1;
  const unsigned hy0 = g1 * kP2, hy1 = g1p * kP2;
  const unsigned hz0 = g2 * kP3, hz1 = g2p * kP3;

  float f0 = 0.0f, f1 = 0.0f;
#pragma unroll
  for (int c = 0; c < 8; ++c) {
    const bool bx = (c >> 2) & 1, by = (c >> 1) & 1, bz = c & 1;
    const unsigned h = ((bx ? hx1 : hx0) + (by ? hy1 : hy0) + (bz ? hz1 : hz0)) & mask;
    const f16x2 e = t[h];
    const float wp = (bx ? w0 : 1.0f - w0) * (by ? w1 : 1.0f - w1) * (bz ? w2 : 1.0f - w2);
    f0 = __builtin_fmaf(wp, (float)e.x, f0);
    f1 = __builtin_fmaf(wp, (float)e.y, f1);
  }
  f16x2 o;
  o.x = (_Float16)f0;
  o.y = (_Float16)f1;
  feats[(size_t)level * n + pt] = o;
}

// =========================================================================
// Kernel 1b: fused gather — fine levels 5..15 via interleaved R rows
// (nontemporal, streaming) + coarse levels 0..3 (lane j owns level j,
// tables stay L2-resident). Level 4 handled separately.
// =========================================================================
__global__ __launch_bounds__(BLOCK) void gather_all(const float* __restrict__ pos,
                                                    const u32x4* __restrict__ R,
                                                    const f16x2* __restrict__ tabS,
                                                    unsigned* __restrict__ feats, int n) {
  const int tid = threadIdx.x;
  const int j = tid & 3;
  int p = blockIdx.x * 64 + (tid >> 2);
  if (p >= n) p = n - 1;

  const float px = pos[3 * p + 0], py = pos[3 * p + 1], pz = pos[3 * p + 2];
  const float pn0 = fminf(fmaxf((px + 1.0f) * 0.5f, 0.0f), 1.0f);
  const float pn1 = fminf(fmaxf((py + 1.0f) * 0.5f, 0.0f), 1.0f);
  const float pn2 = fminf(fmaxf((pz + 1.0f) * 0.5f, 0.0f), 1.0f);

  // ---- fine (res 512, shared hashes across 11 levels) ----
  {
    float w0, w1, w2;
    unsigned g0, g1, g2;
    { const float s = pn0 * 511.0f; const float fg = floorf(s); w0 = s - fg; g0 = (unsigned)fg; }
    { const float s = pn1 * 511.0f; const float fg = floorf(s); w1 = s - fg; g1 = (unsigned)fg; }
    { const float s = pn2 * 511.0f; const float fg = floorf(s); w2 = s - fg; g2 = (unsigned)fg; }
    const unsigned g0p = (g0 + 1u > 511u) ? 511u : g0 + 1u;
    const unsigned g1p = (g1 + 1u > 511u) ? 511u : g1 + 1u;
    const unsigned g2p = (g2 + 1u > 511u) ? 511u : g2 + 1u;
    const unsigned hx0 = g0 * kP1, hx1 = g0p * kP1;
    const unsigned hy0 = g1 * kP2, hy1 = g1p * kP2;
    const unsigned hz0 = g2 * kP3, hz1 = g2p * kP3;

    float fa[8] = {0.0f, 0.0f, 0.0f, 0.0f, 0.0f, 0.0f, 0.0f, 0.0f};
#pragma unroll
    for (int c = 0; c < 8; ++c) {
      const bool bx = (c >> 2) & 1, by = (c >> 1) & 1, bz = c & 1;
      const unsigned h = ((bx ? hx1 : hx0) + (by ? hy1 : hy0) + (bz ? hz1 : hz0)) & 524287u;
      const u32x4 v = __builtin_nontemporal_load(&R[h * 4 + j]);
      const float wp = (bx ? w0 : 1.0f - w0) * (by ? w1 : 1.0f - w1) * (bz ? w2 : 1.0f - w2);
      U32F16 cv;
      cv.u = v[0]; fa[0] = __builtin_fmaf(wp, (float)cv.h.x, fa[0]); fa[1] = __builtin_fmaf(wp, (float)cv.h.y, fa[1]);
      cv.u = v[1]; fa[2] = __builtin_fmaf(wp, (float)cv.h.x, fa[2]); fa[3] = __builtin_fmaf(wp, (float)cv.h.y, fa[3]);
      cv.u = v[2]; fa[4] = __builtin_fmaf(wp, (float)cv.h.x, fa[4]); fa[5] = __builtin_fmaf(wp, (float)cv.h.y, fa[5]);
      cv.u = v[3]; fa[6] = __builtin_fmaf(wp, (float)cv.h.x, fa[6]); fa[7] = __builtin_fmaf(wp, (float)cv.h.y, fa[7]);
    }
#pragma unroll
    for (int m = 0; m < 4; ++m) {
      const int lvl = 4 * j + m;
      if (lvl < kNumFine) {
        U32F16 cv;
        cv.h.x = (_Float16)fa[2 * m];
        cv.h.y = (_Float16)fa[2 * m + 1];
        feats[(size_t)(5 + lvl) * n + p] = cv.u;
      }
    }
  }

  // ---- coarse: lane j fully owns level j (0..3) ----
  {
    const int res = kRes[j];
    const unsigned mask = kMask[j];
    const f16x2* t = tabS + kOff[j];
    float w0, w1, w2;
    unsigned g0, g1, g2;
    { const float s = pn0 * (float)(res - 1); const float fg = floorf(s); w0 = s - fg; g0 = (unsigned)fg; }
    { const float s = pn1 * (float)(res - 1); const float fg = floorf(s); w1 = s - fg; g1 = (unsigned)fg; }
    { const float s = pn2 * (float)(res - 1); const float fg = floorf(s); w2 = s - fg; g2 = (unsigned)fg; }
    const unsigned rm = (unsigned)(res - 1);
    const unsigned g0p = (g0 + 1u > rm) ? rm : g0 + 1u;
    const unsigned g1p = (g1 + 1u > rm) ? rm : g1 + 1u;
    const unsigned g2p = (g2 + 1u > rm) ? rm : g2 + 1u;
    const unsigned hx0 = g0 * kP1, hx1 = g0p * kP1;
    const unsigned hy0 = g1 * kP2, hy1 = g1p * kP2;
    const unsigned hz0 = g2 * kP3, hz1 = g2p * kP3;

    float f0 = 0.0f, f1 = 0.0f;
#pragma unroll
    for (int c = 0; c < 8; ++c) {
      const bool bx = (c >> 2) & 1, by = (c >> 1) & 1, bz = c & 1;
      const unsigned h = ((bx ? hx1 : hx0) + (by ? hy1 : hy0) + (bz ? hz1 : hz0)) & mask;
      const f16x2 e = t[h];
      const float wp = (bx ? w0 : 1.0f - w0) * (by ? w1 : 1.0f - w1) * (bz ? w2 : 1.0f - w2);
      f0 = __builtin_fmaf(wp, (float)e.x, f0);
      f1 = __builtin_fmaf(wp, (float)e.y, f1);
    }
    U32F16 cv;
    cv.h.x = (_Float16)f0;
    cv.h.y = (_Float16)f1;
    feats[(size_t)j * n + p] = cv.u;
  }
}

// =========================================================================
// MFMA machinery (verified R2/R3)
// =========================================================================
__device__ __forceinline__ int swz(int row, int col) {
  return row * 64 + (col ^ ((row & 7) << 3));
}

template <int KT, int OT>
__device__ __forceinline__ void mfma_tiles(const _Float16* act, const _Float16* wp,
                                           int lane, f32x4 (&acc)[OT][4]) {
  const int lr = lane & 15, lg = lane >> 4;
  f16x8 bF[4][KT];
#pragma unroll
  for (int pt = 0; pt < 4; ++pt)
#pragma unroll
    for (int kf = 0; kf < KT; ++kf) {
      const int row = pt * 16 + lr;
      bF[pt][kf] = *reinterpret_cast<const f16x8*>(&act[swz(row, kf * 32 + lg * 8)]);
    }
#pragma unroll
  for (int ot = 0; ot < OT; ++ot)
#pragma unroll
    for (int pt = 0; pt < 4; ++pt) acc[ot][pt] = 0.0f;
#pragma unroll
  for (int ot = 0; ot < OT; ++ot) {
#pragma unroll
    for (int kf = 0; kf < KT; ++kf) {
      const f16x8 aF =
          *reinterpret_cast<const f16x8*>(&wp[((kf * 4 + lg) * (OT * 16) + ot * 16 + lr) * 8]);
#pragma unroll
      for (int pt = 0; pt < 4; ++pt)
        acc[ot][pt] = __builtin_amdgcn_mfma_f32_16x16x32_f16(aF, bF[pt][kf], acc[ot][pt], 0, 0, 0);
    }
  }
}

template <int OT, bool RELU>
__device__ __forceinline__ void epilogue_act(const f32x4 (&acc)[OT][4], const float* bias,
                                             _Float16* act, int lane) {
  const int lr = lane & 15, lg = lane >> 4;
#pragma unroll
  for (int ot = 0; ot < OT; ++ot) {
    const float4 b4 = *reinterpret_cast<const float4*>(&bias[ot * 16 + lg * 4]);
#pragma unroll
    for (int pt = 0; pt < 4; ++pt) {
      const int row = pt * 16 + lr;
      float v0 = acc[ot][pt][0] + b4.x;
      float v1 = acc[ot][pt][1] + b4.y;
      float v2 = acc[ot][pt][2] + b4.z;
      float v3 = acc[ot][pt][3] + b4.w;
      if (RELU) {
        v0 = fmaxf(v0, 0.0f); v1 = fmaxf(v1, 0.0f);
        v2 = fmaxf(v2, 0.0f); v3 = fmaxf(v3, 0.0f);
      }
      f16x4 h;
      h[0] = (_Float16)v0; h[1] = (_Float16)v1; h[2] = (_Float16)v2; h[3] = (_Float16)v3;
      *reinterpret_cast<f16x4*>(&act[swz(row, ot * 16 + lg * 4)]) = h;
    }
  }
}

// =========================================================================
// Kernel 2: fused MLPs; weights from pre-packed images (straight copies)
// =========================================================================
__global__ __launch_bounds__(BLOCK, 2) void ngp_mlp(
    const unsigned* __restrict__ feats, const float* __restrict__ dirs,
    const _Float16* __restrict__ pW, const float* __restrict__ pB,
    float* __restrict__ out, int n) {
  __shared__ __align__(16) _Float16 sAct[4 * 4096];
  __shared__ __align__(16) _Float16 sWp[11264];
  __shared__ __align__(16) float sB[208];

  const int tid = threadIdx.x;
  const int lane = tid & 63, wid = tid >> 6;
  const int lr = lane & 15, lg = lane >> 4;
  _Float16* myAct = &sAct[wid * 4096];
  const int blockBase = blockIdx.x * BLOCK;
  const int base64 = blockBase + wid * 64;

  int i = blockBase + tid;
  if (i >= n) i = n - 1;

  float sh[16];
  {
    const float dxr = dirs[3 * i + 0], dyr = dirs[3 * i + 1], dzr = dirs[3 * i + 2];
    const float invn = 1.0f / sqrtf(dxr * dxr + dyr * dyr + dzr * dzr);
    const float x = dxr * invn, y = dyr * invn, z = dzr * invn;
    const float x2 = x * x, y2 = y * y, z2 = z * z;
    sh[0] = 0.28209479177387814f;
    sh[1] = -0.48860251190291987f * y;
    sh[2] = 0.48860251190291987f * z;
    sh[3] = -0.48860251190291987f * x;
    sh[4] = 1.0925484305920792f * x * y;
    sh[5] = -1.0925484305920792f * y * z;
    sh[6] = 0.31539156525252005f * (2.0f * z2 - x2 - y2);
    sh[7] = -1.0925484305920792f * x * z;
    sh[8] = 0.5462742152960396f * (x2 - y2);
    sh[9] = -0.5900435899266435f * y * (3.0f * x2 - y2);
    sh[10] = 2.890611442640554f * x * y * z;
    sh[11] = -0.4570457994644658f * y * (4.0f * z2 - x2 - y2);
    sh[12] = 0.3731763325901154f * z * (2.0f * z2 - 3.0f * x2 - 3.0f * y2);
    sh[13] = -0.4570457994644658f * x * (4.0f * z2 - x2 - y2);
    sh[14] = 1.445305721320277f * z * (x2 - y2);
    sh[15] = -0.5900435899266435f * x * (x2 - 3.0f * y2);
  }

  // ---- Phase-1 weights: straight vector copy of packed image ----
  {
    const f16x8* s = reinterpret_cast<const f16x8*>(pW);
    f16x8* d = reinterpret_cast<f16x8*>(sWp);
    for (int t = tid; t < 896; t += BLOCK) d[t] = s[t];
    for (int t = tid; t < 144; t += BLOCK) sB[t] = pB[t];
  }
  __syncthreads();

  // ---- Density layer 0: B-frags straight from feat buffer ----
  {
    f32x4 acc[4][4];
    {
      f16x8 bF[4];
#pragma unroll
      for (int pt = 0; pt < 4; ++pt) {
        int gpt = base64 + pt * 16 + lr;
        if (gpt >= n) gpt = n - 1;
        union { unsigned u[4]; f16x8 v; } cv;
#pragma unroll
        for (int m = 0; m < 4; ++m) cv.u[m] = feats[(unsigned)(4 * lg + m) * (unsigned)n + gpt];
        bF[pt] = cv.v;
      }
#pragma unroll
      for (int ot = 0; ot < 4; ++ot)
#pragma unroll
        for (int pt = 0; pt < 4; ++pt) acc[ot][pt] = 0.0f;
#pragma unroll
      for (int ot = 0; ot < 4; ++ot) {
        const f16x8 aF = *reinterpret_cast<const f16x8*>(&sWp[(lg * 64 + ot * 16 + lr) * 8]);
#pragma unroll
        for (int pt = 0; pt < 4; ++pt)
          acc[ot][pt] = __builtin_amdgcn_mfma_f32_16x16x32_f16(aF, bF[pt], acc[ot][pt], 0, 0, 0);
      }
    }
    epilogue_act<4, true>(acc, sB + 0, myAct, lane);
  }
  {
    f32x4 acc[4][4];
    mfma_tiles<2, 4>(myAct, sWp + 2048, lane, acc);
    epilogue_act<4, true>(acc, sB + 64, myAct, lane);
  }
  {
    f32x4 acc[1][4];
    mfma_tiles<2, 1>(myAct, sWp + 6144, lane, acc);
    const float4 b4 = *reinterpret_cast<const float4*>(&sB[128 + lg * 4]);
#pragma unroll
    for (int pt = 0; pt < 4; ++pt) {
      const int row = pt * 16 + lr;
      const int gpt = base64 + row;
      const float v0 = acc[0][pt][0] + b4.x;
      const float v1 = acc[0][pt][1] + b4.y;
      const float v2 = acc[0][pt][2] + b4.z;
      const float v3 = acc[0][pt][3] + b4.w;
      if (lg == 0) {
        if (gpt < n) out[gpt * 4] = v0;  // sigma
        myAct[swz(row, 1)] = (_Float16)v1;
        myAct[swz(row, 2)] = (_Float16)v2;
        myAct[swz(row, 3)] = (_Float16)v3;
      } else {
        f16x4 h;
        h[0] = (_Float16)v0; h[1] = (_Float16)v1; h[2] = (_Float16)v2; h[3] = (_Float16)v3;
        *reinterpret_cast<f16x4*>(&myAct[swz(row, lg * 4)]) = h;
      }
    }
  }

  myAct[swz(lane, 0)] = (_Float16)0.0f;
  {
    f16x8 v0, v1;
#pragma unroll
    for (int j = 0; j < 8; ++j) { v0[j] = (_Float16)sh[j]; v1[j] = (_Float16)sh[8 + j]; }
    *reinterpret_cast<f16x8*>(&myAct[swz(lane, 16)]) = v0;
    *reinterpret_cast<f16x8*>(&myAct[swz(lane, 24)]) = v1;
  }
  __syncthreads();

  // ---- Phase-2 weights ----
  {
    const f16x8* s = reinterpret_cast<const f16x8*>(pW + 7168);
    f16x8* d = reinterpret_cast<f16x8*>(sWp);
    for (int t = tid; t < 1408; t += BLOCK) d[t] = s[t];
    for (int t = tid; t < 208; t += BLOCK) sB[t] = pB[144 + t];
  }
  __syncthreads();

  {
    f32x4 acc[4][4];
    mfma_tiles<1, 4>(myAct, sWp + 0, lane, acc);
    epilogue_act<4, true>(acc, sB + 0, myAct, lane);
  }
  {
    f32x4 acc[4][4];
    mfma_tiles<2, 4>(myAct, sWp + 2048, lane, acc);
    epilogue_act<4, true>(acc, sB + 64, myAct, lane);
  }
  {
    f32x4 acc[4][4];
    mfma_tiles<2, 4>(myAct, sWp + 6144, lane, acc);
    epilogue_act<4, true>(acc, sB + 128, myAct, lane);
  }
  {
    f32x4 acc[1][4];
    mfma_tiles<2, 1>(myAct, sWp + 10240, lane, acc);
    if (lg == 0) {
      const float4 b4 = *reinterpret_cast<const float4*>(&sB[192]);
#pragma unroll
      for (int pt = 0; pt < 4; ++pt) {
        const int gpt = base64 + pt * 16 + lr;
        if (gpt < n) {
          out[gpt * 4 + 1] = 1.0f / (1.0f + __expf(-(acc[0][pt][0] + b4.x)));
          out[gpt * 4 + 2] = 1.0f / (1.0f + __expf(-(acc[0][pt][1] + b4.y)));
          out[gpt * 4 + 3] = 1.0f / (1.0f + __expf(-(acc[0][pt][2] + b4.z)));
        }
      }
    }
  }
}

// =========================================================================
// Fallback: R2's proven self-contained fused kernel (ws too small)
// =========================================================================
__global__ __launch_bounds__(BLOCK, 2) void ngp_mfma(
    const float* __restrict__ pos, const float* __restrict__ dirs, const float* __restrict__ emb,
    const float* __restrict__ dw0, const float* __restrict__ db0,
    const float* __restrict__ dw1, const float* __restrict__ db1,
    const float* __restrict__ dw2, const float* __restrict__ db2,
    const float* __restrict__ cw0, const float* __restrict__ cb0,
    const float* __restrict__ cw1, const float* __restrict__ cb1,
    const float* __restrict__ cw2, const float* __restrict__ cb2,
    const float* __restrict__ cw3, const float* __restrict__ cb3,
    float* __restrict__ out, int n) {
  __shared__ __align__(16) _Float16 sAct[4 * 4096];
  __shared__ __align__(16) _Float16 sWp[11264];
  __shared__ __align__(16) float sB[208];

  const int tid = threadIdx.x;
  const int lane = tid & 63, wid = tid >> 6;
  const int lr = lane & 15, lg = lane >> 4;
  _Float16* myAct = &sAct[wid * 4096];
  const int blockBase = blockIdx.x * BLOCK;

  int i = blockBase + tid;
  if (i >= n) i = n - 1;

  const float px = pos[3 * i + 0], py = pos[3 * i + 1], pz = pos[3 * i + 2];
  const float pn0 = fminf(fmaxf((px + 1.0f) * 0.5f, 0.0f), 1.0f);
  const float pn1 = fminf(fmaxf((py + 1.0f) * 0.5f, 0.0f), 1.0f);
  const float pn2 = fminf(fmaxf((pz + 1.0f) * 0.5f, 0.0f), 1.0f);

  float feat[32];
  const float2* emb2 = reinterpret_cast<const float2*>(emb);
#pragma unroll
  for (int l = 0; l < 16; ++l) {
    const int res = kRes[l];
    const unsigned mask = kMask[l];
    const float2* elvl = emb2 + kOff[l];
    float w0, w1, w2;
    unsigned g0, g1, g2;
    { const float s = pn0 * (float)(res - 1); const float fg = floorf(s); w0 = s - fg; g0 = (unsigned)fg; }
    { const float s = pn1 * (float)(res - 1); const float fg = floorf(s); w1 = s - fg; g1 = (unsigned)fg; }
    { const float s = pn2 * (float)(res - 1); const float fg = floorf(s); w2 = s - fg; g2 = (unsigned)fg; }
    const unsigned rm = (unsigned)(res - 1);
    const unsigned g0p = (g0 + 1u > rm) ? rm : g0 + 1u;
    const unsigned g1p = (g1 + 1u > rm) ? rm : g1 + 1u;
    const unsigned g2p = (g2 + 1u > rm) ? rm : g2 + 1u;
    const unsigned hx0 = g0 * kP1, hx1 = g0p * kP1;
    const unsigned hy0 = g1 * kP2, hy1 = g1p * kP2;
    const unsigned hz0 = g2 * kP3, hz1 = g2p * kP3;
    float f0 = 0.0f, f1 = 0.0f;
#pragma unroll
    for (int c = 0; c < 8; ++c) {
      const bool bx = (c >> 2) & 1, by = (c >> 1) & 1, bz = c & 1;
      const unsigned h = ((bx ? hx1 : hx0) + (by ? hy1 : hy0) + (bz ? hz1 : hz0)) & mask;
      const float2 e = elvl[h];
      const float wp = (bx ? w0 : 1.0f - w0) * (by ? w1 : 1.0f - w1) * (bz ? w2 : 1.0f - w2);
      f0 = __builtin_fmaf(wp, e.x, f0);
      f1 = __builtin_fmaf(wp, e.y, f1);
    }
    feat[2 * l + 0] = f0;
    feat[2 * l + 1] = f1;
  }

  float sh[16];
  {
    const float dxr = dirs[3 * i + 0], dyr = dirs[3 * i + 1], dzr = dirs[3 * i + 2];
    const float invn = 1.0f / sqrtf(dxr * dxr + dyr * dyr + dzr * dzr);
    const float x = dxr * invn, y = dyr * invn, z = dzr * invn;
    const float x2 = x * x, y2 = y * y, z2 = z * z;
    sh[0] = 0.28209479177387814f;
    sh[1] = -0.48860251190291987f * y;
    sh[2] = 0.48860251190291987f * z;
    sh[3] = -0.48860251190291987f * x;
    sh[4] = 1.0925484305920792f * x * y;
    sh[5] = -1.0925484305920792f * y * z;
    sh[6] = 0.31539156525252005f * (2.0f * z2 - x2 - y2);
    sh[7] = -1.0925484305920792f * x * z;
    sh[8] = 0.5462742152960396f * (x2 - y2);
    sh[9] = -0.5900435899266435f * y * (3.0f * x2 - y2);
    sh[10] = 2.890611442640554f * x * y * z;
    sh[11] = -0.4570457994644658f * y * (4.0f * z2 - x2 - y2);
    sh[12] = 0.3731763325901154f * z * (2.0f * z2 - 3.0f * x2 - 3.0f * y2);
    sh[13] = -0.4570457994644658f * x * (4.0f * z2 - x2 - y2);
    sh[14] = 1.445305721320277f * z * (x2 - y2);
    sh[15] = -0.5900435899266435f * x * (x2 - 3.0f * y2);
  }

#pragma unroll
  for (int cb = 0; cb < 4; ++cb) {
    f16x8 v;
#pragma unroll
    for (int j = 0; j < 8; ++j) v[j] = (_Float16)feat[cb * 8 + j];
    *reinterpret_cast<f16x8*>(&myAct[swz(lane, cb * 8)]) = v;
  }

  stage_w(sWp + 0, dw0, 32, 64, 32, 64, 0, tid);
  stage_w(sWp + 2048, dw1, 64, 64, 64, 64, 0, tid);
  stage_w(sWp + 6144, dw2, 64, 16, 64, 16, 0, tid);
  stage_b(sB + 0, db0, 64, 64, tid);
  stage_b(sB + 64, db1, 64, 64, tid);
  stage_b(sB + 128, db2, 16, 16, tid);
  __syncthreads();

  {
    f32x4 acc[4][4];
    mfma_tiles<1, 4>(myAct, sWp + 0, lane, acc);
    epilogue_act<4, true>(acc, sB + 0, myAct, lane);
  }
  {
    f32x4 acc[4][4];
    mfma_tiles<2, 4>(myAct, sWp + 2048, lane, acc);
    epilogue_act<4, true>(acc, sB + 64, myAct, lane);
  }
  {
    f32x4 acc[1][4];
    mfma_tiles<2, 1>(myAct, sWp + 6144, lane, acc);
    const float4 b4 = *reinterpret_cast<const float4*>(&sB[128 + lg * 4]);
#pragma unroll
    for (int pt = 0; pt < 4; ++pt) {
      const int row = pt * 16 + lr;
      const int gpt = blockBase + wid * 64 + row;
      const float v0 = acc[0][pt][0] + b4.x;
      const float v1 = acc[0][pt][1] + b4.y;
      const float v2 = acc[0][pt][2] + b4.z;
      const float v3 = acc[0][pt][3] + b4.w;
      if (lg == 0) {
        if (gpt < n) out[gpt * 4] = v0;
        myAct[swz(row, 1)] = (_Float16)v1;
        myAct[swz(row, 2)] = (_Float16)v2;
        myAct[swz(row, 3)] = (_Float16)v3;
      } else {
        f16x4 h;
        h[0] = (_Float16)v0; h[1] = (_Float16)v1; h[2] = (_Float16)v2; h[3] = (_Float16)v3;
        *reinterpret_cast<f16x4*>(&myAct[swz(row, lg * 4)]) = h;
      }
    }
  }

  myAct[swz(lane, 0)] = (_Float16)0.0f;
  {
    f16x8 v0, v1;
#pragma unroll
    for (int j = 0; j < 8; ++j) { v0[j] = (_Float16)sh[j]; v1[j] = (_Float16)sh[8 + j]; }
    *reinterpret_cast<f16x8*>(&myAct[swz(lane, 16)]) = v0;
    *reinterpret_cast<f16x8*>(&myAct[swz(lane, 24)]) = v1;
  }
  __syncthreads();

  stage_w(sWp + 0, cw0, 31, 64, 32, 64, 1, tid);
  stage_w(sWp + 2048, cw1, 64, 64, 64, 64, 0, tid);
  stage_w(sWp + 6144, cw2, 64, 64, 64, 64, 0, tid);
  stage_w(sWp + 10240, cw3, 64, 3, 64, 16, 0, tid);
  stage_b(sB + 0, cb0, 64, 64, tid);
  stage_b(sB + 64, cb1, 64, 64, tid);
  stage_b(sB + 128, cb2, 64, 64, tid);
  stage_b(sB + 192, cb3, 3, 16, tid);
  __syncthreads();

  {
    f32x4 acc[4][4];
    mfma_tiles<1, 4>(myAct, sWp + 0, lane, acc);
    epilogue_act<4, true>(acc, sB + 0, myAct, lane);
  }
  {
    f32x4 acc[4][4];
    mfma_tiles<2, 4>(myAct, sWp + 2048, lane, acc);
    epilogue_act<4, true>(acc, sB + 64, myAct, lane);
  }
  {
    f32x4 acc[4][4];
    mfma_tiles<2, 4>(myAct, sWp + 6144, lane, acc);
    epilogue_act<4, true>(acc, sB + 128, myAct, lane);
  }
  {
    f32x4 acc[1][4];
    mfma_tiles<2, 1>(myAct, sWp + 10240, lane, acc);
    if (lg == 0) {
      const float4 b4 = *reinterpret_cast<const float4*>(&sB[192]);
#pragma unroll
      for (int pt = 0; pt < 4; ++pt) {
        const int gpt = blockBase + wid * 64 + pt * 16 + lr;
        if (gpt < n) {
          out[gpt * 4 + 1] = 1.0f / (1.0f + __expf(-(acc[0][pt][0] + b4.x)));
          out[gpt * 4 + 2] = 1.0f / (1.0f + __expf(-(acc[0][pt][1] + b4.y)));
          out[gpt * 4 + 3] = 1.0f / (1.0f + __expf(-(acc[0][pt][2] + b4.z)));
        }
      }
    }
  }
}

extern "C" void kernel_launch(void* const* d_in, const int* in_sizes, int n_in,
                              void* d_out, int out_size, void* d_ws, size_t ws_size,
                              hipStream_t stream) {
  const float* pos = (const float*)d_in[0];
  const float* dirs = (const float*)d_in[1];
  const float* emb = (const float*)d_in[2];
  const float* dw0 = (const float*)d_in[3];
  const float* db0 = (const float*)d_in[4];
  const float* dw1 = (const float*)d_in[5];
  const float* db1 = (const float*)d_in[6];
  const float* dw2 = (const float*)d_in[7];
  const float* db2 = (const float*)d_in[8];
  const float* cw0 = (const float*)d_in[9];
  const float* cb0 = (const float*)d_in[10];
  const float* cw1 = (const float*)d_in[11];
  const float* cb1 = (const float*)d_in[12];
  const float* cw2 = (const float*)d_in[13];
  const float* cb2 = (const float*)d_in[14];
  const float* cw3 = (const float*)d_in[15];
  const float* cb3 = (const float*)d_in[16];
  float* out = (float*)d_out;

  const int n = in_sizes[0] / 3;
  const int nTab = in_sizes[2] / 2;
  const int grid = (n + BLOCK - 1) / BLOCK;
  const size_t featBytes = (size_t)16 * (size_t)n * 4;
  const size_t rBytes = (size_t)kFineEntries * 64;
  const size_t tabSmallBytes = (size_t)kSmallEntries * 4;
  const size_t tabFullBytes = (size_t)nTab * 4;
  const size_t packBytes = 18432 * 2 + 352 * 4 + 64;  // pW + pB + pad
  const size_t need1 = rBytes + featBytes + tabSmallBytes + packBytes;
  const size_t need2 = tabFullBytes + featBytes + packBytes;

  if (ws_size >= need1) {
    // Tier 1: fused fine+coarse gather, level-4 level-major, prepacked MLP
    u32x4* R = (u32x4*)d_ws;
    f16x2* feats = (f16x2*)((char*)d_ws + rBytes);
    f16x2* tabS = (f16x2*)((char*)d_ws + rBytes + featBytes);
    _Float16* pW = (_Float16*)((char*)d_ws + rBytes + featBytes + tabSmallBytes);
    float* pB = (float*)((char*)pW + 18432 * 2);
    cvt_emb<<<(kSmallEntries + BLOCK - 1) / BLOCK, BLOCK, 0, stream>>>(
        (const float2*)emb, tabS, kSmallEntries);
    build_R<<<kFineEntries / 64, BLOCK, 0, stream>>>((const float2*)emb, R);
    pack_weights<<<8, BLOCK, 0, stream>>>(dw0, db0, dw1, db1, dw2, db2, cw0, cb0, cw1,
                                          cb1, cw2, cb2, cw3, cb3, pW, pB);
    gather_all<<<(n + 63) / 64, BLOCK, 0, stream>>>(pos, R, tabS, (unsigned*)feats, n);
    hash_gather<<<grid, BLOCK, 0, stream>>>(pos, tabS, feats, n, grid, 4);
    ngp_mlp<<<grid, BLOCK, 0, stream>>>((const unsigned*)feats, dirs, pW, pB, out, n);
  } else if (ws_size >= need2) {
    // Tier 2: level-major everything (R3 path) + prepacked MLP
    f16x2* tab = (f16x2*)d_ws;
    f16x2* feats = (f16x2*)((char*)d_ws + tabFullBytes);
    _Float16* pW = (_Float16*)((char*)d_ws + tabFullBytes + featBytes);
    float* pB = (float*)((char*)pW + 18432 * 2);
    cvt_emb<<<(nTab + BLOCK - 1) / BLOCK, BLOCK, 0, stream>>>((const float2*)emb, tab, nTab);
    pack_weights<<<8, BLOCK, 0, stream>>>(dw0, db0, dw1, db1, dw2, db2, cw0, cb0, cw1,
                                          cb1, cw2, cb2, cw3, cb3, pW, pB);
    hash_gather<<<16 * grid, BLOCK, 0, stream>>>(pos, tab, feats, n, grid, 0);
    ngp_mlp<<<grid, BLOCK, 0, stream>>>((const unsigned*)feats, dirs, pW, pB, out, n);
  } else {
    ngp_mfma<<<grid, BLOCK, 0, stream>>>(pos, dirs, emb, dw0, db0, dw1, db1, dw2, db2,
                                         cw0, cb0, cw1, cb1, cw2, cb2, cw3, cb3, out, n);
  }
}

// Round 6
// 381.685 us; speedup vs baseline: 7.5564x; 1.1321x over previous
//
#include <hip/hip_runtime.h>

#define BLOCK 256

typedef _Float16 f16x8 __attribute__((ext_vector_type(8)));
typedef _Float16 f16x4 __attribute__((ext_vector_type(4)));
typedef _Float16 f16x2 __attribute__((ext_vector_type(2)));
typedef float f32x4 __attribute__((ext_vector_type(4)));
typedef unsigned u32x4 __attribute__((ext_vector_type(4)));

// ---- Hash-grid compile-time tables -------------------------------------
constexpr unsigned kP1 = 73856093u, kP2 = 19349663u, kP3 = 83492791u;
constexpr int kRes[16] = {16, 32, 64, 128, 256, 512, 512, 512,
                          512, 512, 512, 512, 512, 512, 512, 512};
constexpr unsigned kMask[16] = {4095u, 32767u, 262143u, 524287u, 524287u, 524287u,
                                524287u, 524287u, 524287u, 524287u, 524287u, 524287u,
                                524287u, 524287u, 524287u, 524287u};
constexpr int kOff[16] = {0,       4096,    36864,   299008,  823296,  1347584,
                          1871872, 2396160, 2920448, 3444736, 3969024, 4493312,
                          5017600, 5541888, 6066176, 6590464};
constexpr int kNumFine = 11;            // levels 5..15 share res=512, size=2^19
constexpr int kFineEntries = 524288;
constexpr int kSmallEntries = 1347584;  // entries of levels 0..4 (= kOff[5])

union U32F16 { unsigned u; f16x2 h; };

// =========================================================================
// Kernel 0: fp32 embedding -> f16 (levels 0..4 region)
// =========================================================================
__global__ __launch_bounds__(BLOCK) void cvt_emb(const float2* __restrict__ emb,
                                                 f16x2* __restrict__ tab, int total) {
  const int i = blockIdx.x * BLOCK + threadIdx.x;
  if (i < total) {
    const float2 e = emb[i];
    f16x2 h;
    h.x = (_Float16)e.x;
    h.y = (_Float16)e.y;
    tab[i] = h;
  }
}

// =========================================================================
// Kernel 0b: interleaved fine table R[h] = 64-B row; dword m (m<11) = f16x2
// of level 5+m at entry h.
// =========================================================================
__global__ __launch_bounds__(BLOCK) void build_R(const float2* __restrict__ emb,
                                                 u32x4* __restrict__ R) {
  const int tid = threadIdx.x;
  const int j = tid & 3;
  const int row = blockIdx.x * 64 + (tid >> 2);
  u32x4 v;
#pragma unroll
  for (int m = 0; m < 4; ++m) {
    const int lvl = 4 * j + m;
    unsigned u = 0;
    if (lvl < kNumFine) {
      const float2 e = emb[kOff[5 + lvl] + row];
      U32F16 cv;
      cv.h.x = (_Float16)e.x;
      cv.h.y = (_Float16)e.y;
      u = cv.u;
    }
    v[m] = u;
  }
  R[row * 4 + j] = v;
}

// =========================================================================
// Weight pre-pack. Packed f16 layout [K/8][N][8]:
//  ph1: dw0@0(2048) dw1@2048(4096) dw2@6144(1024)           -> 7168
//  ph2a: cw0@7168(2048) cw1@9216(4096)                      -> 6144
//  ph2b: cw2@13312(4096) cw3@17408(1024)                    -> 5120
// biases fp32 pB[352]: db0@0 db1@64 db2@128 cb0@144 cb1@208 cb2@272 cb3@336
// =========================================================================
__device__ __forceinline__ void stage_w(_Float16* dst, const float* __restrict__ W,
                                        int Ksrc, int Nsrc, int KP, int NP, int rowShift,
                                        int tid) {
  const int total = KP * NP;
  for (int t = tid; t < total; t += BLOCK) {
    const int j = t & 7;
    const int nn = (t >> 3) % NP;
    const int kb = t / (8 * NP);
    const int k = kb * 8 + j - rowShift;
    float v = 0.0f;
    if (k >= 0 && k < Ksrc && nn < Nsrc) v = W[k * Nsrc + nn];
    dst[t] = (_Float16)v;
  }
}

__device__ __forceinline__ void stage_b(float* dst, const float* __restrict__ B,
                                        int nsrc, int np, int tid) {
  for (int t = tid; t < np; t += BLOCK) dst[t] = (t < nsrc) ? B[t] : 0.0f;
}

__global__ __launch_bounds__(BLOCK) void pack_weights(
    const float* __restrict__ dw0, const float* __restrict__ db0,
    const float* __restrict__ dw1, const float* __restrict__ db1,
    const float* __restrict__ dw2, const float* __restrict__ db2,
    const float* __restrict__ cw0, const float* __restrict__ cb0,
    const float* __restrict__ cw1, const float* __restrict__ cb1,
    const float* __restrict__ cw2, const float* __restrict__ cb2,
    const float* __restrict__ cw3, const float* __restrict__ cb3,
    _Float16* __restrict__ pW, float* __restrict__ pB) {
  const int b = blockIdx.x, tid = threadIdx.x;
  switch (b) {
    case 0: stage_w(pW + 0, dw0, 32, 64, 32, 64, 0, tid); break;
    case 1: stage_w(pW + 2048, dw1, 64, 64, 64, 64, 0, tid); break;
    case 2: stage_w(pW + 6144, dw2, 64, 16, 64, 16, 0, tid); break;
    case 3: stage_w(pW + 7168, cw0, 31, 64, 32, 64, 1, tid); break;
    case 4: stage_w(pW + 9216, cw1, 64, 64, 64, 64, 0, tid); break;
    case 5: stage_w(pW + 13312, cw2, 64, 64, 64, 64, 0, tid); break;
    case 6: stage_w(pW + 17408, cw3, 64, 3, 64, 16, 0, tid); break;
    default:
      for (int t = tid; t < 352; t += BLOCK) {
        float v;
        if (t < 64) v = db0[t];
        else if (t < 128) v = db1[t - 64];
        else if (t < 144) v = (t - 128) < 16 ? db2[t - 128] : 0.0f;
        else if (t < 208) v = cb0[t - 144];
        else if (t < 272) v = cb1[t - 208];
        else if (t < 336) v = cb2[t - 272];
        else v = (t - 336) < 3 ? cb3[t - 336] : 0.0f;
        pB[t] = v;
      }
  }
}

// =========================================================================
// MFMA machinery (verified R2-R5)
// =========================================================================
__device__ __forceinline__ int swz(int row, int col) {
  return row * 64 + (col ^ ((row & 7) << 3));
}

template <int KT, int OT>
__device__ __forceinline__ void mfma_tiles(const _Float16* act, const _Float16* wp,
                                           int lane, f32x4 (&acc)[OT][4]) {
  const int lr = lane & 15, lg = lane >> 4;
  f16x8 bF[4][KT];
#pragma unroll
  for (int pt = 0; pt < 4; ++pt)
#pragma unroll
    for (int kf = 0; kf < KT; ++kf) {
      const int row = pt * 16 + lr;
      bF[pt][kf] = *reinterpret_cast<const f16x8*>(&act[swz(row, kf * 32 + lg * 8)]);
    }
#pragma unroll
  for (int ot = 0; ot < OT; ++ot)
#pragma unroll
    for (int pt = 0; pt < 4; ++pt) acc[ot][pt] = 0.0f;
#pragma unroll
  for (int ot = 0; ot < OT; ++ot) {
#pragma unroll
    for (int kf = 0; kf < KT; ++kf) {
      const f16x8 aF =
          *reinterpret_cast<const f16x8*>(&wp[((kf * 4 + lg) * (OT * 16) + ot * 16 + lr) * 8]);
#pragma unroll
      for (int pt = 0; pt < 4; ++pt)
        acc[ot][pt] = __builtin_amdgcn_mfma_f32_16x16x32_f16(aF, bF[pt][kf], acc[ot][pt], 0, 0, 0);
    }
  }
}

template <int OT, bool RELU>
__device__ __forceinline__ void epilogue_act(const f32x4 (&acc)[OT][4], const float* bias,
                                             _Float16* act, int lane) {
  const int lr = lane & 15, lg = lane >> 4;
#pragma unroll
  for (int ot = 0; ot < OT; ++ot) {
    const float4 b4 = *reinterpret_cast<const float4*>(&bias[ot * 16 + lg * 4]);
#pragma unroll
    for (int pt = 0; pt < 4; ++pt) {
      const int row = pt * 16 + lr;
      float v0 = acc[ot][pt][0] + b4.x;
      float v1 = acc[ot][pt][1] + b4.y;
      float v2 = acc[ot][pt][2] + b4.z;
      float v3 = acc[ot][pt][3] + b4.w;
      if (RELU) {
        v0 = fmaxf(v0, 0.0f); v1 = fmaxf(v1, 0.0f);
        v2 = fmaxf(v2, 0.0f); v3 = fmaxf(v3, 0.0f);
      }
      f16x4 h;
      h[0] = (_Float16)v0; h[1] = (_Float16)v1; h[2] = (_Float16)v2; h[3] = (_Float16)v3;
      *reinterpret_cast<f16x4*>(&act[swz(row, ot * 16 + lg * 4)]) = h;
    }
  }
}

// =========================================================================
// THE kernel: gather (all 16 levels) + full MLP, fused.
// Gather: 4-lane groups per point, 4 rounds -> 64 rows per wave.
//   lane j: fine R-row dwords 4j..4j+3 (levels 5+4j..) via NT dwordx4,
//           coarse level j+1 (8 x 4B, L2-resident),
//           level 0 split 2 corners/lane from LDS + shfl reduce.
// MLP: identical to verified ngp_mlp, weights in 3 staging chunks (14 KB).
// =========================================================================
__global__ __launch_bounds__(BLOCK, 2) void ngp_fused_all(
    const float* __restrict__ pos, const float* __restrict__ dirs,
    const u32x4* __restrict__ R, const unsigned* __restrict__ tabSu,
    const _Float16* __restrict__ pW, const float* __restrict__ pB,
    float* __restrict__ out, int n) {
  __shared__ __align__(16) _Float16 sAct[4 * 4096];  // 32 KB
  __shared__ __align__(16) _Float16 sWp[7168];       // 14 KB
  __shared__ __align__(16) float sB[352];            // 1.4 KB
  __shared__ __align__(16) unsigned sL0[4096];       // 16 KB level-0 table

  const int tid = threadIdx.x;
  const int lane = tid & 63, wid = tid >> 6;
  const int lr = lane & 15, lg = lane >> 4;
  _Float16* myAct = &sAct[wid * 4096];
  const int blockBase = blockIdx.x * BLOCK;
  const int base64 = blockBase + wid * 64;

  // ---- stage: level-0 table (16 KB) + phase-1 weights + all biases ----
  {
    const uint4* s0 = reinterpret_cast<const uint4*>(tabSu);
    uint4* d0 = reinterpret_cast<uint4*>(sL0);
#pragma unroll
    for (int k = 0; k < 4; ++k) d0[tid + k * BLOCK] = s0[tid + k * BLOCK];
    const f16x8* s = reinterpret_cast<const f16x8*>(pW);
    f16x8* d = reinterpret_cast<f16x8*>(sWp);
    for (int t = tid; t < 896; t += BLOCK) d[t] = s[t];
    for (int t = tid; t < 352; t += BLOCK) sB[t] = pB[t];
  }
  __syncthreads();

  // ---- gather phase ----
  const int j = lane & 3;
  const int g = lane >> 2;
  const int resC = kRes[j + 1];
  const unsigned maskC = kMask[j + 1];
  const unsigned offC = (unsigned)kOff[j + 1];
  const unsigned rmC = (unsigned)(resC - 1);
  const unsigned zbx = (unsigned)((j >> 1) & 1), zby = (unsigned)(j & 1);

#pragma unroll
  for (int ii = 0; ii < 4; ++ii) {
    const int row = ii * 16 + g;
    int p = base64 + row;
    if (p >= n) p = n - 1;
    const float px = pos[3 * p + 0], py = pos[3 * p + 1], pz = pos[3 * p + 2];
    const float pn0 = fminf(fmaxf((px + 1.0f) * 0.5f, 0.0f), 1.0f);
    const float pn1 = fminf(fmaxf((py + 1.0f) * 0.5f, 0.0f), 1.0f);
    const float pn2 = fminf(fmaxf((pz + 1.0f) * 0.5f, 0.0f), 1.0f);

    // fine (res 512)
    float fw0, fw1, fw2;
    unsigned fg0, fg1, fg2;
    { const float s = pn0 * 511.0f, fl = floorf(s); fw0 = s - fl; fg0 = (unsigned)fl; }
    { const float s = pn1 * 511.0f, fl = floorf(s); fw1 = s - fl; fg1 = (unsigned)fl; }
    { const float s = pn2 * 511.0f, fl = floorf(s); fw2 = s - fl; fg2 = (unsigned)fl; }
    const unsigned fg0p = (fg0 + 1u > 511u) ? 511u : fg0 + 1u;
    const unsigned fg1p = (fg1 + 1u > 511u) ? 511u : fg1 + 1u;
    const unsigned fg2p = (fg2 + 1u > 511u) ? 511u : fg2 + 1u;
    const unsigned fx0 = fg0 * kP1, fx1 = fg0p * kP1;
    const unsigned fy0 = fg1 * kP2, fy1 = fg1p * kP2;
    const unsigned fz0 = fg2 * kP3, fz1 = fg2p * kP3;

    // coarse level j+1
    float cwx, cwy, cwz;
    unsigned cg0, cg1, cg2;
    { const float s = pn0 * (float)(resC - 1), fl = floorf(s); cwx = s - fl; cg0 = (unsigned)fl; }
    { const float s = pn1 * (float)(resC - 1), fl = floorf(s); cwy = s - fl; cg1 = (unsigned)fl; }
    { const float s = pn2 * (float)(resC - 1), fl = floorf(s); cwz = s - fl; cg2 = (unsigned)fl; }
    const unsigned cg0p = (cg0 + 1u > rmC) ? rmC : cg0 + 1u;
    const unsigned cg1p = (cg1 + 1u > rmC) ? rmC : cg1 + 1u;
    const unsigned cg2p = (cg2 + 1u > rmC) ? rmC : cg2 + 1u;
    const unsigned cx0 = cg0 * kP1, cx1 = cg0p * kP1;
    const unsigned cy0 = cg1 * kP2, cy1 = cg1p * kP2;
    const unsigned cz0 = cg2 * kP3, cz1 = cg2p * kP3;

    // level 0 (res 16)
    float zwx, zwy, zwz;
    unsigned zg0, zg1, zg2;
    { const float s = pn0 * 15.0f, fl = floorf(s); zwx = s - fl; zg0 = (unsigned)fl; }
    { const float s = pn1 * 15.0f, fl = floorf(s); zwy = s - fl; zg1 = (unsigned)fl; }
    { const float s = pn2 * 15.0f, fl = floorf(s); zwz = s - fl; zg2 = (unsigned)fl; }
    const unsigned zg0p = (zg0 + 1u > 15u) ? 15u : zg0 + 1u;
    const unsigned zg1p = (zg1 + 1u > 15u) ? 15u : zg1 + 1u;
    const unsigned zg2p = (zg2 + 1u > 15u) ? 15u : zg2 + 1u;
    const unsigned zx = (zbx ? zg0p : zg0) * kP1;
    const unsigned zy = (zby ? zg1p : zg1) * kP2;
    const unsigned zz0 = zg2 * kP3, zz1 = zg2p * kP3;

    // ---- issue ALL VMEM loads before any consumption ----
    u32x4 F[8];
#pragma unroll
    for (int c = 0; c < 8; ++c) {
      const bool bx = (c >> 2) & 1, by = (c >> 1) & 1, bz = c & 1;
      const unsigned h = ((bx ? fx1 : fx0) + (by ? fy1 : fy0) + (bz ? fz1 : fz0)) & 524287u;
      F[c] = __builtin_nontemporal_load(&R[h * 4 + j]);
    }
    unsigned C[8];
#pragma unroll
    for (int c = 0; c < 8; ++c) {
      const bool bx = (c >> 2) & 1, by = (c >> 1) & 1, bz = c & 1;
      const unsigned h = ((bx ? cx1 : cx0) + (by ? cy1 : cy0) + (bz ? cz1 : cz0)) & maskC;
      C[c] = tabSu[offC + h];
    }
    // level-0 from LDS (2 corners for this lane)
    const unsigned A0 = sL0[(zx + zy + zz0) & 4095u];
    const unsigned A1 = sL0[(zx + zy + zz1) & 4095u];

    // ---- consume fine ----
    float fa[8] = {0.0f, 0.0f, 0.0f, 0.0f, 0.0f, 0.0f, 0.0f, 0.0f};
#pragma unroll
    for (int c = 0; c < 8; ++c) {
      const bool bx = (c >> 2) & 1, by = (c >> 1) & 1, bz = c & 1;
      const float wp = (bx ? fw0 : 1.0f - fw0) * (by ? fw1 : 1.0f - fw1) * (bz ? fw2 : 1.0f - fw2);
      U32F16 cv;
      cv.u = F[c][0]; fa[0] = __builtin_fmaf(wp, (float)cv.h.x, fa[0]); fa[1] = __builtin_fmaf(wp, (float)cv.h.y, fa[1]);
      cv.u = F[c][1]; fa[2] = __builtin_fmaf(wp, (float)cv.h.x, fa[2]); fa[3] = __builtin_fmaf(wp, (float)cv.h.y, fa[3]);
      cv.u = F[c][2]; fa[4] = __builtin_fmaf(wp, (float)cv.h.x, fa[4]); fa[5] = __builtin_fmaf(wp, (float)cv.h.y, fa[5]);
      cv.u = F[c][3]; fa[6] = __builtin_fmaf(wp, (float)cv.h.x, fa[6]); fa[7] = __builtin_fmaf(wp, (float)cv.h.y, fa[7]);
    }
    // ---- consume coarse ----
    float cf0 = 0.0f, cf1 = 0.0f;
#pragma unroll
    for (int c = 0; c < 8; ++c) {
      const bool bx = (c >> 2) & 1, by = (c >> 1) & 1, bz = c & 1;
      const float wp = (bx ? cwx : 1.0f - cwx) * (by ? cwy : 1.0f - cwy) * (bz ? cwz : 1.0f - cwz);
      U32F16 cv;
      cv.u = C[c];
      cf0 = __builtin_fmaf(wp, (float)cv.h.x, cf0);
      cf1 = __builtin_fmaf(wp, (float)cv.h.y, cf1);
    }
    // ---- level 0: 2 corners + 4-lane butterfly reduce ----
    float z0, z1;
    {
      const float wxy = (zbx ? zwx : 1.0f - zwx) * (zby ? zwy : 1.0f - zwy);
      const float w0 = wxy * (1.0f - zwz), w1 = wxy * zwz;
      U32F16 a, b;
      a.u = A0; b.u = A1;
      z0 = w0 * (float)a.h.x + w1 * (float)b.h.x;
      z1 = w0 * (float)a.h.y + w1 * (float)b.h.y;
      z0 += __shfl_xor(z0, 1); z0 += __shfl_xor(z0, 2);
      z1 += __shfl_xor(z1, 1); z1 += __shfl_xor(z1, 2);
    }

    // ---- write act row (f16x2 at even cols stays contiguous under swz) ----
#pragma unroll
    for (int m = 0; m < 4; ++m) {
      const int lvl = 4 * j + m;
      if (lvl < kNumFine) {
        U32F16 cv;
        cv.h.x = (_Float16)fa[2 * m];
        cv.h.y = (_Float16)fa[2 * m + 1];
        *reinterpret_cast<unsigned*>(&myAct[swz(row, 10 + 2 * lvl)]) = cv.u;
      }
    }
    {
      U32F16 cv;
      cv.h.x = (_Float16)cf0;
      cv.h.y = (_Float16)cf1;
      *reinterpret_cast<unsigned*>(&myAct[swz(row, 2 * (j + 1))]) = cv.u;
    }
    if (j == 0) {
      U32F16 cv;
      cv.h.x = (_Float16)z0;
      cv.h.y = (_Float16)z1;
      *reinterpret_cast<unsigned*>(&myAct[swz(row, 0)]) = cv.u;
    }
  }

  // ---- Density MLP (wave-private tile; no barriers needed) ----
  int i = blockBase + tid;
  if (i >= n) i = n - 1;
  {
    f32x4 acc[4][4];
    mfma_tiles<1, 4>(myAct, sWp + 0, lane, acc);
    epilogue_act<4, true>(acc, sB + 0, myAct, lane);
  }
  {
    f32x4 acc[4][4];
    mfma_tiles<2, 4>(myAct, sWp + 2048, lane, acc);
    epilogue_act<4, true>(acc, sB + 64, myAct, lane);
  }
  {
    f32x4 acc[1][4];
    mfma_tiles<2, 1>(myAct, sWp + 6144, lane, acc);
    const float4 b4 = *reinterpret_cast<const float4*>(&sB[128 + lg * 4]);
#pragma unroll
    for (int pt = 0; pt < 4; ++pt) {
      const int row = pt * 16 + lr;
      const int gpt = base64 + row;
      const float v0 = acc[0][pt][0] + b4.x;
      const float v1 = acc[0][pt][1] + b4.y;
      const float v2 = acc[0][pt][2] + b4.z;
      const float v3 = acc[0][pt][3] + b4.w;
      if (lg == 0) {
        if (gpt < n) out[gpt * 4] = v0;  // sigma
        myAct[swz(row, 1)] = (_Float16)v1;
        myAct[swz(row, 2)] = (_Float16)v2;
        myAct[swz(row, 3)] = (_Float16)v3;
      } else {
        f16x4 h;
        h[0] = (_Float16)v0; h[1] = (_Float16)v1; h[2] = (_Float16)v2; h[3] = (_Float16)v3;
        *reinterpret_cast<f16x4*>(&myAct[swz(row, lg * 4)]) = h;
      }
    }
  }

  // ---- SH deg-3 -> act cols 16..31; col 0 = pad (cw0 rows shifted +1) ----
  {
    const float dxr = dirs[3 * i + 0], dyr = dirs[3 * i + 1], dzr = dirs[3 * i + 2];
    const float invn = 1.0f / sqrtf(dxr * dxr + dyr * dyr + dzr * dzr);
    const float x = dxr * invn, y = dyr * invn, z = dzr * invn;
    const float x2 = x * x, y2 = y * y, z2 = z * z;
    float sh[16];
    sh[0] = 0.28209479177387814f;
    sh[1] = -0.48860251190291987f * y;
    sh[2] = 0.48860251190291987f * z;
    sh[3] = -0.48860251190291987f * x;
    sh[4] = 1.0925484305920792f * x * y;
    sh[5] = -1.0925484305920792f * y * z;
    sh[6] = 0.31539156525252005f * (2.0f * z2 - x2 - y2);
    sh[7] = -1.0925484305920792f * x * z;
    sh[8] = 0.5462742152960396f * (x2 - y2);
    sh[9] = -0.5900435899266435f * y * (3.0f * x2 - y2);
    sh[10] = 2.890611442640554f * x * y * z;
    sh[11] = -0.4570457994644658f * y * (4.0f * z2 - x2 - y2);
    sh[12] = 0.3731763325901154f * z * (2.0f * z2 - 3.0f * x2 - 3.0f * y2);
    sh[13] = -0.4570457994644658f * x * (4.0f * z2 - x2 - y2);
    sh[14] = 1.445305721320277f * z * (x2 - y2);
    sh[15] = -0.5900435899266435f * x * (x2 - 3.0f * y2);
    myAct[swz(lane, 0)] = (_Float16)0.0f;
    f16x8 v0, v1;
#pragma unroll
    for (int q = 0; q < 8; ++q) { v0[q] = (_Float16)sh[q]; v1[q] = (_Float16)sh[8 + q]; }
    *reinterpret_cast<f16x8*>(&myAct[swz(lane, 16)]) = v0;
    *reinterpret_cast<f16x8*>(&myAct[swz(lane, 24)]) = v1;
  }
  __syncthreads();

  // ---- Phase-2a weights (cw0, cw1) ----
  {
    const f16x8* s = reinterpret_cast<const f16x8*>(pW + 7168);
    f16x8* d = reinterpret_cast<f16x8*>(sWp);
    for (int t = tid; t < 768; t += BLOCK) d[t] = s[t];
  }
  __syncthreads();
  {
    f32x4 acc[4][4];
    mfma_tiles<1, 4>(myAct, sWp + 0, lane, acc);
    epilogue_act<4, true>(acc, sB + 144, myAct, lane);
  }
  {
    f32x4 acc[4][4];
    mfma_tiles<2, 4>(myAct, sWp + 2048, lane, acc);
    epilogue_act<4, true>(acc, sB + 208, myAct, lane);
  }
  __syncthreads();

  // ---- Phase-2b weights (cw2, cw3) ----
  {
    const f16x8* s = reinterpret_cast<const f16x8*>(pW + 13312);
    f16x8* d = reinterpret_cast<f16x8*>(sWp);
    for (int t = tid; t < 640; t += BLOCK) d[t] = s[t];
  }
  __syncthreads();
  {
    f32x4 acc[4][4];
    mfma_tiles<2, 4>(myAct, sWp + 0, lane, acc);
    epilogue_act<4, true>(acc, sB + 272, myAct, lane);
  }
  {
    f32x4 acc[1][4];
    mfma_tiles<2, 1>(myAct, sWp + 4096, lane, acc);
    if (lg == 0) {
      const float4 b4 = *reinterpret_cast<const float4*>(&sB[336]);
#pragma unroll
      for (int pt = 0; pt < 4; ++pt) {
        const int gpt = base64 + pt * 16 + lr;
        if (gpt < n) {
          out[gpt * 4 + 1] = 1.0f / (1.0f + __expf(-(acc[0][pt][0] + b4.x)));
          out[gpt * 4 + 2] = 1.0f / (1.0f + __expf(-(acc[0][pt][1] + b4.y)));
          out[gpt * 4 + 3] = 1.0f / (1.0f + __expf(-(acc[0][pt][2] + b4.z)));
        }
      }
    }
  }
}

// =========================================================================
// Fallback: R2's proven self-contained fused kernel (ws too small)
// =========================================================================
__global__ __launch_bounds__(BLOCK, 2) void ngp_mfma(
    const float* __restrict__ pos, const float* __restrict__ dirs, const float* __restrict__ emb,
    const float* __restrict__ dw0, const float* __restrict__ db0,
    const float* __restrict__ dw1, const float* __restrict__ db1,
    const float* __restrict__ dw2, const float* __restrict__ db2,
    const float* __restrict__ cw0, const float* __restrict__ cb0,
    const float* __restrict__ cw1, const float* __restrict__ cb1,
    const float* __restrict__ cw2, const float* __restrict__ cb2,
    const float* __restrict__ cw3, const float* __restrict__ cb3,
    float* __restrict__ out, int n) {
  __shared__ __align__(16) _Float16 sAct[4 * 4096];
  __shared__ __align__(16) _Float16 sWp[11264];
  __shared__ __align__(16) float sB[208];

  const int tid = threadIdx.x;
  const int lane = tid & 63, wid = tid >> 6;
  const int lr = lane & 15, lg = lane >> 4;
  _Float16* myAct = &sAct[wid * 4096];
  const int blockBase = blockIdx.x * BLOCK;

  int i = blockBase + tid;
  if (i >= n) i = n - 1;

  const float px = pos[3 * i + 0], py = pos[3 * i + 1], pz = pos[3 * i + 2];
  const float pn0 = fminf(fmaxf((px + 1.0f) * 0.5f, 0.0f), 1.0f);
  const float pn1 = fminf(fmaxf((py + 1.0f) * 0.5f, 0.0f), 1.0f);
  const float pn2 = fminf(fmaxf((pz + 1.0f) * 0.5f, 0.0f), 1.0f);

  float feat[32];
  const float2* emb2 = reinterpret_cast<const float2*>(emb);
#pragma unroll
  for (int l = 0; l < 16; ++l) {
    const int res = kRes[l];
    const unsigned mask = kMask[l];
    const float2* elvl = emb2 + kOff[l];
    float w0, w1, w2;
    unsigned g0, g1, g2;
    { const float s = pn0 * (float)(res - 1); const float fg = floorf(s); w0 = s - fg; g0 = (unsigned)fg; }
    { const float s = pn1 * (float)(res - 1); const float fg = floorf(s); w1 = s - fg; g1 = (unsigned)fg; }
    { const float s = pn2 * (float)(res - 1); const float fg = floorf(s); w2 = s - fg; g2 = (unsigned)fg; }
    const unsigned rm = (unsigned)(res - 1);
    const unsigned g0p = (g0 + 1u > rm) ? rm : g0 + 1u;
    const unsigned g1p = (g1 + 1u > rm) ? rm : g1 + 1u;
    const unsigned g2p = (g2 + 1u > rm) ? rm : g2 + 1u;
    const unsigned hx0 = g0 * kP1, hx1 = g0p * kP1;
    const unsigned hy0 = g1 * kP2, hy1 = g1p * kP2;
    const unsigned hz0 = g2 * kP3, hz1 = g2p * kP3;
    float f0 = 0.0f, f1 = 0.0f;
#pragma unroll
    for (int c = 0; c < 8; ++c) {
      const bool bx = (c >> 2) & 1, by = (c >> 1) & 1, bz = c & 1;
      const unsigned h = ((bx ? hx1 : hx0) + (by ? hy1 : hy0) + (bz ? hz1 : hz0)) & mask;
      const float2 e = elvl[h];
      const float wp = (bx ? w0 : 1.0f - w0) * (by ? w1 : 1.0f - w1) * (bz ? w2 : 1.0f - w2);
      f0 = __builtin_fmaf(wp, e.x, f0);
      f1 = __builtin_fmaf(wp, e.y, f1);
    }
    feat[2 * l + 0] = f0;
    feat[2 * l + 1] = f1;
  }

  float sh[16];
  {
    const float dxr = dirs[3 * i + 0], dyr = dirs[3 * i + 1], dzr = dirs[3 * i + 2];
    const float invn = 1.0f / sqrtf(dxr * dxr + dyr * dyr + dzr * dzr);
    const float x = dxr * invn, y = dyr * invn, z = dzr * invn;
    const float x2 = x * x, y2 = y * y, z2 = z * z;
    sh[0] = 0.28209479177387814f;
    sh[1] = -0.48860251190291987f * y;
    sh[2] = 0.48860251190291987f * z;
    sh[3] = -0.48860251190291987f * x;
    sh[4] = 1.0925484305920792f * x * y;
    sh[5] = -1.0925484305920792f * y * z;
    sh[6] = 0.31539156525252005f * (2.0f * z2 - x2 - y2);
    sh[7] = -1.0925484305920792f * x * z;
    sh[8] = 0.5462742152960396f * (x2 - y2);
    sh[9] = -0.5900435899266435f * y * (3.0f * x2 - y2);
    sh[10] = 2.890611442640554f * x * y * z;
    sh[11] = -0.4570457994644658f * y * (4.0f * z2 - x2 - y2);
    sh[12] = 0.3731763325901154f * z * (2.0f * z2 - 3.0f * x2 - 3.0f * y2);
    sh[13] = -0.4570457994644658f * x * (4.0f * z2 - x2 - y2);
    sh[14] = 1.445305721320277f * z * (x2 - y2);
    sh[15] = -0.5900435899266435f * x * (x2 - 3.0f * y2);
  }

#pragma unroll
  for (int cb = 0; cb < 4; ++cb) {
    f16x8 v;
#pragma unroll
    for (int q = 0; q < 8; ++q) v[q] = (_Float16)feat[cb * 8 + q];
    *reinterpret_cast<f16x8*>(&myAct[swz(lane, cb * 8)]) = v;
  }

  stage_w(sWp + 0, dw0, 32, 64, 32, 64, 0, tid);
  stage_w(sWp + 2048, dw1, 64, 64, 64, 64, 0, tid);
  stage_w(sWp + 6144, dw2, 64, 16, 64, 16, 0, tid);
  stage_b(sB + 0, db0, 64, 64, tid);
  stage_b(sB + 64, db1, 64, 64, tid);
  stage_b(sB + 128, db2, 16, 16, tid);
  __syncthreads();

  {
    f32x4 acc[4][4];
    mfma_tiles<1, 4>(myAct, sWp + 0, lane, acc);
    epilogue_act<4, true>(acc, sB + 0, myAct, lane);
  }
  {
    f32x4 acc[4][4];
    mfma_tiles<2, 4>(myAct, sWp + 2048, lane, acc);
    epilogue_act<4, true>(acc, sB + 64, myAct, lane);
  }
  {
    f32x4 acc[1][4];
    mfma_tiles<2, 1>(myAct, sWp + 6144, lane, acc);
    const float4 b4 = *reinterpret_cast<const float4*>(&sB[128 + lg * 4]);
#pragma unroll
    for (int pt = 0; pt < 4; ++pt) {
      const int row = pt * 16 + lr;
      const int gpt = blockBase + wid * 64 + row;
      const float v0 = acc[0][pt][0] + b4.x;
      const float v1 = acc[0][pt][1] + b4.y;
      const float v2 = acc[0][pt][2] + b4.z;
      const float v3 = acc[0][pt][3] + b4.w;
      if (lg == 0) {
        if (gpt < n) out[gpt * 4] = v0;
        myAct[swz(row, 1)] = (_Float16)v1;
        myAct[swz(row, 2)] = (_Float16)v2;
        myAct[swz(row, 3)] = (_Float16)v3;
      } else {
        f16x4 h;
        h[0] = (_Float16)v0; h[1] = (_Float16)v1; h[2] = (_Float16)v2; h[3] = (_Float16)v3;
        *reinterpret_cast<f16x4*>(&myAct[swz(row, lg * 4)]) = h;
      }
    }
  }

  myAct[swz(lane, 0)] = (_Float16)0.0f;
  {
    f16x8 v0, v1;
#pragma unroll
    for (int q = 0; q < 8; ++q) { v0[q] = (_Float16)sh[q]; v1[q] = (_Float16)sh[8 + q]; }
    *reinterpret_cast<f16x8*>(&myAct[swz(lane, 16)]) = v0;
    *reinterpret_cast<f16x8*>(&myAct[swz(lane, 24)]) = v1;
  }
  __syncthreads();

  stage_w(sWp + 0, cw0, 31, 64, 32, 64, 1, tid);
  stage_w(sWp + 2048, cw1, 64, 64, 64, 64, 0, tid);
  stage_w(sWp + 6144, cw2, 64, 64, 64, 64, 0, tid);
  stage_w(sWp + 10240, cw3, 64, 3, 64, 16, 0, tid);
  stage_b(sB + 0, cb0, 64, 64, tid);
  stage_b(sB + 64, cb1, 64, 64, tid);
  stage_b(sB + 128, cb2, 64, 64, tid);
  stage_b(sB + 192, cb3, 3, 16, tid);
  __syncthreads();

  {
    f32x4 acc[4][4];
    mfma_tiles<1, 4>(myAct, sWp + 0, lane, acc);
    epilogue_act<4, true>(acc, sB + 0, myAct, lane);
  }
  {
    f32x4 acc[4][4];
    mfma_tiles<2, 4>(myAct, sWp + 2048, lane, acc);
    epilogue_act<4, true>(acc, sB + 64, myAct, lane);
  }
  {
    f32x4 acc[4][4];
    mfma_tiles<2, 4>(myAct, sWp + 6144, lane, acc);
    epilogue_act<4, true>(acc, sB + 128, myAct, lane);
  }
  {
    f32x4 acc[1][4];
    mfma_tiles<2, 1>(myAct, sWp + 10240, lane, acc);
    if (lg == 0) {
      const float4 b4 = *reinterpret_cast<const float4*>(&sB[192]);
#pragma unroll
      for (int pt = 0; pt < 4; ++pt) {
        const int gpt = blockBase + wid * 64 + pt * 16 + lr;
        if (gpt < n) {
          out[gpt * 4 + 1] = 1.0f / (1.0f + __expf(-(acc[0][pt][0] + b4.x)));
          out[gpt * 4 + 2] = 1.0f / (1.0f + __expf(-(acc[0][pt][1] + b4.y)));
          out[gpt * 4 + 3] = 1.0f / (1.0f + __expf(-(acc[0][pt][2] + b4.z)));
        }
      }
    }
  }
}

extern "C" void kernel_launch(void* const* d_in, const int* in_sizes, int n_in,
                              void* d_out, int out_size, void* d_ws, size_t ws_size,
                              hipStream_t stream) {
  const float* pos = (const float*)d_in[0];
  const float* dirs = (const float*)d_in[1];
  const float* emb = (const float*)d_in[2];
  const float* dw0 = (const float*)d_in[3];
  const float* db0 = (const float*)d_in[4];
  const float* dw1 = (const float*)d_in[5];
  const float* db1 = (const float*)d_in[6];
  const float* dw2 = (const float*)d_in[7];
  const float* db2 = (const float*)d_in[8];
  const float* cw0 = (const float*)d_in[9];
  const float* cb0 = (const float*)d_in[10];
  const float* cw1 = (const float*)d_in[11];
  const float* cb1 = (const float*)d_in[12];
  const float* cw2 = (const float*)d_in[13];
  const float* cb2 = (const float*)d_in[14];
  const float* cw3 = (const float*)d_in[15];
  const float* cb3 = (const float*)d_in[16];
  float* out = (float*)d_out;

  const int n = in_sizes[0] / 3;
  const int grid = (n + BLOCK - 1) / BLOCK;
  const size_t rBytes = (size_t)kFineEntries * 64;         // 32 MiB
  const size_t tabSBytes = (size_t)kSmallEntries * 4;      // 5.14 MiB
  const size_t pWBytes = 18432 * 2;
  const size_t pBBytes = 352 * 4;
  const size_t need = rBytes + tabSBytes + pWBytes + pBBytes + 64;

  if (ws_size >= need) {
    u32x4* R = (u32x4*)d_ws;
    f16x2* tabS = (f16x2*)((char*)d_ws + rBytes);
    _Float16* pW = (_Float16*)((char*)d_ws + rBytes + tabSBytes);
    float* pB = (float*)((char*)pW + pWBytes);
    cvt_emb<<<(kSmallEntries + BLOCK - 1) / BLOCK, BLOCK, 0, stream>>>(
        (const float2*)emb, tabS, kSmallEntries);
    build_R<<<kFineEntries / 64, BLOCK, 0, stream>>>((const float2*)emb, R);
    pack_weights<<<8, BLOCK, 0, stream>>>(dw0, db0, dw1, db1, dw2, db2, cw0, cb0, cw1,
                                          cb1, cw2, cb2, cw3, cb3, pW, pB);
    ngp_fused_all<<<grid, BLOCK, 0, stream>>>(pos, dirs, R, (const unsigned*)tabS, pW, pB,
                                              out, n);
  } else {
    ngp_mfma<<<grid, BLOCK, 0, stream>>>(pos, dirs, emb, dw0, db0, dw1, db1, dw2, db2,
                                         cw0, cb0, cw1, cb1, cw2, cb2, cw3, cb3, out, n);
  }
}

// Round 7
// 366.728 us; speedup vs baseline: 7.8646x; 1.0408x over previous
//
#include <hip/hip_runtime.h>

#define BLOCK 256

typedef _Float16 f16x8 __attribute__((ext_vector_type(8)));
typedef _Float16 f16x4 __attribute__((ext_vector_type(4)));
typedef _Float16 f16x2 __attribute__((ext_vector_type(2)));
typedef float f32x4 __attribute__((ext_vector_type(4)));
typedef unsigned u32x4 __attribute__((ext_vector_type(4)));

// ---- Hash-grid compile-time tables -------------------------------------
constexpr unsigned kP1 = 73856093u, kP2 = 19349663u, kP3 = 83492791u;
constexpr int kRes[16] = {16, 32, 64, 128, 256, 512, 512, 512,
                          512, 512, 512, 512, 512, 512, 512, 512};
constexpr unsigned kMask[16] = {4095u, 32767u, 262143u, 524287u, 524287u, 524287u,
                                524287u, 524287u, 524287u, 524287u, 524287u, 524287u,
                                524287u, 524287u, 524287u, 524287u};
constexpr int kOff[16] = {0,       4096,    36864,   299008,  823296,  1347584,
                          1871872, 2396160, 2920448, 3444736, 3969024, 4493312,
                          5017600, 5541888, 6066176, 6590464};
constexpr int kNumFine = 11;            // levels 5..15 share res=512, size=2^19
constexpr int kFineEntries = 524288;
constexpr int kSmallEntries = 1347584;  // entries of levels 0..4 (= kOff[5])

constexpr int NB_R = kFineEntries / 64;                            // 8192
constexpr int NB_CVT = (kSmallEntries - 4096) / BLOCK;             // 5248

union U32F16 { unsigned u; f16x2 h; };

// ---- fp8 e4m3 helpers (L0 table only; scale x256 folded into dw0) ------
__device__ __forceinline__ unsigned enc_fp8(float x) {
  const unsigned s = x < 0.0f ? 128u : 0u;
  float a = fabsf(x);
  if (a < 0.0009765625f) return s;                 // < 2^-10 -> 0
  if (a >= 448.0f) return s | 0x7Eu;               // clamp
  int e;
  const float m = frexpf(a, &e);                   // a = m * 2^e, m in [0.5,1)
  const int E = e - 1 + 7;
  if (E < 1) {                                     // subnormal: round(a*512)
    int q = (int)rintf(a * 512.0f);
    if (q >= 8) return s | 8u;
    return s | (unsigned)q;
  }
  int q = (int)rintf(m * 16.0f);                   // in [8,16]
  int EE = E;
  if (q == 16) { q = 8; EE++; }
  if (EE > 15) return s | 0x7Eu;
  return s | ((unsigned)EE << 3) | ((unsigned)q & 7u);
}

__device__ __forceinline__ float dec_fp8(unsigned b) {
  const unsigned s = b & 128u, e = (b >> 3) & 15u, m = b & 7u;
  float v;
  if (e == 0) {
    v = (float)m * 0.001953125f;                   // m * 2^-9
  } else {
    union { unsigned u; float f; } c;
    c.u = ((e + 120u) << 23) | (m << 20);
    v = c.f;
  }
  return s ? -v : v;
}

// =========================================================================
// Weight packing helpers. Packed f16 layout [K/8][N][8]:
//  dw0@0(2048) dw1@2048(4096) dw2@6144(1024)
//  cw0@7168(2048) cw1@9216(4096) cw2@13312(4096) cw3@17408(1024)
// biases f16 pBh[352]: db0@0 db1@64 db2@128 cb0@144 cb1@208 cb2@272 cb3@336
// =========================================================================
__device__ __forceinline__ void stage_w2(_Float16* dst, const float* __restrict__ W,
                                         int Ksrc, int Nsrc, int KP, int NP, int rowShift,
                                         int tid, float s0, int srows) {
  const int total = KP * NP;
  for (int t = tid; t < total; t += BLOCK) {
    const int j = t & 7;
    const int nn = (t >> 3) % NP;
    const int kb = t / (8 * NP);
    const int k = kb * 8 + j - rowShift;
    float v = 0.0f;
    if (k >= 0 && k < Ksrc && nn < Nsrc) {
      v = W[k * Nsrc + nn];
      if (k < srows) v *= s0;
    }
    dst[t] = (_Float16)v;
  }
}

// fp32 staging for the fallback kernel
__device__ __forceinline__ void stage_w(_Float16* dst, const float* __restrict__ W,
                                        int Ksrc, int Nsrc, int KP, int NP, int rowShift,
                                        int tid) {
  stage_w2(dst, W, Ksrc, Nsrc, KP, NP, rowShift, tid, 1.0f, 0);
}

__device__ __forceinline__ void stage_b(float* dst, const float* __restrict__ B,
                                        int nsrc, int np, int tid) {
  for (int t = tid; t < np; t += BLOCK) dst[t] = (t < nsrc) ? B[t] : 0.0f;
}

// =========================================================================
// Prologue kernel (merged): build R, cvt coarse levels 1-4 to f16,
// build fp8 L0 table, pack weights + f16 biases.
// =========================================================================
__global__ __launch_bounds__(BLOCK) void prep(
    const float2* __restrict__ emb, u32x4* __restrict__ R, f16x2* __restrict__ tabS,
    unsigned short* __restrict__ tabL0,
    const float* __restrict__ dw0, const float* __restrict__ db0,
    const float* __restrict__ dw1, const float* __restrict__ db1,
    const float* __restrict__ dw2, const float* __restrict__ db2,
    const float* __restrict__ cw0, const float* __restrict__ cb0,
    const float* __restrict__ cw1, const float* __restrict__ cb1,
    const float* __restrict__ cw2, const float* __restrict__ cb2,
    const float* __restrict__ cw3, const float* __restrict__ cb3,
    _Float16* __restrict__ pW, _Float16* __restrict__ pBh) {
  const int b = blockIdx.x, tid = threadIdx.x;
  if (b < NB_R) {
    // interleaved fine table: R[h] = 64-B row; dword m (m<11) = level 5+m
    const int j = tid & 3;
    const int row = b * 64 + (tid >> 2);
    u32x4 v;
#pragma unroll
    for (int m = 0; m < 4; ++m) {
      const int lvl = 4 * j + m;
      unsigned u = 0;
      if (lvl < kNumFine) {
        const float2 e = emb[kOff[5 + lvl] + row];
        U32F16 cv;
        cv.h.x = (_Float16)e.x;
        cv.h.y = (_Float16)e.y;
        u = cv.u;
      }
      v[m] = u;
    }
    R[row * 4 + j] = v;
  } else if (b < NB_R + NB_CVT) {
    const int e = 4096 + (b - NB_R) * BLOCK + tid;
    if (e < kSmallEntries) {
      const float2 x = emb[e];
      f16x2 h;
      h.x = (_Float16)x.x;
      h.y = (_Float16)x.y;
      tabS[e] = h;
    }
  } else if (b == NB_R + NB_CVT) {
    // level-0 table -> fp8, scaled x256
#pragma unroll
    for (int k = 0; k < 16; ++k) {
      const int idx = k * BLOCK + tid;
      const float2 e = emb[idx];
      const unsigned lo = enc_fp8(e.x * 256.0f);
      const unsigned hi = enc_fp8(e.y * 256.0f);
      tabL0[idx] = (unsigned short)(lo | (hi << 8));
    }
  } else if (b == NB_R + NB_CVT + 1) {
    for (int t = tid; t < 352; t += BLOCK) {
      float v;
      if (t < 64) v = db0[t];
      else if (t < 128) v = db1[t - 64];
      else if (t < 144) v = (t - 128) < 16 ? db2[t - 128] : 0.0f;
      else if (t < 208) v = cb0[t - 144];
      else if (t < 272) v = cb1[t - 208];
      else if (t < 336) v = cb2[t - 272];
      else v = (t - 336) < 3 ? cb3[t - 336] : 0.0f;
      pBh[t] = (_Float16)v;
    }
  } else {
    switch (b - (NB_R + NB_CVT + 2)) {
      case 0: stage_w2(pW + 0, dw0, 32, 64, 32, 64, 0, tid, 1.0f / 256.0f, 2); break;
      case 1: stage_w2(pW + 2048, dw1, 64, 64, 64, 64, 0, tid, 1.0f, 0); break;
      case 2: stage_w2(pW + 6144, dw2, 64, 16, 64, 16, 0, tid, 1.0f, 0); break;
      case 3: stage_w2(pW + 7168, cw0, 31, 64, 32, 64, 1, tid, 1.0f, 0); break;
      case 4: stage_w2(pW + 9216, cw1, 64, 64, 64, 64, 0, tid, 1.0f, 0); break;
      case 5: stage_w2(pW + 13312, cw2, 64, 64, 64, 64, 0, tid, 1.0f, 0); break;
      default: stage_w2(pW + 17408, cw3, 64, 3, 64, 16, 0, tid, 1.0f, 0); break;
    }
  }
}

// =========================================================================
// MFMA machinery (verified R2-R6)
// =========================================================================
__device__ __forceinline__ int swz(int row, int col) {
  return row * 64 + (col ^ ((row & 7) << 3));
}

template <int KT, int OT>
__device__ __forceinline__ void mfma_tiles(const _Float16* act, const _Float16* wp,
                                           int lane, f32x4 (&acc)[OT][4]) {
  const int lr = lane & 15, lg = lane >> 4;
  f16x8 bF[4][KT];
#pragma unroll
  for (int pt = 0; pt < 4; ++pt)
#pragma unroll
    for (int kf = 0; kf < KT; ++kf) {
      const int row = pt * 16 + lr;
      bF[pt][kf] = *reinterpret_cast<const f16x8*>(&act[swz(row, kf * 32 + lg * 8)]);
    }
#pragma unroll
  for (int ot = 0; ot < OT; ++ot)
#pragma unroll
    for (int pt = 0; pt < 4; ++pt) acc[ot][pt] = 0.0f;
#pragma unroll
  for (int ot = 0; ot < OT; ++ot) {
#pragma unroll
    for (int kf = 0; kf < KT; ++kf) {
      const f16x8 aF =
          *reinterpret_cast<const f16x8*>(&wp[((kf * 4 + lg) * (OT * 16) + ot * 16 + lr) * 8]);
#pragma unroll
      for (int pt = 0; pt < 4; ++pt)
        acc[ot][pt] = __builtin_amdgcn_mfma_f32_16x16x32_f16(aF, bF[pt][kf], acc[ot][pt], 0, 0, 0);
    }
  }
}

template <int OT, bool RELU>
__device__ __forceinline__ void epilogue_h(const f32x4 (&acc)[OT][4], const _Float16* bias,
                                           _Float16* act, int lane) {
  const int lr = lane & 15, lg = lane >> 4;
#pragma unroll
  for (int ot = 0; ot < OT; ++ot) {
    const f16x4 b4 = *reinterpret_cast<const f16x4*>(&bias[ot * 16 + lg * 4]);
#pragma unroll
    for (int pt = 0; pt < 4; ++pt) {
      const int row = pt * 16 + lr;
      float v0 = acc[ot][pt][0] + (float)b4[0];
      float v1 = acc[ot][pt][1] + (float)b4[1];
      float v2 = acc[ot][pt][2] + (float)b4[2];
      float v3 = acc[ot][pt][3] + (float)b4[3];
      if (RELU) {
        v0 = fmaxf(v0, 0.0f); v1 = fmaxf(v1, 0.0f);
        v2 = fmaxf(v2, 0.0f); v3 = fmaxf(v3, 0.0f);
      }
      f16x4 h;
      h[0] = (_Float16)v0; h[1] = (_Float16)v1; h[2] = (_Float16)v2; h[3] = (_Float16)v3;
      *reinterpret_cast<f16x4*>(&act[swz(row, ot * 16 + lg * 4)]) = h;
    }
  }
}

// fp32-bias variant for the fallback kernel
template <int OT, bool RELU>
__device__ __forceinline__ void epilogue_act(const f32x4 (&acc)[OT][4], const float* bias,
                                             _Float16* act, int lane) {
  const int lr = lane & 15, lg = lane >> 4;
#pragma unroll
  for (int ot = 0; ot < OT; ++ot) {
    const float4 b4 = *reinterpret_cast<const float4*>(&bias[ot * 16 + lg * 4]);
#pragma unroll
    for (int pt = 0; pt < 4; ++pt) {
      const int row = pt * 16 + lr;
      float v0 = acc[ot][pt][0] + b4.x;
      float v1 = acc[ot][pt][1] + b4.y;
      float v2 = acc[ot][pt][2] + b4.z;
      float v3 = acc[ot][pt][3] + b4.w;
      if (RELU) {
        v0 = fmaxf(v0, 0.0f); v1 = fmaxf(v1, 0.0f);
        v2 = fmaxf(v2, 0.0f); v3 = fmaxf(v3, 0.0f);
      }
      f16x4 h;
      h[0] = (_Float16)v0; h[1] = (_Float16)v1; h[2] = (_Float16)v2; h[3] = (_Float16)v3;
      *reinterpret_cast<f16x4*>(&act[swz(row, ot * 16 + lg * 4)]) = h;
    }
  }
}

// =========================================================================
// Fused kernel: gather (16 levels) + full MLP. LDS 52.7 KB -> 3 blocks/CU.
// =========================================================================
__global__ __launch_bounds__(BLOCK, 3) void ngp_fused_all(
    const float* __restrict__ pos, const float* __restrict__ dirs,
    const u32x4* __restrict__ R, const unsigned* __restrict__ tabSu,
    const unsigned short* __restrict__ tabL0,
    const _Float16* __restrict__ pW, const _Float16* __restrict__ pBh,
    float* __restrict__ out, int n) {
  __shared__ __align__(16) _Float16 sAct[4 * 4096];      // 32 KB
  __shared__ __align__(16) _Float16 sWp[6144];           // 12 KB
  __shared__ __align__(16) _Float16 sBh[352];            // 704 B
  __shared__ __align__(16) unsigned short sL0[4096];     // 8 KB fp8-pairs

  const int tid = threadIdx.x;
  const int lane = tid & 63, wid = tid >> 6;
  const int lr = lane & 15, lg = lane >> 4;
  _Float16* myAct = &sAct[wid * 4096];
  const int blockBase = blockIdx.x * BLOCK;
  const int base64 = blockBase + wid * 64;

  // ---- stage: L0 table + phase-1a weights {dw0,dw1} + biases ----
  {
    const uint4* s0 = reinterpret_cast<const uint4*>(tabL0);  // 512 uint4
    uint4* d0 = reinterpret_cast<uint4*>(sL0);
    d0[tid] = s0[tid];
    d0[tid + 256] = s0[tid + 256];
    const f16x8* s = reinterpret_cast<const f16x8*>(pW);
    f16x8* d = reinterpret_cast<f16x8*>(sWp);
#pragma unroll
    for (int k = 0; k < 3; ++k) d[tid + k * BLOCK] = s[tid + k * BLOCK];
    for (int t = tid; t < 352; t += BLOCK) sBh[t] = pBh[t];
  }
  __syncthreads();

  // ---- gather phase: 4-lane groups, 4 rounds -> 64 rows/wave ----
  const int j = lane & 3;
  const int g = lane >> 2;
  const int resC = kRes[j + 1];
  const unsigned maskC = kMask[j + 1];
  const unsigned offC = (unsigned)kOff[j + 1];
  const unsigned rmC = (unsigned)(resC - 1);
  const unsigned zbx = (unsigned)((j >> 1) & 1), zby = (unsigned)(j & 1);

#pragma unroll
  for (int ii = 0; ii < 4; ++ii) {
    const int row = ii * 16 + g;
    int p = base64 + row;
    if (p >= n) p = n - 1;
    const float px = pos[3 * p + 0], py = pos[3 * p + 1], pz = pos[3 * p + 2];
    const float pn0 = fminf(fmaxf((px + 1.0f) * 0.5f, 0.0f), 1.0f);
    const float pn1 = fminf(fmaxf((py + 1.0f) * 0.5f, 0.0f), 1.0f);
    const float pn2 = fminf(fmaxf((pz + 1.0f) * 0.5f, 0.0f), 1.0f);

    // fine (res 512)
    float fw0, fw1, fw2;
    unsigned fg0, fg1, fg2;
    { const float s = pn0 * 511.0f, fl = floorf(s); fw0 = s - fl; fg0 = (unsigned)fl; }
    { const float s = pn1 * 511.0f, fl = floorf(s); fw1 = s - fl; fg1 = (unsigned)fl; }
    { const float s = pn2 * 511.0f, fl = floorf(s); fw2 = s - fl; fg2 = (unsigned)fl; }
    const unsigned fg0p = (fg0 + 1u > 511u) ? 511u : fg0 + 1u;
    const unsigned fg1p = (fg1 + 1u > 511u) ? 511u : fg1 + 1u;
    const unsigned fg2p = (fg2 + 1u > 511u) ? 511u : fg2 + 1u;
    const unsigned fx0 = fg0 * kP1, fx1 = fg0p * kP1;
    const unsigned fy0 = fg1 * kP2, fy1 = fg1p * kP2;
    const unsigned fz0 = fg2 * kP3, fz1 = fg2p * kP3;

    // coarse level j+1
    float cwx, cwy, cwz;
    unsigned cg0, cg1, cg2;
    { const float s = pn0 * (float)(resC - 1), fl = floorf(s); cwx = s - fl; cg0 = (unsigned)fl; }
    { const float s = pn1 * (float)(resC - 1), fl = floorf(s); cwy = s - fl; cg1 = (unsigned)fl; }
    { const float s = pn2 * (float)(resC - 1), fl = floorf(s); cwz = s - fl; cg2 = (unsigned)fl; }
    const unsigned cg0p = (cg0 + 1u > rmC) ? rmC : cg0 + 1u;
    const unsigned cg1p = (cg1 + 1u > rmC) ? rmC : cg1 + 1u;
    const unsigned cg2p = (cg2 + 1u > rmC) ? rmC : cg2 + 1u;
    const unsigned cx0 = cg0 * kP1, cx1 = cg0p * kP1;
    const unsigned cy0 = cg1 * kP2, cy1 = cg1p * kP2;
    const unsigned cz0 = cg2 * kP3, cz1 = cg2p * kP3;

    // level 0 (res 16)
    float zwx, zwy, zwz;
    unsigned zg0, zg1, zg2;
    { const float s = pn0 * 15.0f, fl = floorf(s); zwx = s - fl; zg0 = (unsigned)fl; }
    { const float s = pn1 * 15.0f, fl = floorf(s); zwy = s - fl; zg1 = (unsigned)fl; }
    { const float s = pn2 * 15.0f, fl = floorf(s); zwz = s - fl; zg2 = (unsigned)fl; }
    const unsigned zg0p = (zg0 + 1u > 15u) ? 15u : zg0 + 1u;
    const unsigned zg1p = (zg1 + 1u > 15u) ? 15u : zg1 + 1u;
    const unsigned zg2p = (zg2 + 1u > 15u) ? 15u : zg2 + 1u;
    const unsigned zx = (zbx ? zg0p : zg0) * kP1;
    const unsigned zy = (zby ? zg1p : zg1) * kP2;
    const unsigned zz0 = zg2 * kP3, zz1 = zg2p * kP3;

    // ---- issue ALL VMEM loads before any consumption ----
    u32x4 F[8];
#pragma unroll
    for (int c = 0; c < 8; ++c) {
      const bool bx = (c >> 2) & 1, by = (c >> 1) & 1, bz = c & 1;
      const unsigned h = ((bx ? fx1 : fx0) + (by ? fy1 : fy0) + (bz ? fz1 : fz0)) & 524287u;
      F[c] = __builtin_nontemporal_load(&R[h * 4 + j]);
    }
    unsigned C[8];
#pragma unroll
    for (int c = 0; c < 8; ++c) {
      const bool bx = (c >> 2) & 1, by = (c >> 1) & 1, bz = c & 1;
      const unsigned h = ((bx ? cx1 : cx0) + (by ? cy1 : cy0) + (bz ? cz1 : cz0)) & maskC;
      C[c] = tabSu[offC + h];
    }
    const unsigned A0 = sL0[(zx + zy + zz0) & 4095u];
    const unsigned A1 = sL0[(zx + zy + zz1) & 4095u];

    // ---- consume fine ----
    float fa[8] = {0.0f, 0.0f, 0.0f, 0.0f, 0.0f, 0.0f, 0.0f, 0.0f};
#pragma unroll
    for (int c = 0; c < 8; ++c) {
      const bool bx = (c >> 2) & 1, by = (c >> 1) & 1, bz = c & 1;
      const float wp = (bx ? fw0 : 1.0f - fw0) * (by ? fw1 : 1.0f - fw1) * (bz ? fw2 : 1.0f - fw2);
      U32F16 cv;
      cv.u = F[c][0]; fa[0] = __builtin_fmaf(wp, (float)cv.h.x, fa[0]); fa[1] = __builtin_fmaf(wp, (float)cv.h.y, fa[1]);
      cv.u = F[c][1]; fa[2] = __builtin_fmaf(wp, (float)cv.h.x, fa[2]); fa[3] = __builtin_fmaf(wp, (float)cv.h.y, fa[3]);
      cv.u = F[c][2]; fa[4] = __builtin_fmaf(wp, (float)cv.h.x, fa[4]); fa[5] = __builtin_fmaf(wp, (float)cv.h.y, fa[5]);
      cv.u = F[c][3]; fa[6] = __builtin_fmaf(wp, (float)cv.h.x, fa[6]); fa[7] = __builtin_fmaf(wp, (float)cv.h.y, fa[7]);
    }
    // ---- consume coarse ----
    float cf0 = 0.0f, cf1 = 0.0f;
#pragma unroll
    for (int c = 0; c < 8; ++c) {
      const bool bx = (c >> 2) & 1, by = (c >> 1) & 1, bz = c & 1;
      const float wp = (bx ? cwx : 1.0f - cwx) * (by ? cwy : 1.0f - cwy) * (bz ? cwz : 1.0f - cwz);
      U32F16 cv;
      cv.u = C[c];
      cf0 = __builtin_fmaf(wp, (float)cv.h.x, cf0);
      cf1 = __builtin_fmaf(wp, (float)cv.h.y, cf1);
    }
    // ---- level 0 (fp8, scaled x256; dw0 rows 0-1 carry 1/256) ----
    float z0, z1;
    {
      const float wxy = (zbx ? zwx : 1.0f - zwx) * (zby ? zwy : 1.0f - zwy);
      const float w0 = wxy * (1.0f - zwz), w1 = wxy * zwz;
      z0 = w0 * dec_fp8(A0 & 255u) + w1 * dec_fp8(A1 & 255u);
      z1 = w0 * dec_fp8(A0 >> 8) + w1 * dec_fp8(A1 >> 8);
      z0 += __shfl_xor(z0, 1); z0 += __shfl_xor(z0, 2);
      z1 += __shfl_xor(z1, 1); z1 += __shfl_xor(z1, 2);
    }

    // ---- write act row ----
#pragma unroll
    for (int m = 0; m < 4; ++m) {
      const int lvl = 4 * j + m;
      if (lvl < kNumFine) {
        U32F16 cv;
        cv.h.x = (_Float16)fa[2 * m];
        cv.h.y = (_Float16)fa[2 * m + 1];
        *reinterpret_cast<unsigned*>(&myAct[swz(row, 10 + 2 * lvl)]) = cv.u;
      }
    }
    {
      U32F16 cv;
      cv.h.x = (_Float16)cf0;
      cv.h.y = (_Float16)cf1;
      *reinterpret_cast<unsigned*>(&myAct[swz(row, 2 * (j + 1))]) = cv.u;
    }
    if (j == 0) {
      U32F16 cv;
      cv.h.x = (_Float16)z0;
      cv.h.y = (_Float16)z1;
      *reinterpret_cast<unsigned*>(&myAct[swz(row, 0)]) = cv.u;
    }
  }

  // ---- Density layers 0,1 (weights: ph1a already staged) ----
  int i = blockBase + tid;
  if (i >= n) i = n - 1;
  {
    f32x4 acc[4][4];
    mfma_tiles<1, 4>(myAct, sWp + 0, lane, acc);
    epilogue_h<4, true>(acc, sBh + 0, myAct, lane);
  }
  {
    f32x4 acc[4][4];
    mfma_tiles<2, 4>(myAct, sWp + 2048, lane, acc);
    epilogue_h<4, true>(acc, sBh + 64, myAct, lane);
  }
  __syncthreads();

  // ---- ph1b: dw2 ----
  {
    const f16x8* s = reinterpret_cast<const f16x8*>(pW + 6144);
    f16x8* d = reinterpret_cast<f16x8*>(sWp);
    if (tid < 128) d[tid] = s[tid];
  }
  __syncthreads();
  {
    f32x4 acc[1][4];
    mfma_tiles<2, 1>(myAct, sWp + 0, lane, acc);
    const f16x4 b4 = *reinterpret_cast<const f16x4*>(&sBh[128 + lg * 4]);
#pragma unroll
    for (int pt = 0; pt < 4; ++pt) {
      const int row = pt * 16 + lr;
      const int gpt = base64 + row;
      const float v0 = acc[0][pt][0] + (float)b4[0];
      const float v1 = acc[0][pt][1] + (float)b4[1];
      const float v2 = acc[0][pt][2] + (float)b4[2];
      const float v3 = acc[0][pt][3] + (float)b4[3];
      if (lg == 0) {
        if (gpt < n) out[gpt * 4] = v0;  // sigma
        myAct[swz(row, 1)] = (_Float16)v1;
        myAct[swz(row, 2)] = (_Float16)v2;
        myAct[swz(row, 3)] = (_Float16)v3;
      } else {
        f16x4 h;
        h[0] = (_Float16)v0; h[1] = (_Float16)v1; h[2] = (_Float16)v2; h[3] = (_Float16)v3;
        *reinterpret_cast<f16x4*>(&myAct[swz(row, lg * 4)]) = h;
      }
    }
  }

  // ---- SH deg-3 -> act cols 16..31; col 0 = pad (cw0 rows shifted +1) ----
  {
    const float dxr = dirs[3 * i + 0], dyr = dirs[3 * i + 1], dzr = dirs[3 * i + 2];
    const float invn = 1.0f / sqrtf(dxr * dxr + dyr * dyr + dzr * dzr);
    const float x = dxr * invn, y = dyr * invn, z = dzr * invn;
    const float x2 = x * x, y2 = y * y, z2 = z * z;
    float sh[16];
    sh[0] = 0.28209479177387814f;
    sh[1] = -0.48860251190291987f * y;
    sh[2] = 0.48860251190291987f * z;
    sh[3] = -0.48860251190291987f * x;
    sh[4] = 1.0925484305920792f * x * y;
    sh[5] = -1.0925484305920792f * y * z;
    sh[6] = 0.31539156525252005f * (2.0f * z2 - x2 - y2);
    sh[7] = -1.0925484305920792f * x * z;
    sh[8] = 0.5462742152960396f * (x2 - y2);
    sh[9] = -0.5900435899266435f * y * (3.0f * x2 - y2);
    sh[10] = 2.890611442640554f * x * y * z;
    sh[11] = -0.4570457994644658f * y * (4.0f * z2 - x2 - y2);
    sh[12] = 0.3731763325901154f * z * (2.0f * z2 - 3.0f * x2 - 3.0f * y2);
    sh[13] = -0.4570457994644658f * x * (4.0f * z2 - x2 - y2);
    sh[14] = 1.445305721320277f * z * (x2 - y2);
    sh[15] = -0.5900435899266435f * x * (x2 - 3.0f * y2);
    myAct[swz(lane, 0)] = (_Float16)0.0f;
    f16x8 v0, v1;
#pragma unroll
    for (int q = 0; q < 8; ++q) { v0[q] = (_Float16)sh[q]; v1[q] = (_Float16)sh[8 + q]; }
    *reinterpret_cast<f16x8*>(&myAct[swz(lane, 16)]) = v0;
    *reinterpret_cast<f16x8*>(&myAct[swz(lane, 24)]) = v1;
  }
  __syncthreads();

  // ---- ph2a: cw0, cw1 ----
  {
    const f16x8* s = reinterpret_cast<const f16x8*>(pW + 7168);
    f16x8* d = reinterpret_cast<f16x8*>(sWp);
#pragma unroll
    for (int k = 0; k < 3; ++k) d[tid + k * BLOCK] = s[tid + k * BLOCK];
  }
  __syncthreads();
  {
    f32x4 acc[4][4];
    mfma_tiles<1, 4>(myAct, sWp + 0, lane, acc);
    epilogue_h<4, true>(acc, sBh + 144, myAct, lane);
  }
  {
    f32x4 acc[4][4];
    mfma_tiles<2, 4>(myAct, sWp + 2048, lane, acc);
    epilogue_h<4, true>(acc, sBh + 208, myAct, lane);
  }
  __syncthreads();

  // ---- ph2b: cw2, cw3 ----
  {
    const f16x8* s = reinterpret_cast<const f16x8*>(pW + 13312);
    f16x8* d = reinterpret_cast<f16x8*>(sWp);
#pragma unroll
    for (int k = 0; k < 2; ++k) d[tid + k * BLOCK] = s[tid + k * BLOCK];
    if (tid < 128) d[tid + 512] = s[tid + 512];
  }
  __syncthreads();
  {
    f32x4 acc[4][4];
    mfma_tiles<2, 4>(myAct, sWp + 0, lane, acc);
    epilogue_h<4, true>(acc, sBh + 272, myAct, lane);
  }
  {
    f32x4 acc[1][4];
    mfma_tiles<2, 1>(myAct, sWp + 4096, lane, acc);
    if (lg == 0) {
      const float b0 = (float)sBh[336], b1 = (float)sBh[337], b2 = (float)sBh[338];
#pragma unroll
      for (int pt = 0; pt < 4; ++pt) {
        const int gpt = base64 + pt * 16 + lr;
        if (gpt < n) {
          out[gpt * 4 + 1] = 1.0f / (1.0f + __expf(-(acc[0][pt][0] + b0)));
          out[gpt * 4 + 2] = 1.0f / (1.0f + __expf(-(acc[0][pt][1] + b1)));
          out[gpt * 4 + 3] = 1.0f / (1.0f + __expf(-(acc[0][pt][2] + b2)));
        }
      }
    }
  }
}

// =========================================================================
// Fallback: R2's proven self-contained fused kernel (ws too small)
// =========================================================================
__global__ __launch_bounds__(BLOCK, 2) void ngp_mfma(
    const float* __restrict__ pos, const float* __restrict__ dirs, const float* __restrict__ emb,
    const float* __restrict__ dw0, const float* __restrict__ db0,
    const float* __restrict__ dw1, const float* __restrict__ db1,
    const float* __restrict__ dw2, const float* __restrict__ db2,
    const float* __restrict__ cw0, const float* __restrict__ cb0,
    const float* __restrict__ cw1, const float* __restrict__ cb1,
    const float* __restrict__ cw2, const float* __restrict__ cb2,
    const float* __restrict__ cw3, const float* __restrict__ cb3,
    float* __restrict__ out, int n) {
  __shared__ __align__(16) _Float16 sAct[4 * 4096];
  __shared__ __align__(16) _Float16 sWp[11264];
  __shared__ __align__(16) float sB[208];

  const int tid = threadIdx.x;
  const int lane = tid & 63, wid = tid >> 6;
  const int lr = lane & 15, lg = lane >> 4;
  _Float16* myAct = &sAct[wid * 4096];
  const int blockBase = blockIdx.x * BLOCK;

  int i = blockBase + tid;
  if (i >= n) i = n - 1;

  const float px = pos[3 * i + 0], py = pos[3 * i + 1], pz = pos[3 * i + 2];
  const float pn0 = fminf(fmaxf((px + 1.0f) * 0.5f, 0.0f), 1.0f);
  const float pn1 = fminf(fmaxf((py + 1.0f) * 0.5f, 0.0f), 1.0f);
  const float pn2 = fminf(fmaxf((pz + 1.0f) * 0.5f, 0.0f), 1.0f);

  float feat[32];
  const float2* emb2 = reinterpret_cast<const float2*>(emb);
#pragma unroll
  for (int l = 0; l < 16; ++l) {
    const int res = kRes[l];
    const unsigned mask = kMask[l];
    const float2* elvl = emb2 + kOff[l];
    float w0, w1, w2;
    unsigned g0, g1, g2;
    { const float s = pn0 * (float)(res - 1); const float fg = floorf(s); w0 = s - fg; g0 = (unsigned)fg; }
    { const float s = pn1 * (float)(res - 1); const float fg = floorf(s); w1 = s - fg; g1 = (unsigned)fg; }
    { const float s = pn2 * (float)(res - 1); const float fg = floorf(s); w2 = s - fg; g2 = (unsigned)fg; }
    const unsigned rm = (unsigned)(res - 1);
    const unsigned g0p = (g0 + 1u > rm) ? rm : g0 + 1u;
    const unsigned g1p = (g1 + 1u > rm) ? rm : g1 + 1u;
    const unsigned g2p = (g2 + 1u > rm) ? rm : g2 + 1u;
    const unsigned hx0 = g0 * kP1, hx1 = g0p * kP1;
    const unsigned hy0 = g1 * kP2, hy1 = g1p * kP2;
    const unsigned hz0 = g2 * kP3, hz1 = g2p * kP3;
    float f0 = 0.0f, f1 = 0.0f;
#pragma unroll
    for (int c = 0; c < 8; ++c) {
      const bool bx = (c >> 2) & 1, by = (c >> 1) & 1, bz = c & 1;
      const unsigned h = ((bx ? hx1 : hx0) + (by ? hy1 : hy0) + (bz ? hz1 : hz0)) & mask;
      const float2 e = elvl[h];
      const float wp = (bx ? w0 : 1.0f - w0) * (by ? w1 : 1.0f - w1) * (bz ? w2 : 1.0f - w2);
      f0 = __builtin_fmaf(wp, e.x, f0);
      f1 = __builtin_fmaf(wp, e.y, f1);
    }
    feat[2 * l + 0] = f0;
    feat[2 * l + 1] = f1;
  }

  float sh[16];
  {
    const float dxr = dirs[3 * i + 0], dyr = dirs[3 * i + 1], dzr = dirs[3 * i + 2];
    const float invn = 1.0f / sqrtf(dxr * dxr + dyr * dyr + dzr * dzr);
    const float x = dxr * invn, y = dyr * invn, z = dzr * invn;
    const float x2 = x * x, y2 = y * y, z2 = z * z;
    sh[0] = 0.28209479177387814f;
    sh[1] = -0.48860251190291987f * y;
    sh[2] = 0.48860251190291987f * z;
    sh[3] = -0.48860251190291987f * x;
    sh[4] = 1.0925484305920792f * x * y;
    sh[5] = -1.0925484305920792f * y * z;
    sh[6] = 0.31539156525252005f * (2.0f * z2 - x2 - y2);
    sh[7] = -1.0925484305920792f * x * z;
    sh[8] = 0.5462742152960396f * (x2 - y2);
    sh[9] = -0.5900435899266435f * y * (3.0f * x2 - y2);
    sh[10] = 2.890611442640554f * x * y * z;
    sh[11] = -0.4570457994644658f * y * (4.0f * z2 - x2 - y2);
    sh[12] = 0.3731763325901154f * z * (2.0f * z2 - 3.0f * x2 - 3.0f * y2);
    sh[13] = -0.4570457994644658f * x * (4.0f * z2 - x2 - y2);
    sh[14] = 1.445305721320277f * z * (x2 - y2);
    sh[15] = -0.5900435899266435f * x * (x2 - 3.0f * y2);
  }

#pragma unroll
  for (int cb = 0; cb < 4; ++cb) {
    f16x8 v;
#pragma unroll
    for (int q = 0; q < 8; ++q) v[q] = (_Float16)feat[cb * 8 + q];
    *reinterpret_cast<f16x8*>(&myAct[swz(lane, cb * 8)]) = v;
  }

  stage_w(sWp + 0, dw0, 32, 64, 32, 64, 0, tid);
  stage_w(sWp + 2048, dw1, 64, 64, 64, 64, 0, tid);
  stage_w(sWp + 6144, dw2, 64, 16, 64, 16, 0, tid);
  stage_b(sB + 0, db0, 64, 64, tid);
  stage_b(sB + 64, db1, 64, 64, tid);
  stage_b(sB + 128, db2, 16, 16, tid);
  __syncthreads();

  {
    f32x4 acc[4][4];
    mfma_tiles<1, 4>(myAct, sWp + 0, lane, acc);
    epilogue_act<4, true>(acc, sB + 0, myAct, lane);
  }
  {
    f32x4 acc[4][4];
    mfma_tiles<2, 4>(myAct, sWp + 2048, lane, acc);
    epilogue_act<4, true>(acc, sB + 64, myAct, lane);
  }
  {
    f32x4 acc[1][4];
    mfma_tiles<2, 1>(myAct, sWp + 6144, lane, acc);
    const float4 b4 = *reinterpret_cast<const float4*>(&sB[128 + lg * 4]);
#pragma unroll
    for (int pt = 0; pt < 4; ++pt) {
      const int row = pt * 16 + lr;
      const int gpt = blockBase + wid * 64 + row;
      const float v0 = acc[0][pt][0] + b4.x;
      const float v1 = acc[0][pt][1] + b4.y;
      const float v2 = acc[0][pt][2] + b4.z;
      const float v3 = acc[0][pt][3] + b4.w;
      if (lg == 0) {
        if (gpt < n) out[gpt * 4] = v0;
        myAct[swz(row, 1)] = (_Float16)v1;
        myAct[swz(row, 2)] = (_Float16)v2;
        myAct[swz(row, 3)] = (_Float16)v3;
      } else {
        f16x4 h;
        h[0] = (_Float16)v0; h[1] = (_Float16)v1; h[2] = (_Float16)v2; h[3] = (_Float16)v3;
        *reinterpret_cast<f16x4*>(&myAct[swz(row, lg * 4)]) = h;
      }
    }
  }

  myAct[swz(lane, 0)] = (_Float16)0.0f;
  {
    f16x8 v0, v1;
#pragma unroll
    for (int q = 0; q < 8; ++q) { v0[q] = (_Float16)sh[q]; v1[q] = (_Float16)sh[8 + q]; }
    *reinterpret_cast<f16x8*>(&myAct[swz(lane, 16)]) = v0;
    *reinterpret_cast<f16x8*>(&myAct[swz(lane, 24)]) = v1;
  }
  __syncthreads();

  stage_w(sWp + 0, cw0, 31, 64, 32, 64, 1, tid);
  stage_w(sWp + 2048, cw1, 64, 64, 64, 64, 0, tid);
  stage_w(sWp + 6144, cw2, 64, 64, 64, 64, 0, tid);
  stage_w(sWp + 10240, cw3, 64, 3, 64, 16, 0, tid);
  stage_b(sB + 0, cb0, 64, 64, tid);
  stage_b(sB + 64, cb1, 64, 64, tid);
  stage_b(sB + 128, cb2, 64, 64, tid);
  stage_b(sB + 192, cb3, 3, 16, tid);
  __syncthreads();

  {
    f32x4 acc[4][4];
    mfma_tiles<1, 4>(myAct, sWp + 0, lane, acc);
    epilogue_act<4, true>(acc, sB + 0, myAct, lane);
  }
  {
    f32x4 acc[4][4];
    mfma_tiles<2, 4>(myAct, sWp + 2048, lane, acc);
    epilogue_act<4, true>(acc, sB + 64, myAct, lane);
  }
  {
    f32x4 acc[4][4];
    mfma_tiles<2, 4>(myAct, sWp + 6144, lane, acc);
    epilogue_act<4, true>(acc, sB + 128, myAct, lane);
  }
  {
    f32x4 acc[1][4];
    mfma_tiles<2, 1>(myAct, sWp + 10240, lane, acc);
    if (lg == 0) {
      const float4 b4 = *reinterpret_cast<const float4*>(&sB[192]);
#pragma unroll
      for (int pt = 0; pt < 4; ++pt) {
        const int gpt = blockBase + wid * 64 + pt * 16 + lr;
        if (gpt < n) {
          out[gpt * 4 + 1] = 1.0f / (1.0f + __expf(-(acc[0][pt][0] + b4.x)));
          out[gpt * 4 + 2] = 1.0f / (1.0f + __expf(-(acc[0][pt][1] + b4.y)));
          out[gpt * 4 + 3] = 1.0f / (1.0f + __expf(-(acc[0][pt][2] + b4.z)));
        }
      }
    }
  }
}

extern "C" void kernel_launch(void* const* d_in, const int* in_sizes, int n_in,
                              void* d_out, int out_size, void* d_ws, size_t ws_size,
                              hipStream_t stream) {
  const float* pos = (const float*)d_in[0];
  const float* dirs = (const float*)d_in[1];
  const float* emb = (const float*)d_in[2];
  const float* dw0 = (const float*)d_in[3];
  const float* db0 = (const float*)d_in[4];
  const float* dw1 = (const float*)d_in[5];
  const float* db1 = (const float*)d_in[6];
  const float* dw2 = (const float*)d_in[7];
  const float* db2 = (const float*)d_in[8];
  const float* cw0 = (const float*)d_in[9];
  const float* cb0 = (const float*)d_in[10];
  const float* cw1 = (const float*)d_in[11];
  const float* cb1 = (const float*)d_in[12];
  const float* cw2 = (const float*)d_in[13];
  const float* cb2 = (const float*)d_in[14];
  const float* cw3 = (const float*)d_in[15];
  const float* cb3 = (const float*)d_in[16];
  float* out = (float*)d_out;

  const int n = in_sizes[0] / 3;
  const int grid = (n + BLOCK - 1) / BLOCK;
  const size_t rBytes = (size_t)kFineEntries * 64;        // 32 MiB
  const size_t tabSBytes = (size_t)kSmallEntries * 4;     // 5.39 MiB
  const size_t tabL0Bytes = 4096 * 2;
  const size_t pWBytes = 18432 * 2;
  const size_t pBBytes = 352 * 2;
  const size_t need = rBytes + tabSBytes + tabL0Bytes + pWBytes + pBBytes + 64;

  if (ws_size >= need) {
    u32x4* R = (u32x4*)d_ws;
    f16x2* tabS = (f16x2*)((char*)d_ws + rBytes);
    unsigned short* tabL0 = (unsigned short*)((char*)d_ws + rBytes + tabSBytes);
    _Float16* pW = (_Float16*)((char*)tabL0 + tabL0Bytes);
    _Float16* pBh = (_Float16*)((char*)pW + pWBytes);
    prep<<<NB_R + NB_CVT + 9, BLOCK, 0, stream>>>(
        (const float2*)emb, R, tabS, tabL0, dw0, db0, dw1, db1, dw2, db2, cw0, cb0, cw1,
        cb1, cw2, cb2, cw3, cb3, pW, pBh);
    ngp_fused_all<<<grid, BLOCK, 0, stream>>>(pos, dirs, R, (const unsigned*)tabS, tabL0,
                                              pW, pBh, out, n);
  } else {
    ngp_mfma<<<grid, BLOCK, 0, stream>>>(pos, dirs, emb, dw0, db0, dw1, db1, dw2, db2,
                                         cw0, cb0, cw1, cb1, cw2, cb2, cw3, cb3, out, n);
  }
}

// Round 9
// 276.709 us; speedup vs baseline: 10.4231x; 1.3253x over previous
//
#include <hip/hip_runtime.h>

#define BLOCK 256

typedef _Float16 f16x8 __attribute__((ext_vector_type(8)));
typedef _Float16 f16x4 __attribute__((ext_vector_type(4)));
typedef _Float16 f16x2 __attribute__((ext_vector_type(2)));
typedef float f32x4 __attribute__((ext_vector_type(4)));
typedef float f32x2 __attribute__((ext_vector_type(2)));
typedef unsigned u32x2 __attribute__((ext_vector_type(2)));

// ---- Hash-grid compile-time tables -------------------------------------
constexpr unsigned kP1 = 73856093u, kP2 = 19349663u, kP3 = 83492791u;
constexpr int kRes[16] = {16, 32, 64, 128, 256, 512, 512, 512,
                          512, 512, 512, 512, 512, 512, 512, 512};
constexpr unsigned kMask[16] = {4095u, 32767u, 262143u, 524287u, 524287u, 524287u,
                                524287u, 524287u, 524287u, 524287u, 524287u, 524287u,
                                524287u, 524287u, 524287u, 524287u};
constexpr int kOff[16] = {0,       4096,    36864,   299008,  823296,  1347584,
                          1871872, 2396160, 2920448, 3444736, 3969024, 4493312,
                          5017600, 5541888, 6066176, 6590464};
constexpr int kNumFine = 11;            // levels 5..15 share res=512, size=2^19
constexpr int kFineEntries = 524288;
constexpr int kSmallEntries = 1347584;  // entries of levels 0..4 (= kOff[5])

constexpr float kS = 524288.0f;         // table scale 2^19 (folded into dw0)
constexpr float kInvS = 1.0f / 524288.0f;

constexpr int NB_R32 = kFineEntries / BLOCK;             // 2048
constexpr int NB_CVT = (kSmallEntries - 4096) / BLOCK;   // 5248

union U32F16 { unsigned u; f16x2 h; };

// ---- fp8 e4m3fn software codec (encode: prep only; decode: fallback) ----
__device__ __forceinline__ unsigned enc_fp8(float x) {
  const unsigned s = x < 0.0f ? 128u : 0u;
  float a = fabsf(x);
  if (a < 0.0009765625f) return s;
  if (a >= 448.0f) return s | 0x7Eu;
  int e;
  const float m = frexpf(a, &e);
  const int E = e - 1 + 7;
  if (E < 1) {
    int q = (int)rintf(a * 512.0f);
    if (q >= 8) return s | 8u;
    return s | (unsigned)q;
  }
  int q = (int)rintf(m * 16.0f);
  int EE = E;
  if (q == 16) { q = 8; EE++; }
  if (EE > 15) return s | 0x7Eu;
  return s | ((unsigned)EE << 3) | ((unsigned)q & 7u);
}

__device__ __forceinline__ float dec_fp8(unsigned b) {
  const unsigned s = b & 128u, e = (b >> 3) & 15u, m = b & 7u;
  float v;
  if (e == 0) {
    v = (float)m * 0.001953125f;
  } else {
    union { unsigned u; float f; } c;
    c.u = ((e + 120u) << 23) | (m << 20);
    v = c.f;
  }
  return s ? -v : v;
}

// decode 2 packed fp8 (word-half selected at compile time) -> 2 f32
#if defined(__has_builtin)
#if __has_builtin(__builtin_amdgcn_cvt_pk_f32_fp8)
#define HW_FP8_CVT 1
#endif
#endif

template <bool HI>
__device__ __forceinline__ f32x2 cvt2(unsigned w) {
#ifdef HW_FP8_CVT
  return __builtin_amdgcn_cvt_pk_f32_fp8((int)w, HI);
#else
  const unsigned b0 = HI ? (w >> 16) & 255u : w & 255u;
  const unsigned b1 = HI ? (w >> 24) & 255u : (w >> 8) & 255u;
  f32x2 r;
  r.x = dec_fp8(b0);
  r.y = dec_fp8(b1);
  return r;
#endif
}

// =========================================================================
// Weight packing. Packed f16 [K/8][N][8]:
//  dw0@0(2048) dw1@2048(4096) dw2@6144(1024)
//  cw0@7168(2048) cw1@9216(4096) cw2@13312(4096) cw3@17408(1024)
// biases f16 pBh[352].  dw0 all rows x kInvS (tables scaled x kS).
// =========================================================================
__device__ __forceinline__ void stage_w2(_Float16* dst, const float* __restrict__ W,
                                         int Ksrc, int Nsrc, int KP, int NP, int rowShift,
                                         int tid, float s0, int srows) {
  const int total = KP * NP;
  for (int t = tid; t < total; t += BLOCK) {
    const int j = t & 7;
    const int nn = (t >> 3) % NP;
    const int kb = t / (8 * NP);
    const int k = kb * 8 + j - rowShift;
    float v = 0.0f;
    if (k >= 0 && k < Ksrc && nn < Nsrc) {
      v = W[k * Nsrc + nn];
      if (k < srows) v *= s0;
    }
    dst[t] = (_Float16)v;
  }
}

__device__ __forceinline__ void stage_w(_Float16* dst, const float* __restrict__ W,
                                        int Ksrc, int Nsrc, int KP, int NP, int rowShift,
                                        int tid) {
  stage_w2(dst, W, Ksrc, Nsrc, KP, NP, rowShift, tid, 1.0f, 0);
}

__device__ __forceinline__ void stage_b(float* dst, const float* __restrict__ B,
                                        int nsrc, int np, int tid) {
  for (int t = tid; t < np; t += BLOCK) dst[t] = (t < nsrc) ? B[t] : 0.0f;
}

// =========================================================================
// Prologue kernel: build fp8 tables (R32 fine, tabS8 coarse, tabL0) + pack
// weights/biases.
// =========================================================================
__global__ __launch_bounds__(BLOCK) void prep(
    const float2* __restrict__ emb, uint4* __restrict__ R32q,
    unsigned short* __restrict__ tabS8, unsigned short* __restrict__ tabL0,
    const float* __restrict__ dw0, const float* __restrict__ db0,
    const float* __restrict__ dw1, const float* __restrict__ db1,
    const float* __restrict__ dw2, const float* __restrict__ db2,
    const float* __restrict__ cw0, const float* __restrict__ cb0,
    const float* __restrict__ cw1, const float* __restrict__ cb1,
    const float* __restrict__ cw2, const float* __restrict__ cb2,
    const float* __restrict__ cw3, const float* __restrict__ cb3,
    _Float16* __restrict__ pW, _Float16* __restrict__ pBh) {
  const int b = blockIdx.x, tid = threadIdx.x;
  if (b < NB_R32) {
    // interleaved fine table: 32-B row per hash; bytes 2l..2l+1 = level 5+l
    const int row = b * BLOCK + tid;
    unsigned d[8] = {0, 0, 0, 0, 0, 0, 0, 0};
#pragma unroll
    for (int l = 0; l < kNumFine; ++l) {
      const float2 e = emb[kOff[5 + l] + row];
      const unsigned lo = enc_fp8(e.x * kS);
      const unsigned hi = enc_fp8(e.y * kS);
      d[l >> 1] |= (lo | (hi << 8)) << ((l & 1) * 16);
    }
    uint4 v0, v1;
    v0.x = d[0]; v0.y = d[1]; v0.z = d[2]; v0.w = d[3];
    v1.x = d[4]; v1.y = d[5]; v1.z = d[6]; v1.w = d[7];
    R32q[row * 2] = v0;
    R32q[row * 2 + 1] = v1;
  } else if (b < NB_R32 + NB_CVT) {
    const int e = 4096 + (b - NB_R32) * BLOCK + tid;
    if (e < kSmallEntries) {
      const float2 x = emb[e];
      tabS8[e] = (unsigned short)(enc_fp8(x.x * kS) | (enc_fp8(x.y * kS) << 8));
    }
  } else if (b == NB_R32 + NB_CVT) {
#pragma unroll
    for (int k = 0; k < 16; ++k) {
      const int idx = k * BLOCK + tid;
      const float2 e = emb[idx];
      tabL0[idx] = (unsigned short)(enc_fp8(e.x * kS) | (enc_fp8(e.y * kS) << 8));
    }
  } else if (b == NB_R32 + NB_CVT + 1) {
    for (int t = tid; t < 352; t += BLOCK) {
      float v;
      if (t < 64) v = db0[t];
      else if (t < 128) v = db1[t - 64];
      else if (t < 144) v = (t - 128) < 16 ? db2[t - 128] : 0.0f;
      else if (t < 208) v = cb0[t - 144];
      else if (t < 272) v = cb1[t - 208];
      else if (t < 336) v = cb2[t - 272];
      else v = (t - 336) < 3 ? cb3[t - 336] : 0.0f;
      pBh[t] = (_Float16)v;
    }
  } else {
    switch (b - (NB_R32 + NB_CVT + 2)) {
      case 0: stage_w2(pW + 0, dw0, 32, 64, 32, 64, 0, tid, kInvS, 32); break;
      case 1: stage_w2(pW + 2048, dw1, 64, 64, 64, 64, 0, tid, 1.0f, 0); break;
      case 2: stage_w2(pW + 6144, dw2, 64, 16, 64, 16, 0, tid, 1.0f, 0); break;
      case 3: stage_w2(pW + 7168, cw0, 31, 64, 32, 64, 1, tid, 1.0f, 0); break;
      case 4: stage_w2(pW + 9216, cw1, 64, 64, 64, 64, 0, tid, 1.0f, 0); break;
      case 5: stage_w2(pW + 13312, cw2, 64, 64, 64, 64, 0, tid, 1.0f, 0); break;
      default: stage_w2(pW + 17408, cw3, 64, 3, 64, 16, 0, tid, 1.0f, 0); break;
    }
  }
}

// =========================================================================
// MFMA machinery (verified R2-R7)
// =========================================================================
__device__ __forceinline__ int swz(int row, int col) {
  return row * 64 + (col ^ ((row & 7) << 3));
}

template <int KT, int OT>
__device__ __forceinline__ void mfma_tiles(const _Float16* act, const _Float16* wp,
                                           int lane, f32x4 (&acc)[OT][4]) {
  const int lr = lane & 15, lg = lane >> 4;
  f16x8 bF[4][KT];
#pragma unroll
  for (int pt = 0; pt < 4; ++pt)
#pragma unroll
    for (int kf = 0; kf < KT; ++kf) {
      const int row = pt * 16 + lr;
      bF[pt][kf] = *reinterpret_cast<const f16x8*>(&act[swz(row, kf * 32 + lg * 8)]);
    }
#pragma unroll
  for (int ot = 0; ot < OT; ++ot)
#pragma unroll
    for (int pt = 0; pt < 4; ++pt) acc[ot][pt] = 0.0f;
#pragma unroll
  for (int ot = 0; ot < OT; ++ot) {
#pragma unroll
    for (int kf = 0; kf < KT; ++kf) {
      const f16x8 aF =
          *reinterpret_cast<const f16x8*>(&wp[((kf * 4 + lg) * (OT * 16) + ot * 16 + lr) * 8]);
#pragma unroll
      for (int pt = 0; pt < 4; ++pt)
        acc[ot][pt] = __builtin_amdgcn_mfma_f32_16x16x32_f16(aF, bF[pt][kf], acc[ot][pt], 0, 0, 0);
    }
  }
}

template <int OT, bool RELU>
__device__ __forceinline__ void epilogue_h(const f32x4 (&acc)[OT][4], const _Float16* bias,
                                           _Float16* act, int lane) {
  const int lr = lane & 15, lg = lane >> 4;
#pragma unroll
  for (int ot = 0; ot < OT; ++ot) {
    const f16x4 b4 = *reinterpret_cast<const f16x4*>(&bias[ot * 16 + lg * 4]);
#pragma unroll
    for (int pt = 0; pt < 4; ++pt) {
      const int row = pt * 16 + lr;
      float v0 = acc[ot][pt][0] + (float)b4[0];
      float v1 = acc[ot][pt][1] + (float)b4[1];
      float v2 = acc[ot][pt][2] + (float)b4[2];
      float v3 = acc[ot][pt][3] + (float)b4[3];
      if (RELU) {
        v0 = fmaxf(v0, 0.0f); v1 = fmaxf(v1, 0.0f);
        v2 = fmaxf(v2, 0.0f); v3 = fmaxf(v3, 0.0f);
      }
      f16x4 h;
      h[0] = (_Float16)v0; h[1] = (_Float16)v1; h[2] = (_Float16)v2; h[3] = (_Float16)v3;
      *reinterpret_cast<f16x4*>(&act[swz(row, ot * 16 + lg * 4)]) = h;
    }
  }
}

template <int OT, bool RELU>
__device__ __forceinline__ void epilogue_act(const f32x4 (&acc)[OT][4], const float* bias,
                                             _Float16* act, int lane) {
  const int lr = lane & 15, lg = lane >> 4;
#pragma unroll
  for (int ot = 0; ot < OT; ++ot) {
    const float4 b4 = *reinterpret_cast<const float4*>(&bias[ot * 16 + lg * 4]);
#pragma unroll
    for (int pt = 0; pt < 4; ++pt) {
      const int row = pt * 16 + lr;
      float v0 = acc[ot][pt][0] + b4.x;
      float v1 = acc[ot][pt][1] + b4.y;
      float v2 = acc[ot][pt][2] + b4.z;
      float v3 = acc[ot][pt][3] + b4.w;
      if (RELU) {
        v0 = fmaxf(v0, 0.0f); v1 = fmaxf(v1, 0.0f);
        v2 = fmaxf(v2, 0.0f); v3 = fmaxf(v3, 0.0f);
      }
      f16x4 h;
      h[0] = (_Float16)v0; h[1] = (_Float16)v1; h[2] = (_Float16)v2; h[3] = (_Float16)v3;
      *reinterpret_cast<f16x4*>(&act[swz(row, ot * 16 + lg * 4)]) = h;
    }
  }
}

// =========================================================================
// Gather round buffer + issue/consume (2-deep software pipeline)
// =========================================================================
struct RB {
  u32x2 F[8];      // fine: 8 B of R32 row (4 levels x fp8-pair)
  unsigned C[8];   // coarse: fp8-pair per corner
  float fw0, fw1, fw2, cwx, cwy, cwz;
};

__device__ __forceinline__ void issue_rb(
    float px, float py, float pz, int j, int row,
    const u32x2* __restrict__ R32, const unsigned short* __restrict__ tabS8,
    int resC, unsigned maskC, unsigned offC, unsigned rmC,
    unsigned zbx, unsigned zby, const unsigned short* sL0, _Float16* myAct, RB& b) {
  const float pn0 = fminf(fmaxf((px + 1.0f) * 0.5f, 0.0f), 1.0f);
  const float pn1 = fminf(fmaxf((py + 1.0f) * 0.5f, 0.0f), 1.0f);
  const float pn2 = fminf(fmaxf((pz + 1.0f) * 0.5f, 0.0f), 1.0f);

  // fine (res 512)
  {
    unsigned fg0, fg1, fg2;
    { const float s = pn0 * 511.0f, fl = floorf(s); b.fw0 = s - fl; fg0 = (unsigned)fl; }
    { const float s = pn1 * 511.0f, fl = floorf(s); b.fw1 = s - fl; fg1 = (unsigned)fl; }
    { const float s = pn2 * 511.0f, fl = floorf(s); b.fw2 = s - fl; fg2 = (unsigned)fl; }
    const unsigned fg0p = (fg0 + 1u > 511u) ? 511u : fg0 + 1u;
    const unsigned fg1p = (fg1 + 1u > 511u) ? 511u : fg1 + 1u;
    const unsigned fg2p = (fg2 + 1u > 511u) ? 511u : fg2 + 1u;
    const unsigned fx0 = fg0 * kP1, fx1 = fg0p * kP1;
    const unsigned fy0 = fg1 * kP2, fy1 = fg1p * kP2;
    const unsigned fz0 = fg2 * kP3, fz1 = fg2p * kP3;
#pragma unroll
    for (int c = 0; c < 8; ++c) {
      const bool bx = (c >> 2) & 1, by = (c >> 1) & 1, bz = c & 1;
      const unsigned h = ((bx ? fx1 : fx0) + (by ? fy1 : fy0) + (bz ? fz1 : fz0)) & 524287u;
      b.F[c] = R32[h * 4 + j];   // lane 3 reads row pad (same line, discarded)
    }
  }
  // coarse level j+1
  {
    unsigned cg0, cg1, cg2;
    { const float s = pn0 * (float)(resC - 1), fl = floorf(s); b.cwx = s - fl; cg0 = (unsigned)fl; }
    { const float s = pn1 * (float)(resC - 1), fl = floorf(s); b.cwy = s - fl; cg1 = (unsigned)fl; }
    { const float s = pn2 * (float)(resC - 1), fl = floorf(s); b.cwz = s - fl; cg2 = (unsigned)fl; }
    const unsigned cg0p = (cg0 + 1u > rmC) ? rmC : cg0 + 1u;
    const unsigned cg1p = (cg1 + 1u > rmC) ? rmC : cg1 + 1u;
    const unsigned cg2p = (cg2 + 1u > rmC) ? rmC : cg2 + 1u;
    const unsigned cx0 = cg0 * kP1, cx1 = cg0p * kP1;
    const unsigned cy0 = cg1 * kP2, cy1 = cg1p * kP2;
    const unsigned cz0 = cg2 * kP3, cz1 = cg2p * kP3;
#pragma unroll
    for (int c = 0; c < 8; ++c) {
      const bool bx = (c >> 2) & 1, by = (c >> 1) & 1, bz = c & 1;
      const unsigned h = ((bx ? cx1 : cx0) + (by ? cy1 : cy0) + (bz ? cz1 : cz0)) & maskC;
      b.C[c] = tabS8[offC + h];
    }
  }
  // level 0 (res 16) — LDS, completed here
  {
    float zwx, zwy, zwz;
    unsigned zg0, zg1, zg2;
    { const float s = pn0 * 15.0f, fl = floorf(s); zwx = s - fl; zg0 = (unsigned)fl; }
    { const float s = pn1 * 15.0f, fl = floorf(s); zwy = s - fl; zg1 = (unsigned)fl; }
    { const float s = pn2 * 15.0f, fl = floorf(s); zwz = s - fl; zg2 = (unsigned)fl; }
    const unsigned zg0p = (zg0 + 1u > 15u) ? 15u : zg0 + 1u;
    const unsigned zg1p = (zg1 + 1u > 15u) ? 15u : zg1 + 1u;
    const unsigned zg2p = (zg2 + 1u > 15u) ? 15u : zg2 + 1u;
    const unsigned zx = (zbx ? zg0p : zg0) * kP1;
    const unsigned zy = (zby ? zg1p : zg1) * kP2;
    const unsigned A0 = sL0[(zx + zy + zg2 * kP3) & 4095u];
    const unsigned A1 = sL0[(zx + zy + zg2p * kP3) & 4095u];
    const float wxy = (zbx ? zwx : 1.0f - zwx) * (zby ? zwy : 1.0f - zwy);
    const float w0 = wxy * (1.0f - zwz), w1 = wxy * zwz;
    const f32x2 a = cvt2<false>(A0), bb = cvt2<false>(A1);
    float z0 = w0 * a.x + w1 * bb.x;
    float z1 = w0 * a.y + w1 * bb.y;
    z0 += __shfl_xor(z0, 1); z0 += __shfl_xor(z0, 2);
    z1 += __shfl_xor(z1, 1); z1 += __shfl_xor(z1, 2);
    if (j == 0) {
      U32F16 cv;
      cv.h.x = (_Float16)z0;
      cv.h.y = (_Float16)z1;
      *reinterpret_cast<unsigned*>(&myAct[swz(row, 0)]) = cv.u;
    }
  }
}

__device__ __forceinline__ void consume_rb(const RB& b, int j, int row, _Float16* myAct) {
  float fa[8] = {0.0f, 0.0f, 0.0f, 0.0f, 0.0f, 0.0f, 0.0f, 0.0f};
#pragma unroll
  for (int c = 0; c < 8; ++c) {
    const bool bx = (c >> 2) & 1, by = (c >> 1) & 1, bz = c & 1;
    const float wp =
        (bx ? b.fw0 : 1.0f - b.fw0) * (by ? b.fw1 : 1.0f - b.fw1) * (bz ? b.fw2 : 1.0f - b.fw2);
    const f32x2 v0 = cvt2<false>(b.F[c].x);
    const f32x2 v1 = cvt2<true>(b.F[c].x);
    const f32x2 v2 = cvt2<false>(b.F[c].y);
    const f32x2 v3 = cvt2<true>(b.F[c].y);
    fa[0] = __builtin_fmaf(wp, v0.x, fa[0]); fa[1] = __builtin_fmaf(wp, v0.y, fa[1]);
    fa[2] = __builtin_fmaf(wp, v1.x, fa[2]); fa[3] = __builtin_fmaf(wp, v1.y, fa[3]);
    fa[4] = __builtin_fmaf(wp, v2.x, fa[4]); fa[5] = __builtin_fmaf(wp, v2.y, fa[5]);
    fa[6] = __builtin_fmaf(wp, v3.x, fa[6]); fa[7] = __builtin_fmaf(wp, v3.y, fa[7]);
  }
  float cf0 = 0.0f, cf1 = 0.0f;
#pragma unroll
  for (int c = 0; c < 8; ++c) {
    const bool bx = (c >> 2) & 1, by = (c >> 1) & 1, bz = c & 1;
    const float wp =
        (bx ? b.cwx : 1.0f - b.cwx) * (by ? b.cwy : 1.0f - b.cwy) * (bz ? b.cwz : 1.0f - b.cwz);
    const f32x2 v = cvt2<false>(b.C[c]);
    cf0 = __builtin_fmaf(wp, v.x, cf0);
    cf1 = __builtin_fmaf(wp, v.y, cf1);
  }
#pragma unroll
  for (int m = 0; m < 4; ++m) {
    const int lvl = 4 * j + m;
    if (lvl < kNumFine) {
      U32F16 cv;
      cv.h.x = (_Float16)fa[2 * m];
      cv.h.y = (_Float16)fa[2 * m + 1];
      *reinterpret_cast<unsigned*>(&myAct[swz(row, 10 + 2 * lvl)]) = cv.u;
    }
  }
  {
    U32F16 cv;
    cv.h.x = (_Float16)cf0;
    cv.h.y = (_Float16)cf1;
    *reinterpret_cast<unsigned*>(&myAct[swz(row, 2 * (j + 1))]) = cv.u;
  }
}

__device__ __forceinline__ void copy_wp(_Float16* sWp, const _Float16* src, int n8, int tid) {
  const f16x8* s = reinterpret_cast<const f16x8*>(src);
  f16x8* d = reinterpret_cast<f16x8*>(sWp);
  for (int t = tid; t < n8; t += BLOCK) d[t] = s[t];
}

// =========================================================================
// Fused kernel: pipelined fp8 gather + full MLP. LDS 48.7 KB -> 3 blocks/CU.
// =========================================================================
__global__ __launch_bounds__(BLOCK, 3) void ngp_fused_all(
    const float* __restrict__ pos, const float* __restrict__ dirs,
    const u32x2* __restrict__ R32, const unsigned short* __restrict__ tabS8,
    const unsigned short* __restrict__ tabL0,
    const _Float16* __restrict__ pW, const _Float16* __restrict__ pBh,
    float* __restrict__ out, int n) {
  __shared__ __align__(16) _Float16 sAct[4 * 4096];   // 32 KB
  __shared__ __align__(16) _Float16 sWp[4096];        // 8 KB (per-layer)
  __shared__ __align__(16) _Float16 sBh[352];         // 704 B
  __shared__ __align__(16) unsigned short sL0[4096];  // 8 KB

  const int tid = threadIdx.x;
  const int lane = tid & 63, wid = tid >> 6;
  const int lr = lane & 15, lg = lane >> 4;
  _Float16* myAct = &sAct[wid * 4096];
  const int blockBase = blockIdx.x * BLOCK;
  const int base64 = blockBase + wid * 64;

  const int j = lane & 3;
  const int g = lane >> 2;

  // ---- preload all 4 rounds' positions + this thread's dir ----
  float Px[4], Py[4], Pz[4];
#pragma unroll
  for (int r = 0; r < 4; ++r) {
    int p = base64 + r * 16 + g;
    if (p >= n) p = n - 1;
    Px[r] = pos[3 * p + 0];
    Py[r] = pos[3 * p + 1];
    Pz[r] = pos[3 * p + 2];
  }
  int i = blockBase + tid;
  if (i >= n) i = n - 1;
  const float dxr = dirs[3 * i + 0], dyr = dirs[3 * i + 1], dzr = dirs[3 * i + 2];

  // ---- prologue staging: L0 table + dw0 + biases ----
  {
    const uint4* s0 = reinterpret_cast<const uint4*>(tabL0);
    uint4* d0 = reinterpret_cast<uint4*>(sL0);
    d0[tid] = s0[tid];
    d0[tid + 256] = s0[tid + 256];
    copy_wp(sWp, pW, 256, tid);  // dw0
    for (int t = tid; t < 352; t += BLOCK) sBh[t] = pBh[t];
  }
  __syncthreads();

  // ---- gather: 2-deep pipelined rounds ----
  const int resC = kRes[j + 1];
  const unsigned maskC = kMask[j + 1];
  const unsigned offC = (unsigned)kOff[j + 1];
  const unsigned rmC = (unsigned)(resC - 1);
  const unsigned zbx = (unsigned)((j >> 1) & 1), zby = (unsigned)(j & 1);

  {
    RB A, B;
    issue_rb(Px[0], Py[0], Pz[0], j, g, R32, tabS8, resC, maskC, offC, rmC, zbx, zby, sL0, myAct, A);
    issue_rb(Px[1], Py[1], Pz[1], j, 16 + g, R32, tabS8, resC, maskC, offC, rmC, zbx, zby, sL0, myAct, B);
    consume_rb(A, j, g, myAct);
    issue_rb(Px[2], Py[2], Pz[2], j, 32 + g, R32, tabS8, resC, maskC, offC, rmC, zbx, zby, sL0, myAct, A);
    consume_rb(B, j, 16 + g, myAct);
    issue_rb(Px[3], Py[3], Pz[3], j, 48 + g, R32, tabS8, resC, maskC, offC, rmC, zbx, zby, sL0, myAct, B);
    consume_rb(A, j, 32 + g, myAct);
    consume_rb(B, j, 48 + g, myAct);
  }

  // ---- Density layer 0 (dw0 staged) ----
  {
    f32x4 acc[4][4];
    mfma_tiles<1, 4>(myAct, sWp, lane, acc);
    epilogue_h<4, true>(acc, sBh + 0, myAct, lane);
  }
  __syncthreads();
  copy_wp(sWp, pW + 2048, 512, tid);  // dw1
  __syncthreads();
  {
    f32x4 acc[4][4];
    mfma_tiles<2, 4>(myAct, sWp, lane, acc);
    epilogue_h<4, true>(acc, sBh + 64, myAct, lane);
  }
  __syncthreads();
  copy_wp(sWp, pW + 6144, 128, tid);  // dw2
  __syncthreads();
  {
    f32x4 acc[1][4];
    mfma_tiles<2, 1>(myAct, sWp, lane, acc);
    const f16x4 b4 = *reinterpret_cast<const f16x4*>(&sBh[128 + lg * 4]);
#pragma unroll
    for (int pt = 0; pt < 4; ++pt) {
      const int row = pt * 16 + lr;
      const int gpt = base64 + row;
      const float v0 = acc[0][pt][0] + (float)b4[0];
      const float v1 = acc[0][pt][1] + (float)b4[1];
      const float v2 = acc[0][pt][2] + (float)b4[2];
      const float v3 = acc[0][pt][3] + (float)b4[3];
      if (lg == 0) {
        if (gpt < n) out[gpt * 4] = v0;  // sigma
        myAct[swz(row, 1)] = (_Float16)v1;
        myAct[swz(row, 2)] = (_Float16)v2;
        myAct[swz(row, 3)] = (_Float16)v3;
      } else {
        f16x4 h;
        h[0] = (_Float16)v0; h[1] = (_Float16)v1; h[2] = (_Float16)v2; h[3] = (_Float16)v3;
        *reinterpret_cast<f16x4*>(&myAct[swz(row, lg * 4)]) = h;
      }
    }
  }

  // ---- SH deg-3 -> act cols 16..31; col 0 = pad (cw0 rows shifted +1) ----
  {
    const float invn = 1.0f / sqrtf(dxr * dxr + dyr * dyr + dzr * dzr);
    const float x = dxr * invn, y = dyr * invn, z = dzr * invn;
    const float x2 = x * x, y2 = y * y, z2 = z * z;
    float sh[16];
    sh[0] = 0.28209479177387814f;
    sh[1] = -0.48860251190291987f * y;
    sh[2] = 0.48860251190291987f * z;
    sh[3] = -0.48860251190291987f * x;
    sh[4] = 1.0925484305920792f * x * y;
    sh[5] = -1.0925484305920792f * y * z;
    sh[6] = 0.31539156525252005f * (2.0f * z2 - x2 - y2);
    sh[7] = -1.0925484305920792f * x * z;
    sh[8] = 0.5462742152960396f * (x2 - y2);
    sh[9] = -0.5900435899266435f * y * (3.0f * x2 - y2);
    sh[10] = 2.890611442640554f * x * y * z;
    sh[11] = -0.4570457994644658f * y * (4.0f * z2 - x2 - y2);
    sh[12] = 0.3731763325901154f * z * (2.0f * z2 - 3.0f * x2 - 3.0f * y2);
    sh[13] = -0.4570457994644658f * x * (4.0f * z2 - x2 - y2);
    sh[14] = 1.445305721320277f * z * (x2 - y2);
    sh[15] = -0.5900435899266435f * x * (x2 - 3.0f * y2);
    myAct[swz(lane, 0)] = (_Float16)0.0f;
    f16x8 v0, v1;
#pragma unroll
    for (int q = 0; q < 8; ++q) { v0[q] = (_Float16)sh[q]; v1[q] = (_Float16)sh[8 + q]; }
    *reinterpret_cast<f16x8*>(&myAct[swz(lane, 16)]) = v0;
    *reinterpret_cast<f16x8*>(&myAct[swz(lane, 24)]) = v1;
  }
  __syncthreads();
  copy_wp(sWp, pW + 7168, 256, tid);  // cw0
  __syncthreads();
  {
    f32x4 acc[4][4];
    mfma_tiles<1, 4>(myAct, sWp, lane, acc);
    epilogue_h<4, true>(acc, sBh + 144, myAct, lane);
  }
  __syncthreads();
  copy_wp(sWp, pW + 9216, 512, tid);  // cw1
  __syncthreads();
  {
    f32x4 acc[4][4];
    mfma_tiles<2, 4>(myAct, sWp, lane, acc);
    epilogue_h<4, true>(acc, sBh + 208, myAct, lane);
  }
  __syncthreads();
  copy_wp(sWp, pW + 13312, 512, tid);  // cw2
  __syncthreads();
  {
    f32x4 acc[4][4];
    mfma_tiles<2, 4>(myAct, sWp, lane, acc);
    epilogue_h<4, true>(acc, sBh + 272, myAct, lane);
  }
  __syncthreads();
  copy_wp(sWp, pW + 17408, 128, tid);  // cw3
  __syncthreads();
  {
    f32x4 acc[1][4];
    mfma_tiles<2, 1>(myAct, sWp, lane, acc);
    if (lg == 0) {
      const float b0 = (float)sBh[336], b1 = (float)sBh[337], b2 = (float)sBh[338];
#pragma unroll
      for (int pt = 0; pt < 4; ++pt) {
        const int gpt = base64 + pt * 16 + lr;
        if (gpt < n) {
          out[gpt * 4 + 1] = 1.0f / (1.0f + __expf(-(acc[0][pt][0] + b0)));
          out[gpt * 4 + 2] = 1.0f / (1.0f + __expf(-(acc[0][pt][1] + b1)));
          out[gpt * 4 + 3] = 1.0f / (1.0f + __expf(-(acc[0][pt][2] + b2)));
        }
      }
    }
  }
}

// =========================================================================
// Fallback: R2's proven self-contained fused kernel (ws too small)
// =========================================================================
__global__ __launch_bounds__(BLOCK, 2) void ngp_mfma(
    const float* __restrict__ pos, const float* __restrict__ dirs, const float* __restrict__ emb,
    const float* __restrict__ dw0, const float* __restrict__ db0,
    const float* __restrict__ dw1, const float* __restrict__ db1,
    const float* __restrict__ dw2, const float* __restrict__ db2,
    const float* __restrict__ cw0, const float* __restrict__ cb0,
    const float* __restrict__ cw1, const float* __restrict__ cb1,
    const float* __restrict__ cw2, const float* __restrict__ cb2,
    const float* __restrict__ cw3, const float* __restrict__ cb3,
    float* __restrict__ out, int n) {
  __shared__ __align__(16) _Float16 sAct[4 * 4096];
  __shared__ __align__(16) _Float16 sWp[11264];
  __shared__ __align__(16) float sB[208];

  const int tid = threadIdx.x;
  const int lane = tid & 63, wid = tid >> 6;
  const int lr = lane & 15, lg = lane >> 4;
  _Float16* myAct = &sAct[wid * 4096];
  const int blockBase = blockIdx.x * BLOCK;

  int i = blockBase + tid;
  if (i >= n) i = n - 1;

  const float px = pos[3 * i + 0], py = pos[3 * i + 1], pz = pos[3 * i + 2];
  const float pn0 = fminf(fmaxf((px + 1.0f) * 0.5f, 0.0f), 1.0f);
  const float pn1 = fminf(fmaxf((py + 1.0f) * 0.5f, 0.0f), 1.0f);
  const float pn2 = fminf(fmaxf((pz + 1.0f) * 0.5f, 0.0f), 1.0f);

  float feat[32];
  const float2* emb2 = reinterpret_cast<const float2*>(emb);
#pragma unroll
  for (int l = 0; l < 16; ++l) {
    const int res = kRes[l];
    const unsigned mask = kMask[l];
    const float2* elvl = emb2 + kOff[l];
    float w0, w1, w2;
    unsigned g0, g1, g2;
    { const float s = pn0 * (float)(res - 1); const float fg = floorf(s); w0 = s - fg; g0 = (unsigned)fg; }
    { const float s = pn1 * (float)(res - 1); const float fg = floorf(s); w1 = s - fg; g1 = (unsigned)fg; }
    { const float s = pn2 * (float)(res - 1); const float fg = floorf(s); w2 = s - fg; g2 = (unsigned)fg; }
    const unsigned rm = (unsigned)(res - 1);
    const unsigned g0p = (g0 + 1u > rm) ? rm : g0 + 1u;
    const unsigned g1p = (g1 + 1u > rm) ? rm : g1 + 1u;
    const unsigned g2p = (g2 + 1u > rm) ? rm : g2 + 1u;
    const unsigned hx0 = g0 * kP1, hx1 = g0p * kP1;
    const unsigned hy0 = g1 * kP2, hy1 = g1p * kP2;
    const unsigned hz0 = g2 * kP3, hz1 = g2p * kP3;
    float f0 = 0.0f, f1 = 0.0f;
#pragma unroll
    for (int c = 0; c < 8; ++c) {
      const bool bx = (c >> 2) & 1, by = (c >> 1) & 1, bz = c & 1;
      const unsigned h = ((bx ? hx1 : hx0) + (by ? hy1 : hy0) + (bz ? hz1 : hz0)) & mask;
      const float2 e = elvl[h];
      const float wp = (bx ? w0 : 1.0f - w0) * (by ? w1 : 1.0f - w1) * (bz ? w2 : 1.0f - w2);
      f0 = __builtin_fmaf(wp, e.x, f0);
      f1 = __builtin_fmaf(wp, e.y, f1);
    }
    feat[2 * l + 0] = f0;
    feat[2 * l + 1] = f1;
  }

  float sh[16];
  {
    const float dxr = dirs[3 * i + 0], dyr = dirs[3 * i + 1], dzr = dirs[3 * i + 2];
    const float invn = 1.0f / sqrtf(dxr * dxr + dyr * dyr + dzr * dzr);
    const float x = dxr * invn, y = dyr * invn, z = dzr * invn;
    const float x2 = x * x, y2 = y * y, z2 = z * z;
    sh[0] = 0.28209479177387814f;
    sh[1] = -0.48860251190291987f * y;
    sh[2] = 0.48860251190291987f * z;
    sh[3] = -0.48860251190291987f * x;
    sh[4] = 1.0925484305920792f * x * y;
    sh[5] = -1.0925484305920792f * y * z;
    sh[6] = 0.31539156525252005f * (2.0f * z2 - x2 - y2);
    sh[7] = -1.0925484305920792f * x * z;
    sh[8] = 0.5462742152960396f * (x2 - y2);
    sh[9] = -0.5900435899266435f * y * (3.0f * x2 - y2);
    sh[10] = 2.890611442640554f * x * y * z;
    sh[11] = -0.4570457994644658f * y * (4.0f * z2 - x2 - y2);
    sh[12] = 0.3731763325901154f * z * (2.0f * z2 - 3.0f * x2 - 3.0f * y2);
    sh[13] = -0.4570457994644658f * x * (4.0f * z2 - x2 - y2);
    sh[14] = 1.445305721320277f * z * (x2 - y2);
    sh[15] = -0.5900435899266435f * x * (x2 - 3.0f * y2);
  }

#pragma unroll
  for (int cb = 0; cb < 4; ++cb) {
    f16x8 v;
#pragma unroll
    for (int q = 0; q < 8; ++q) v[q] = (_Float16)feat[cb * 8 + q];
    *reinterpret_cast<f16x8*>(&myAct[swz(lane, cb * 8)]) = v;
  }

  stage_w(sWp + 0, dw0, 32, 64, 32, 64, 0, tid);
  stage_w(sWp + 2048, dw1, 64, 64, 64, 64, 0, tid);
  stage_w(sWp + 6144, dw2, 64, 16, 64, 16, 0, tid);
  stage_b(sB + 0, db0, 64, 64, tid);
  stage_b(sB + 64, db1, 64, 64, tid);
  stage_b(sB + 128, db2, 16, 16, tid);
  __syncthreads();

  {
    f32x4 acc[4][4];
    mfma_tiles<1, 4>(myAct, sWp + 0, lane, acc);
    epilogue_act<4, true>(acc, sB + 0, myAct, lane);
  }
  {
    f32x4 acc[4][4];
    mfma_tiles<2, 4>(myAct, sWp + 2048, lane, acc);
    epilogue_act<4, true>(acc, sB + 64, myAct, lane);
  }
  {
    f32x4 acc[1][4];
    mfma_tiles<2, 1>(myAct, sWp + 6144, lane, acc);
    const float4 b4 = *reinterpret_cast<const float4*>(&sB[128 + lg * 4]);
#pragma unroll
    for (int pt = 0; pt < 4; ++pt) {
      const int row = pt * 16 + lr;
      const int gpt = blockBase + wid * 64 + row;
      const float v0 = acc[0][pt][0] + b4.x;
      const float v1 = acc[0][pt][1] + b4.y;
      const float v2 = acc[0][pt][2] + b4.z;
      const float v3 = acc[0][pt][3] + b4.w;
      if (lg == 0) {
        if (gpt < n) out[gpt * 4] = v0;
        myAct[swz(row, 1)] = (_Float16)v1;
        myAct[swz(row, 2)] = (_Float16)v2;
        myAct[swz(row, 3)] = (_Float16)v3;
      } else {
        f16x4 h;
        h[0] = (_Float16)v0; h[1] = (_Float16)v1; h[2] = (_Float16)v2; h[3] = (_Float16)v3;
        *reinterpret_cast<f16x4*>(&myAct[swz(row, lg * 4)]) = h;
      }
    }
  }

  myAct[swz(lane, 0)] = (_Float16)0.0f;
  {
    f16x8 v0, v1;
#pragma unroll
    for (int q = 0; q < 8; ++q) { v0[q] = (_Float16)sh[q]; v1[q] = (_Float16)sh[8 + q]; }
    *reinterpret_cast<f16x8*>(&myAct[swz(lane, 16)]) = v0;
    *reinterpret_cast<f16x8*>(&myAct[swz(lane, 24)]) = v1;
  }
  __syncthreads();

  stage_w(sWp + 0, cw0, 31, 64, 32, 64, 1, tid);
  stage_w(sWp + 2048, cw1, 64, 64, 64, 64, 0, tid);
  stage_w(sWp + 6144, cw2, 64, 64, 64, 64, 0, tid);
  stage_w(sWp + 10240, cw3, 64, 3, 64, 16, 0, tid);
  stage_b(sB + 0, cb0, 64, 64, tid);
  stage_b(sB + 64, cb1, 64, 64, tid);
  stage_b(sB + 128, cb2, 64, 64, tid);
  stage_b(sB + 192, cb3, 3, 16, tid);
  __syncthreads();

  {
    f32x4 acc[4][4];
    mfma_tiles<1, 4>(myAct, sWp + 0, lane, acc);
    epilogue_act<4, true>(acc, sB + 0, myAct, lane);
  }
  {
    f32x4 acc[4][4];
    mfma_tiles<2, 4>(myAct, sWp + 2048, lane, acc);
    epilogue_act<4, true>(acc, sB + 64, myAct, lane);
  }
  {
    f32x4 acc[4][4];
    mfma_tiles<2, 4>(myAct, sWp + 6144, lane, acc);
    epilogue_act<4, true>(acc, sB + 128, myAct, lane);
  }
  {
    f32x4 acc[1][4];
    mfma_tiles<2, 1>(myAct, sWp + 10240, lane, acc);
    if (lg == 0) {
      const float4 b4 = *reinterpret_cast<const float4*>(&sB[192]);
#pragma unroll
      for (int pt = 0; pt < 4; ++pt) {
        const int gpt = blockBase + wid * 64 + pt * 16 + lr;
        if (gpt < n) {
          out[gpt * 4 + 1] = 1.0f / (1.0f + __expf(-(acc[0][pt][0] + b4.x)));
          out[gpt * 4 + 2] = 1.0f / (1.0f + __expf(-(acc[0][pt][1] + b4.y)));
          out[gpt * 4 + 3] = 1.0f / (1.0f + __expf(-(acc[0][pt][2] + b4.z)));
        }
      }
    }
  }
}

extern "C" void kernel_launch(void* const* d_in, const int* in_sizes, int n_in,
                              void* d_out, int out_size, void* d_ws, size_t ws_size,
                              hipStream_t stream) {
  const float* pos = (const float*)d_in[0];
  const float* dirs = (const float*)d_in[1];
  const float* emb = (const float*)d_in[2];
  const float* dw0 = (const float*)d_in[3];
  const float* db0 = (const float*)d_in[4];
  const float* dw1 = (const float*)d_in[5];
  const float* db1 = (const float*)d_in[6];
  const float* dw2 = (const float*)d_in[7];
  const float* db2 = (const float*)d_in[8];
  const float* cw0 = (const float*)d_in[9];
  const float* cb0 = (const float*)d_in[10];
  const float* cw1 = (const float*)d_in[11];
  const float* cb1 = (const float*)d_in[12];
  const float* cw2 = (const float*)d_in[13];
  const float* cb2 = (const float*)d_in[14];
  const float* cw3 = (const float*)d_in[15];
  const float* cb3 = (const float*)d_in[16];
  float* out = (float*)d_out;

  const int n = in_sizes[0] / 3;
  const int grid = (n + BLOCK - 1) / BLOCK;
  const size_t rBytes = (size_t)kFineEntries * 32;      // 16 MiB
  const size_t tabSBytes = (size_t)kSmallEntries * 2;   // 2.7 MiB
  const size_t tabL0Bytes = 4096 * 2;
  const size_t pWBytes = 18432 * 2;
  const size_t pBBytes = 352 * 2;
  const size_t need = rBytes + tabSBytes + tabL0Bytes + pWBytes + pBBytes + 64;

  if (ws_size >= need) {
    u32x2* R32 = (u32x2*)d_ws;
    unsigned short* tabS8 = (unsigned short*)((char*)d_ws + rBytes);
    unsigned short* tabL0 = (unsigned short*)((char*)tabS8 + tabSBytes);
    _Float16* pW = (_Float16*)((char*)tabL0 + tabL0Bytes);
    _Float16* pBh = (_Float16*)((char*)pW + pWBytes);
    prep<<<NB_R32 + NB_CVT + 9, BLOCK, 0, stream>>>(
        (const float2*)emb, (uint4*)R32, tabS8, tabL0, dw0, db0, dw1, db1, dw2, db2,
        cw0, cb0, cw1, cb1, cw2, cb2, cw3, cb3, pW, pBh);
    ngp_fused_all<<<grid, BLOCK, 0, stream>>>(pos, dirs, R32, tabS8, tabL0, pW, pBh, out, n);
  } else {
    ngp_mfma<<<grid, BLOCK, 0, stream>>>(pos, dirs, emb, dw0, db0, dw1, db1, dw2, db2,
                                         cw0, cb0, cw1, cb1, cw2, cb2, cw3, cb3, out, n);
  }
}